// Round 17
// baseline (401.933 us; speedup 1.0000x reference)
//
#include <hip/hip_runtime.h>

#define NN 60000
#define NE 300000
typedef unsigned short ush;

static inline int cdiv(int a, int b) { return (a + b - 1) / b; }

__device__ inline unsigned ord_enc(float x) {
  unsigned u = __float_as_uint(x);
  return (u & 0x80000000u) ? ~u : (u | 0x80000000u);
}
__device__ inline float ord_dec(unsigned u) {
  return __uint_as_float((u & 0x80000000u) ? (u & 0x7fffffffu) : ~u);
}
__device__ inline float bf2f(unsigned u16) { return __uint_as_float(u16 << 16); }
__device__ inline ush f2bf(float x) {
  unsigned u = __float_as_uint(x);
  return (ush)((u + 0x7FFFu + ((u >> 16) & 1u)) >> 16);
}
__device__ inline unsigned pack2(float lo, float hi) {
  return ((unsigned)f2bf(hi) << 16) | (unsigned)f2bf(lo);
}

// ================= CSR build (dst-sorted) =================
__global__ void deg_kernel(const int* __restrict__ key, int* __restrict__ deg) {
  int e = blockIdx.x * blockDim.x + threadIdx.x;
  if (e < NE) atomicAdd(deg + key[e], 1);
}

__global__ void scan1_kernel(const int* __restrict__ deg, int* __restrict__ rowptr,
                             int* __restrict__ partial) {
  __shared__ int s[256];
  int i = blockIdx.x * 256 + threadIdx.x;
  int v = (i < NN) ? deg[i] : 0;
  s[threadIdx.x] = v;
  __syncthreads();
  for (int off = 1; off < 256; off <<= 1) {
    int t = (threadIdx.x >= off) ? s[threadIdx.x - off] : 0;
    __syncthreads();
    s[threadIdx.x] += t;
    __syncthreads();
  }
  if (i < NN) rowptr[i] = s[threadIdx.x] - v;
  if (threadIdx.x == 255) partial[blockIdx.x] = s[255];
}

__global__ void scan2_kernel(int* __restrict__ partial, int nb) {
  __shared__ int s[256];
  int v = (threadIdx.x < nb) ? partial[threadIdx.x] : 0;
  s[threadIdx.x] = v;
  __syncthreads();
  for (int off = 1; off < 256; off <<= 1) {
    int t = (threadIdx.x >= off) ? s[threadIdx.x - off] : 0;
    __syncthreads();
    s[threadIdx.x] += t;
    __syncthreads();
  }
  if (threadIdx.x < nb) partial[threadIdx.x] = s[threadIdx.x] - v;
}

__global__ void scan3_kernel(int* __restrict__ rowptr, const int* __restrict__ partial,
                             int* __restrict__ cursor) {
  int i = blockIdx.x * 256 + threadIdx.x;
  if (i < NN) {
    int r = rowptr[i] + partial[blockIdx.x];
    rowptr[i] = r;
    cursor[i] = r;
  }
}

// scatter + ef permutation fused (sequential ef read, random 64B write)
__global__ void scatter_dst_kernel(const int* __restrict__ src, const int* __restrict__ dst,
                                   const float* __restrict__ ef, int* __restrict__ cursor,
                                   int* __restrict__ src_s, int* __restrict__ dst_s,
                                   float* __restrict__ ef_s) {
  int e = blockIdx.x * blockDim.x + threadIdx.x;
  if (e >= NE) return;
  int d = dst[e];
  int j = atomicAdd(cursor + d, 1);
  src_s[j] = src[e];
  dst_s[j] = d;
  const float4* ep = (const float4*)(ef + (size_t)e * 16);
  float4 a = ep[0], b = ep[1], c = ep[2], dd = ep[3];
  float4* op = (float4*)(ef_s + (size_t)j * 16);
  op[0] = a; op[1] = b; op[2] = c; op[3] = dd;
}

// ---------------- fold: precompute folded weight products (7424 dots of length 64) -------
__global__ void fold_kernel(const float* __restrict__ fp_w, const float* __restrict__ fp_b,
                            const float* __restrict__ ep_w, const float* __restrict__ ep_b,
                            const float* __restrict__ fij, const float* __restrict__ ebias,
                            const float* __restrict__ ni, const float* __restrict__ nj,
                            const float* __restrict__ node, float* __restrict__ fold) {
  int t = blockIdx.x * blockDim.x + threadIdx.x;
  if (t >= 7424) return;
  int o = t & 63;
  const float* A;
  const float* B;
  float init = 0.f;
  if (t < 1024)      { A = ep_w + (size_t)(t >> 6) * 64; B = fij + o; }
  else if (t < 1088) { A = ep_b; B = fij + o; init = ebias[o]; }
  else if (t < 3136) { A = fp_w + (size_t)((t - 1088) >> 6) * 64; B = ni + o; }
  else if (t < 5184) { A = fp_w + (size_t)((t - 3136) >> 6) * 64; B = nj + o; }
  else if (t < 7232) { A = fp_w + (size_t)((t - 5184) >> 6) * 64; B = node + o; }
  else if (t < 7296) { A = fp_b; B = ni + o; }
  else if (t < 7360) { A = fp_b; B = nj + o; }
  else               { A = fp_b; B = node + o; }
  float a = init;
  for (int i = 0; i < 64; ++i) a = fmaf(A[i], B[(size_t)i * 64], a);
  fold[t] = a;
}

// ---------------- pack nn_w/nn_b -> bf16 W2bf[544][32] ----------------
__global__ void nnwt_kernel(const float* __restrict__ nn_w, const float* __restrict__ nn_b,
                            ush* __restrict__ W2bf) {
  int t = blockIdx.x * blockDim.x + threadIdx.x;
  if (t >= 544 * 32) return;
  int c = t >> 5, o = t & 31;
  float v;
  if (c < 512) {
    int k = c >> 5, i = c & 31;
    v = nn_w[(size_t)k * 1024 + i * 32 + o];
  } else {
    v = nn_b[(c - 512) * 32 + o];
  }
  W2bf[t] = f2bf(v);
}

// ---------------- tiled GEMM (rows x K) @ (K x 64) -> bf16 out; 3 weight sets ------------
template <int K, bool BIAS>
__global__ __launch_bounds__(256, 2) void gemm3_kernel(
    const float* __restrict__ A, const float* __restrict__ W0, const float* __restrict__ W1,
    const float* __restrict__ W2, const float* __restrict__ b0, const float* __restrict__ b1,
    const float* __restrict__ b2, ush* __restrict__ o0, ush* __restrict__ o1,
    ush* __restrict__ o2, int rows) {
  __shared__ float sA[128][K + 1];
  __shared__ float sW[K][64];
  const float* W = blockIdx.y == 0 ? W0 : blockIdx.y == 1 ? W1 : W2;
  const float* bb = blockIdx.y == 0 ? b0 : blockIdx.y == 1 ? b1 : b2;
  ush* out = blockIdx.y == 0 ? o0 : blockIdx.y == 1 ? o1 : o2;
  int t = threadIdx.x;
  int r0 = blockIdx.x * 128;
  for (int i = t; i < K * 16; i += 256) ((float4*)sW)[i] = ((const float4*)W)[i];
  for (int i = t; i < 128 * (K / 4); i += 256) {
    int rr = i / (K / 4), cc = i % (K / 4);
    float4 v = (r0 + rr < rows) ? ((const float4*)(A + (size_t)(r0 + rr) * K))[cc]
                                : make_float4(0.f, 0.f, 0.f, 0.f);
    sA[rr][cc * 4 + 0] = v.x;
    sA[rr][cc * 4 + 1] = v.y;
    sA[rr][cc * 4 + 2] = v.z;
    sA[rr][cc * 4 + 3] = v.w;
  }
  __syncthreads();
  int rg = t >> 3, cg = t & 7;
  float acc[4][8];
#pragma unroll
  for (int i = 0; i < 4; ++i)
#pragma unroll
    for (int j = 0; j < 8; ++j) acc[i][j] = 0.f;
#pragma unroll 8
  for (int k = 0; k < K; ++k) {
    float a0 = sA[rg * 4 + 0][k], a1 = sA[rg * 4 + 1][k];
    float a2 = sA[rg * 4 + 2][k], a3 = sA[rg * 4 + 3][k];
    float4 wA = *(const float4*)&sW[k][cg * 8];
    float4 wB = *(const float4*)&sW[k][cg * 8 + 4];
#pragma unroll
    for (int i = 0; i < 4; ++i) {
      float a = i == 0 ? a0 : i == 1 ? a1 : i == 2 ? a2 : a3;
      acc[i][0] = fmaf(a, wA.x, acc[i][0]); acc[i][1] = fmaf(a, wA.y, acc[i][1]);
      acc[i][2] = fmaf(a, wA.z, acc[i][2]); acc[i][3] = fmaf(a, wA.w, acc[i][3]);
      acc[i][4] = fmaf(a, wB.x, acc[i][4]); acc[i][5] = fmaf(a, wB.y, acc[i][5]);
      acc[i][6] = fmaf(a, wB.z, acc[i][6]); acc[i][7] = fmaf(a, wB.w, acc[i][7]);
    }
  }
  float bv[8];
#pragma unroll
  for (int j = 0; j < 8; ++j) bv[j] = BIAS ? bb[cg * 8 + j] : 0.f;
#pragma unroll
  for (int i = 0; i < 4; ++i) {
    int r = r0 + rg * 4 + i;
    if (r < rows) {
      uint4 pv;
      pv.x = pack2(acc[i][0] + bv[0], acc[i][1] + bv[1]);
      pv.y = pack2(acc[i][2] + bv[2], acc[i][3] + bv[3]);
      pv.z = pack2(acc[i][4] + bv[4], acc[i][5] + bv[5]);
      pv.w = pack2(acc[i][6] + bv[6], acc[i][7] + bv[7]);
      *(uint4*)(out + (size_t)r * 64 + cg * 8) = pv;
    }
  }
}

// ---------------- edge GEMM + fused f_out epilogue (edges in dst-sorted order) -----------
template <int K, bool STORE, bool ABF>
__global__ __launch_bounds__(256, 2) void gemm_fout_kernel(
    const void* __restrict__ Ap, const float* __restrict__ W, const float* __restrict__ bias,
    const ush* __restrict__ hs, const ush* __restrict__ hd, const int* __restrict__ src_s,
    const int* __restrict__ dst_s, const float* __restrict__ attn, ush* __restrict__ fstore,
    float* __restrict__ logit) {
  __shared__ float sA[128][K + 1];
  __shared__ float sW[K][64];
  int t = threadIdx.x;
  int r0 = blockIdx.x * 128;
  for (int i = t; i < K * 16; i += 256) ((float4*)sW)[i] = ((const float4*)W)[i];
  if (ABF) {
    const ush* A = (const ush*)Ap;
    for (int i = t; i < 128 * (K / 8); i += 256) {
      int rr = i / (K / 8), cc = i % (K / 8);
      uint4 v = (r0 + rr < NE) ? ((const uint4*)(A + (size_t)(r0 + rr) * K))[cc]
                               : make_uint4(0, 0, 0, 0);
      float* dp = &sA[rr][cc * 8];
      dp[0] = bf2f(v.x & 0xffff); dp[1] = bf2f(v.x >> 16);
      dp[2] = bf2f(v.y & 0xffff); dp[3] = bf2f(v.y >> 16);
      dp[4] = bf2f(v.z & 0xffff); dp[5] = bf2f(v.z >> 16);
      dp[6] = bf2f(v.w & 0xffff); dp[7] = bf2f(v.w >> 16);
    }
  } else {
    const float* A = (const float*)Ap;
    for (int i = t; i < 128 * (K / 4); i += 256) {
      int rr = i / (K / 4), cc = i % (K / 4);
      float4 v = (r0 + rr < NE) ? ((const float4*)(A + (size_t)(r0 + rr) * K))[cc]
                                : make_float4(0.f, 0.f, 0.f, 0.f);
      sA[rr][cc * 4 + 0] = v.x;
      sA[rr][cc * 4 + 1] = v.y;
      sA[rr][cc * 4 + 2] = v.z;
      sA[rr][cc * 4 + 3] = v.w;
    }
  }
  __syncthreads();
  int rg = t >> 3, cg = t & 7;
  float acc[4][8];
#pragma unroll
  for (int i = 0; i < 4; ++i)
#pragma unroll
    for (int j = 0; j < 8; ++j) acc[i][j] = 0.f;
#pragma unroll 8
  for (int k = 0; k < K; ++k) {
    float a0 = sA[rg * 4 + 0][k], a1 = sA[rg * 4 + 1][k];
    float a2 = sA[rg * 4 + 2][k], a3 = sA[rg * 4 + 3][k];
    float4 wA = *(const float4*)&sW[k][cg * 8];
    float4 wB = *(const float4*)&sW[k][cg * 8 + 4];
#pragma unroll
    for (int i = 0; i < 4; ++i) {
      float a = i == 0 ? a0 : i == 1 ? a1 : i == 2 ? a2 : a3;
      acc[i][0] = fmaf(a, wA.x, acc[i][0]); acc[i][1] = fmaf(a, wA.y, acc[i][1]);
      acc[i][2] = fmaf(a, wA.z, acc[i][2]); acc[i][3] = fmaf(a, wA.w, acc[i][3]);
      acc[i][4] = fmaf(a, wB.x, acc[i][4]); acc[i][5] = fmaf(a, wB.y, acc[i][5]);
      acc[i][6] = fmaf(a, wB.z, acc[i][6]); acc[i][7] = fmaf(a, wB.w, acc[i][7]);
    }
  }
  float bv[8], av[8];
#pragma unroll
  for (int j = 0; j < 8; ++j) {
    bv[j] = bias[cg * 8 + j];
    av[j] = attn[cg * 8 + j];
  }
#pragma unroll
  for (int i = 0; i < 4; ++i) {
    int r = r0 + rg * 4 + i;
    if (r < NE) {
      int s = src_s[r], d = dst_s[r];
      uint4 hv = *(const uint4*)(hs + (size_t)s * 64 + cg * 8);
      uint4 dv = *(const uint4*)(hd + (size_t)d * 64 + cg * 8);
      float fo[8];
      fo[0] = acc[i][0] + bf2f(hv.x & 0xffff) + bf2f(dv.x & 0xffff) + bv[0];
      fo[1] = acc[i][1] + bf2f(hv.x >> 16)    + bf2f(dv.x >> 16)    + bv[1];
      fo[2] = acc[i][2] + bf2f(hv.y & 0xffff) + bf2f(dv.y & 0xffff) + bv[2];
      fo[3] = acc[i][3] + bf2f(hv.y >> 16)    + bf2f(dv.y >> 16)    + bv[3];
      fo[4] = acc[i][4] + bf2f(hv.z & 0xffff) + bf2f(dv.z & 0xffff) + bv[4];
      fo[5] = acc[i][5] + bf2f(hv.z >> 16)    + bf2f(dv.z >> 16)    + bv[5];
      fo[6] = acc[i][6] + bf2f(hv.w & 0xffff) + bf2f(dv.w & 0xffff) + bv[6];
      fo[7] = acc[i][7] + bf2f(hv.w >> 16)    + bf2f(dv.w >> 16)    + bv[7];
      float p = 0.f;
#pragma unroll
      for (int j = 0; j < 8; ++j) {
        fo[j] = fo[j] >= 0.f ? fo[j] : 0.01f * fo[j];  // LeakyReLU
        p = fmaf(fo[j], av[j], p);
      }
      if (STORE) {
        uint4 pv;
        pv.x = pack2(fo[0], fo[1]);
        pv.y = pack2(fo[2], fo[3]);
        pv.z = pack2(fo[4], fo[5]);
        pv.w = pack2(fo[6], fo[7]);
        *(uint4*)(fstore + (size_t)r * 64 + cg * 8) = pv;
      }
      p += __shfl_xor(p, 1, 64);
      p += __shfl_xor(p, 2, 64);
      p += __shfl_xor(p, 4, 64);
      if (cg == 0) logit[r] = p;
    }
  }
}

// ---------------- EGAT: gather-aggregate, no max pre-pass (logits ~O(1), exp f32-safe) ---
__global__ __launch_bounds__(256, 4) void agg_gather_kernel(
    const ush* __restrict__ hn, const float* __restrict__ logit, const int* __restrict__ rowptr,
    const int* __restrict__ deg, const int* __restrict__ src_s, float* __restrict__ hnew) {
  int wave = (blockIdx.x * blockDim.x + threadIdx.x) >> 6;
  int lane = threadIdx.x & 63;
  if (wave >= NN) return;
  int n = wave, d = deg[n], r0 = rowptr[n];
  if (d == 0) {
    hnew[(size_t)n * 64 + lane] = 0.f;
    return;
  }
  float sum = 0.f, acc0 = 0.f, acc1 = 0.f, acc2 = 0.f, acc3 = 0.f;
  int j = 0;
  for (; j + 3 < d; j += 4) {
    int jj = r0 + j;
    int s0 = src_s[jj + 0], s1 = src_s[jj + 1], s2 = src_s[jj + 2], s3 = src_s[jj + 3];
    float l0 = logit[jj + 0], l1 = logit[jj + 1], l2 = logit[jj + 2], l3 = logit[jj + 3];
    ush h0 = hn[(size_t)s0 * 64 + lane];
    ush h1 = hn[(size_t)s1 * 64 + lane];
    ush h2 = hn[(size_t)s2 * 64 + lane];
    ush h3 = hn[(size_t)s3 * 64 + lane];
    float w0 = __expf(l0), w1 = __expf(l1);
    float w2 = __expf(l2), w3 = __expf(l3);
    sum += (w0 + w1) + (w2 + w3);
    acc0 = fmaf(w0, bf2f(h0), acc0);
    acc1 = fmaf(w1, bf2f(h1), acc1);
    acc2 = fmaf(w2, bf2f(h2), acc2);
    acc3 = fmaf(w3, bf2f(h3), acc3);
  }
  for (; j < d; ++j) {
    int jj = r0 + j;
    float w = __expf(logit[jj]);
    sum += w;
    acc0 = fmaf(w, bf2f(hn[(size_t)src_s[jj] * 64 + lane]), acc0);
  }
  hnew[(size_t)n * 64 + lane] = ((acc0 + acc1) + (acc2 + acc3)) / sum;
}

// ---------------- NNConv phase A: per-node outer-product G accumulate (registers only) ---
__global__ __launch_bounds__(256, 4) void nnconv_G_kernel(
    const float* __restrict__ face, const float* __restrict__ ef_s,
    const int* __restrict__ rowptr, const int* __restrict__ deg, const int* __restrict__ src_s,
    ush* __restrict__ G) {
  int wave = (blockIdx.x * blockDim.x + threadIdx.x) >> 6;
  int lane = threadIdx.x & 63;
  if (wave >= NN) return;
  int n = wave, d = deg[n], r0 = rowptr[n];
  int k4 = lane >> 2, ib = lane & 3;
  float g[8], fs[8];
#pragma unroll
  for (int u = 0; u < 8; ++u) { g[u] = 0.f; fs[u] = 0.f; }
  int j = 0;
  for (; j + 1 < d; j += 2) {
    int jj = r0 + j;
    int s0 = src_s[jj], s1 = src_s[jj + 1];
    float ev0 = ef_s[(size_t)jj * 16 + k4];
    float ev1 = ef_s[(size_t)(jj + 1) * 16 + k4];
    const float4* fp0 = (const float4*)(face + (size_t)s0 * 32 + ib * 8);
    const float4* fp1 = (const float4*)(face + (size_t)s1 * 32 + ib * 8);
    float4 fa0 = fp0[0], fb0 = fp0[1];
    float4 fa1 = fp1[0], fb1 = fp1[1];
    g[0] = fmaf(ev0, fa0.x, g[0]); g[1] = fmaf(ev0, fa0.y, g[1]);
    g[2] = fmaf(ev0, fa0.z, g[2]); g[3] = fmaf(ev0, fa0.w, g[3]);
    g[4] = fmaf(ev0, fb0.x, g[4]); g[5] = fmaf(ev0, fb0.y, g[5]);
    g[6] = fmaf(ev0, fb0.z, g[6]); g[7] = fmaf(ev0, fb0.w, g[7]);
    g[0] = fmaf(ev1, fa1.x, g[0]); g[1] = fmaf(ev1, fa1.y, g[1]);
    g[2] = fmaf(ev1, fa1.z, g[2]); g[3] = fmaf(ev1, fa1.w, g[3]);
    g[4] = fmaf(ev1, fb1.x, g[4]); g[5] = fmaf(ev1, fb1.y, g[5]);
    g[6] = fmaf(ev1, fb1.z, g[6]); g[7] = fmaf(ev1, fb1.w, g[7]);
    if (k4 == 0) {
      fs[0] += fa0.x + fa1.x; fs[1] += fa0.y + fa1.y;
      fs[2] += fa0.z + fa1.z; fs[3] += fa0.w + fa1.w;
      fs[4] += fb0.x + fb1.x; fs[5] += fb0.y + fb1.y;
      fs[6] += fb0.z + fb1.z; fs[7] += fb0.w + fb1.w;
    }
  }
  if (j < d) {
    int jj = r0 + j;
    int s0 = src_s[jj];
    float ev0 = ef_s[(size_t)jj * 16 + k4];
    const float4* fp0 = (const float4*)(face + (size_t)s0 * 32 + ib * 8);
    float4 fa0 = fp0[0], fb0 = fp0[1];
    g[0] = fmaf(ev0, fa0.x, g[0]); g[1] = fmaf(ev0, fa0.y, g[1]);
    g[2] = fmaf(ev0, fa0.z, g[2]); g[3] = fmaf(ev0, fa0.w, g[3]);
    g[4] = fmaf(ev0, fb0.x, g[4]); g[5] = fmaf(ev0, fb0.y, g[5]);
    g[6] = fmaf(ev0, fb0.z, g[6]); g[7] = fmaf(ev0, fb0.w, g[7]);
    if (k4 == 0) {
      fs[0] += fa0.x; fs[1] += fa0.y; fs[2] += fa0.z; fs[3] += fa0.w;
      fs[4] += fb0.x; fs[5] += fb0.y; fs[6] += fb0.z; fs[7] += fb0.w;
    }
  }
  uint4 pv;
  pv.x = pack2(g[0], g[1]); pv.y = pack2(g[2], g[3]);
  pv.z = pack2(g[4], g[5]); pv.w = pack2(g[6], g[7]);
  *(uint4*)(G + (size_t)n * 544 + lane * 8) = pv;
  if (k4 == 0) {
    uint4 fv;
    fv.x = pack2(fs[0], fs[1]); fv.y = pack2(fs[2], fs[3]);
    fv.z = pack2(fs[4], fs[5]); fv.w = pack2(fs[6], fs[7]);
    *(uint4*)(G + (size_t)n * 544 + 512 + ib * 8) = fv;
  }
}

// ---------------- NNConv phase B: sArr = G(NNx544) @ W2bf(544x32) ----------------
// 64-row tiles (938 blocks), W fully LDS-resident as bf16, sA bf16 [64][72].
__global__ __launch_bounds__(256, 3) void gemm_G_kernel(const ush* __restrict__ G,
                                                        const ush* __restrict__ W2bf,
                                                        float* __restrict__ sArr, int rows) {
  __shared__ ush sW[544 * 32];  // 34816 B
  __shared__ ush sA[64][72];    // 9216 B
  int t = threadIdx.x;
  int r0 = blockIdx.x * 64;
  for (int i = t; i < 544 * 32 / 8; i += 256) ((uint4*)sW)[i] = ((const uint4*)W2bf)[i];
  int rg = t >> 3, cg = t & 7;  // rg: 32 row-groups of 2; cg: 8 col-groups of 4
  float acc[2][4];
#pragma unroll
  for (int i = 0; i < 2; ++i)
#pragma unroll
    for (int jc = 0; jc < 4; ++jc) acc[i][jc] = 0.f;
  for (int kc = 0; kc < 9; ++kc) {
    int width = (kc == 8) ? 32 : 64;
    __syncthreads();
    int nv = 64 * (width / 8);
    for (int i = t; i < nv; i += 256) {
      int rr = i / (width / 8), cc = i % (width / 8);
      uint4 v = (r0 + rr < rows)
                    ? *(const uint4*)(G + (size_t)(r0 + rr) * 544 + kc * 64 + cc * 8)
                    : make_uint4(0, 0, 0, 0);
      *(uint4*)&sA[rr][cc * 8] = v;
    }
    __syncthreads();
    for (int k = 0; k < width; ++k) {
      int kg = kc * 64 + k;
      float a0 = bf2f(sA[rg * 2 + 0][k]);
      float a1 = bf2f(sA[rg * 2 + 1][k]);
      const ush* wp = &sW[(size_t)kg * 32 + cg * 4];
      float w0 = bf2f(wp[0]), w1 = bf2f(wp[1]), w2 = bf2f(wp[2]), w3 = bf2f(wp[3]);
      acc[0][0] = fmaf(a0, w0, acc[0][0]); acc[0][1] = fmaf(a0, w1, acc[0][1]);
      acc[0][2] = fmaf(a0, w2, acc[0][2]); acc[0][3] = fmaf(a0, w3, acc[0][3]);
      acc[1][0] = fmaf(a1, w0, acc[1][0]); acc[1][1] = fmaf(a1, w1, acc[1][1]);
      acc[1][2] = fmaf(a1, w2, acc[1][2]); acc[1][3] = fmaf(a1, w3, acc[1][3]);
    }
  }
#pragma unroll
  for (int i = 0; i < 2; ++i) {
    int r = r0 + rg * 2 + i;
    if (r < rows)
      *(float4*)(sArr + (size_t)r * 32 + cg * 4) =
          make_float4(acc[i][0], acc[i][1], acc[i][2], acc[i][3]);
  }
}

// ---------------- combine node_features + gate logit (fused; wave per node) --------------
__global__ void combine_gate_kernel(const float* __restrict__ hfin, const float* __restrict__ sArr,
                                    const int* __restrict__ deg, const float* __restrict__ nn_bias,
                                    const float* __restrict__ gate_w, const float* __restrict__ gate_b,
                                    float* __restrict__ out, float* __restrict__ g) {
  int wave = (blockIdx.x * blockDim.x + threadIdx.x) >> 6;
  int lane = threadIdx.x & 63;
  if (wave >= NN) return;
  int n = wave;
  float v0 = hfin[(size_t)n * 64 + lane];
  int c1 = lane + 64;
  float v1 = (c1 < 96)
                 ? sArr[(size_t)n * 32 + (c1 - 64)] / fmaxf((float)deg[n], 1.0f) + nn_bias[c1 - 64]
                 : 0.f;
  out[(size_t)n * 128 + lane] = v0;
  out[(size_t)n * 128 + c1] = v1;
  float p = v0 * gate_w[lane] + ((c1 < 96) ? v1 * gate_w[c1] : 0.f);
#pragma unroll
  for (int off = 32; off; off >>= 1) p += __shfl_xor(p, off, 64);
  if (lane == 0) g[n] = p + gate_b[0];
}

// ---------------- max over g (block-reduced, 1 atomic per block) ----------------
__global__ void gate_max_kernel(const float* __restrict__ g, unsigned* __restrict__ gmax) {
  int tid = blockIdx.x * blockDim.x + threadIdx.x;
  int stride = gridDim.x * blockDim.x;
  float v = -3.0e38f;
  for (int n = tid; n < NN; n += stride) v = fmaxf(v, g[n]);
#pragma unroll
  for (int off = 32; off; off >>= 1) v = fmaxf(v, __shfl_xor(v, off, 64));
  __shared__ float sm[4];
  int lane = threadIdx.x & 63, wid = threadIdx.x >> 6;
  if (lane == 0) sm[wid] = v;
  __syncthreads();
  if (threadIdx.x == 0) {
    float m = fmaxf(fmaxf(sm[0], sm[1]), fmaxf(sm[2], sm[3]));
    atomicMax(gmax, ord_enc(m));
  }
}

// ---------------- pooling: exp + weighted accumulate (fused) ----------------
__global__ void pool_exp_kernel(const float* __restrict__ nf, const float* __restrict__ g,
                                const unsigned* __restrict__ gmax, float* __restrict__ gacc,
                                float* __restrict__ gsum) {
  int o = threadIdx.x;  // blockDim = 128
  float m = ord_dec(*gmax);
  float acc = 0.f, ws = 0.f;
  for (int n = blockIdx.x; n < NN; n += gridDim.x) {
    float w = __expf(g[n] - m);
    ws += w;
    acc += w * nf[(size_t)n * 128 + o];
  }
  atomicAdd(gacc + o, acc);
  if (o == 0) atomicAdd(gsum, ws);
}

__global__ void finalize_kernel(const float* __restrict__ gacc, const float* __restrict__ gsum,
                                float* __restrict__ out) {
  int o = threadIdx.x;
  if (o < 128) out[(size_t)NN * 128 + o] = gacc[o] / gsum[0];
}

extern "C" void kernel_launch(void* const* d_in, const int* in_sizes, int n_in,
                              void* d_out, int out_size, void* d_ws, size_t ws_size,
                              hipStream_t stream) {
  const float* face    = (const float*)d_in[0];
  const float* ef      = (const float*)d_in[1];
  const float* fp_w    = (const float*)d_in[2];
  const float* fp_b    = (const float*)d_in[3];
  const float* ep_w    = (const float*)d_in[4];
  const float* ep_b    = (const float*)d_in[5];
  const float* nn_w    = (const float*)d_in[6];
  const float* nn_b    = (const float*)d_in[7];
  const float* nn_bias = (const float*)d_in[8];
  const float* gate_w  = (const float*)d_in[9];
  const float* gate_b  = (const float*)d_in[10];
  const int*   src     = (const int*)d_in[11];
  const int*   dst     = (const int*)d_in[12];
  const float* e1_attn = (const float*)d_in[17];
  const float* e2_ni   = (const float*)d_in[19];
  const float* e2_nj   = (const float*)d_in[20];
  const float* e2_fij  = (const float*)d_in[21];
  const float* e2_node = (const float*)d_in[22];
  const float* e2_attn = (const float*)d_in[23];
  const float* e2_bias = (const float*)d_in[24];
  float* out = (float*)d_out;

  char* p = (char*)d_ws;
  auto alloc = [&](size_t nfloats) {
    float* r = (float*)p;
    p += ((nfloats * 4 + 255) / 256) * 256;
    return r;
  };
  float* h0 = alloc((size_t)NN * 64);   // layer-2 output
  float* h1 = alloc((size_t)NN * 64);   // layer-1 output
  // big region: G (NN*544 bf16 = 65.28 MB) aliases hs16|hd16|hn16|f116|logit (dead post-EGAT)
  char* bigreg = p;
  ush* hs16 = (ush*)alloc((size_t)NN * 32);   // NN*64 bf16
  ush* hd16 = (ush*)alloc((size_t)NN * 32);
  ush* hn16 = (ush*)alloc((size_t)NN * 32);
  ush* f116 = (ush*)alloc((size_t)NE * 32);   // NE*64 bf16 (dst-sorted order)
  float* logit = alloc(NE);                   // dst-sorted order
  {  // pad bigreg to >= NN*544*2 bytes for G
    size_t used = (size_t)(p - bigreg);
    size_t need = (size_t)NN * 544 * 2;
    if (used < need) p += ((need - used + 255) / 256) * 256;
  }
  ush* G = (ush*)bigreg;
  float* sArr  = alloc((size_t)NN * 32);
  float* g     = alloc(NN);
  float* gacc  = alloc(128);
  float* gsum  = alloc(1);
  unsigned* gmax = (unsigned*)alloc(1);
  float* fold  = alloc(7424);
  ush* W2bf    = (ush*)alloc(544 * 16);       // 544*32 bf16
  // dst-CSR
  int* deg    = (int*)alloc(NN);
  int* rowptr = (int*)alloc(NN);
  int* cursor = (int*)alloc(NN);
  int* partial = (int*)alloc(256);
  int* src_s  = (int*)alloc(NE);
  int* dst_s  = (int*)alloc(NE);
  float* ef_s = alloc((size_t)NE * 16);       // permuted edge features

  const float* Wf1  = fold;
  const float* b1f  = fold + 1024;
  const float* Wni1 = fold + 1088;
  const float* Wnj1 = fold + 3136;
  const float* Wno1 = fold + 5184;
  const float* bni1 = fold + 7232;
  const float* bnj1 = fold + 7296;
  const float* bno1 = fold + 7360;

  const int B = 256;
  const int NGB = cdiv(NN, 128);
  const int EGB = cdiv(NE, 128);
  const int NB256 = cdiv(NN, 256);

  // ---- CSR build (dst-sorted) + fused edge permutation ----
  hipMemsetAsync(deg, 0, NN * 4, stream);
  deg_kernel<<<cdiv(NE, B), B, 0, stream>>>(dst, deg);
  scan1_kernel<<<NB256, 256, 0, stream>>>(deg, rowptr, partial);
  scan2_kernel<<<1, 256, 0, stream>>>(partial, NB256);
  scan3_kernel<<<NB256, 256, 0, stream>>>(rowptr, partial, cursor);
  scatter_dst_kernel<<<cdiv(NE, B), B, 0, stream>>>(src, dst, ef, cursor, src_s, dst_s, ef_s);

  // folded weights + nn weight pack (tiny)
  fold_kernel<<<29, B, 0, stream>>>(fp_w, fp_b, ep_w, ep_b,
                                    (const float*)d_in[15], (const float*)d_in[18],
                                    (const float*)d_in[13], (const float*)d_in[14],
                                    (const float*)d_in[16], fold);
  nnwt_kernel<<<68, B, 0, stream>>>(nn_w, nn_b, W2bf);

  // ---- EGAT layer 1 (edges processed in dst-sorted order) ----
  gemm3_kernel<32, true><<<dim3(NGB, 3), B, 0, stream>>>(face, Wni1, Wnj1, Wno1, bni1, bnj1,
                                                         bno1, hs16, hd16, hn16, NN);
  gemm_fout_kernel<16, true, false><<<EGB, B, 0, stream>>>(ef_s, Wf1, b1f, hs16, hd16, src_s,
                                                           dst_s, e1_attn, f116, logit);
  agg_gather_kernel<<<cdiv(NN * 64, B), B, 0, stream>>>(hn16, logit, rowptr, deg, src_s, h1);

  // ---- EGAT layer 2 ----
  gemm3_kernel<64, false><<<dim3(NGB, 3), B, 0, stream>>>(h1, e2_ni, e2_nj, e2_node, nullptr,
                                                          nullptr, nullptr, hs16, hd16, hn16, NN);
  gemm_fout_kernel<64, false, true><<<EGB, B, 0, stream>>>(f116, e2_fij, e2_bias, hs16, hd16,
                                                           src_s, dst_s, e2_attn, nullptr, logit);
  agg_gather_kernel<<<cdiv(NN * 64, B), B, 0, stream>>>(hn16, logit, rowptr, deg, src_s, h0);

  // ---- NNConv (outer-product form; G aliases dead EGAT buffers — runs after EGAT) ----
  nnconv_G_kernel<<<cdiv(NN * 64, B), B, 0, stream>>>(face, ef_s, rowptr, deg, src_s, G);
  gemm_G_kernel<<<cdiv(NN, 64), B, 0, stream>>>(G, W2bf, sArr, NN);

  // ---- combine node features + gate logits ----
  hipMemsetAsync(gacc, 0, 128 * 4, stream);
  hipMemsetAsync(gsum, 0, 4, stream);
  hipMemsetAsync(gmax, 0, 4, stream);
  combine_gate_kernel<<<cdiv(NN * 64, B), B, 0, stream>>>(h0, sArr, deg, nn_bias, gate_w,
                                                          gate_b, out, g);
  gate_max_kernel<<<128, B, 0, stream>>>(g, gmax);
  pool_exp_kernel<<<512, 128, 0, stream>>>(out, g, gmax, gacc, gsum);
  finalize_kernel<<<1, 128, 0, stream>>>(gacc, gsum, out);
}

// Round 18
// 372.399 us; speedup vs baseline: 1.0793x; 1.0793x over previous
//
#include <hip/hip_runtime.h>

#define NN 60000
#define NE 300000
typedef unsigned short ush;

static inline int cdiv(int a, int b) { return (a + b - 1) / b; }

__device__ inline unsigned ord_enc(float x) {
  unsigned u = __float_as_uint(x);
  return (u & 0x80000000u) ? ~u : (u | 0x80000000u);
}
__device__ inline float ord_dec(unsigned u) {
  return __uint_as_float((u & 0x80000000u) ? (u & 0x7fffffffu) : ~u);
}
__device__ inline float bf2f(unsigned u16) { return __uint_as_float(u16 << 16); }
__device__ inline ush f2bf(float x) {
  unsigned u = __float_as_uint(x);
  return (ush)((u + 0x7FFFu + ((u >> 16) & 1u)) >> 16);
}
__device__ inline unsigned pack2(float lo, float hi) {
  return ((unsigned)f2bf(hi) << 16) | (unsigned)f2bf(lo);
}

// ================= CSR build (dst-sorted) =================
__global__ void deg_kernel(const int* __restrict__ key, int* __restrict__ deg) {
  int e = blockIdx.x * blockDim.x + threadIdx.x;
  if (e < NE) atomicAdd(deg + key[e], 1);
}

__global__ void scan1_kernel(const int* __restrict__ deg, int* __restrict__ rowptr,
                             int* __restrict__ partial) {
  __shared__ int s[256];
  int i = blockIdx.x * 256 + threadIdx.x;
  int v = (i < NN) ? deg[i] : 0;
  s[threadIdx.x] = v;
  __syncthreads();
  for (int off = 1; off < 256; off <<= 1) {
    int t = (threadIdx.x >= off) ? s[threadIdx.x - off] : 0;
    __syncthreads();
    s[threadIdx.x] += t;
    __syncthreads();
  }
  if (i < NN) rowptr[i] = s[threadIdx.x] - v;
  if (threadIdx.x == 255) partial[blockIdx.x] = s[255];
}

__global__ void scan2_kernel(int* __restrict__ partial, int nb) {
  __shared__ int s[256];
  int v = (threadIdx.x < nb) ? partial[threadIdx.x] : 0;
  s[threadIdx.x] = v;
  __syncthreads();
  for (int off = 1; off < 256; off <<= 1) {
    int t = (threadIdx.x >= off) ? s[threadIdx.x - off] : 0;
    __syncthreads();
    s[threadIdx.x] += t;
    __syncthreads();
  }
  if (threadIdx.x < nb) partial[threadIdx.x] = s[threadIdx.x] - v;
}

__global__ void scan3_kernel(int* __restrict__ rowptr, const int* __restrict__ partial,
                             int* __restrict__ cursor) {
  int i = blockIdx.x * 256 + threadIdx.x;
  if (i < NN) {
    int r = rowptr[i] + partial[blockIdx.x];
    rowptr[i] = r;
    cursor[i] = r;
  }
}

// scatter + ef permutation fused (sequential ef read, random 64B write)
__global__ void scatter_dst_kernel(const int* __restrict__ src, const int* __restrict__ dst,
                                   const float* __restrict__ ef, int* __restrict__ cursor,
                                   int* __restrict__ src_s, int* __restrict__ dst_s,
                                   float* __restrict__ ef_s) {
  int e = blockIdx.x * blockDim.x + threadIdx.x;
  if (e >= NE) return;
  int d = dst[e];
  int j = atomicAdd(cursor + d, 1);
  src_s[j] = src[e];
  dst_s[j] = d;
  const float4* ep = (const float4*)(ef + (size_t)e * 16);
  float4 a = ep[0], b = ep[1], c = ep[2], dd = ep[3];
  float4* op = (float4*)(ef_s + (size_t)j * 16);
  op[0] = a; op[1] = b; op[2] = c; op[3] = dd;
}

// ---------------- fold: precompute folded weight products (7424 dots of length 64) -------
__global__ void fold_kernel(const float* __restrict__ fp_w, const float* __restrict__ fp_b,
                            const float* __restrict__ ep_w, const float* __restrict__ ep_b,
                            const float* __restrict__ fij, const float* __restrict__ ebias,
                            const float* __restrict__ ni, const float* __restrict__ nj,
                            const float* __restrict__ node, float* __restrict__ fold) {
  int t = blockIdx.x * blockDim.x + threadIdx.x;
  if (t >= 7424) return;
  int o = t & 63;
  const float* A;
  const float* B;
  float init = 0.f;
  if (t < 1024)      { A = ep_w + (size_t)(t >> 6) * 64; B = fij + o; }
  else if (t < 1088) { A = ep_b; B = fij + o; init = ebias[o]; }
  else if (t < 3136) { A = fp_w + (size_t)((t - 1088) >> 6) * 64; B = ni + o; }
  else if (t < 5184) { A = fp_w + (size_t)((t - 3136) >> 6) * 64; B = nj + o; }
  else if (t < 7232) { A = fp_w + (size_t)((t - 5184) >> 6) * 64; B = node + o; }
  else if (t < 7296) { A = fp_b; B = ni + o; }
  else if (t < 7360) { A = fp_b; B = nj + o; }
  else               { A = fp_b; B = node + o; }
  float a = init;
  for (int i = 0; i < 64; ++i) a = fmaf(A[i], B[(size_t)i * 64], a);
  fold[t] = a;
}

// ---------------- pack nn_w/nn_b -> bf16 W2bf[544][32] ----------------
__global__ void nnwt_kernel(const float* __restrict__ nn_w, const float* __restrict__ nn_b,
                            ush* __restrict__ W2bf) {
  int t = blockIdx.x * blockDim.x + threadIdx.x;
  if (t >= 544 * 32) return;
  int c = t >> 5, o = t & 31;
  float v;
  if (c < 512) {
    int k = c >> 5, i = c & 31;
    v = nn_w[(size_t)k * 1024 + i * 32 + o];
  } else {
    v = nn_b[(c - 512) * 32 + o];
  }
  W2bf[t] = f2bf(v);
}

// ---------------- tiled GEMM (rows x K) @ (K x 64) -> bf16 out; 3 weight sets ------------
template <int K, bool BIAS>
__global__ __launch_bounds__(256, 2) void gemm3_kernel(
    const float* __restrict__ A, const float* __restrict__ W0, const float* __restrict__ W1,
    const float* __restrict__ W2, const float* __restrict__ b0, const float* __restrict__ b1,
    const float* __restrict__ b2, ush* __restrict__ o0, ush* __restrict__ o1,
    ush* __restrict__ o2, int rows) {
  __shared__ float sA[128][K + 1];
  __shared__ float sW[K][64];
  const float* W = blockIdx.y == 0 ? W0 : blockIdx.y == 1 ? W1 : W2;
  const float* bb = blockIdx.y == 0 ? b0 : blockIdx.y == 1 ? b1 : b2;
  ush* out = blockIdx.y == 0 ? o0 : blockIdx.y == 1 ? o1 : o2;
  int t = threadIdx.x;
  int r0 = blockIdx.x * 128;
  for (int i = t; i < K * 16; i += 256) ((float4*)sW)[i] = ((const float4*)W)[i];
  for (int i = t; i < 128 * (K / 4); i += 256) {
    int rr = i / (K / 4), cc = i % (K / 4);
    float4 v = (r0 + rr < rows) ? ((const float4*)(A + (size_t)(r0 + rr) * K))[cc]
                                : make_float4(0.f, 0.f, 0.f, 0.f);
    sA[rr][cc * 4 + 0] = v.x;
    sA[rr][cc * 4 + 1] = v.y;
    sA[rr][cc * 4 + 2] = v.z;
    sA[rr][cc * 4 + 3] = v.w;
  }
  __syncthreads();
  int rg = t >> 3, cg = t & 7;
  float acc[4][8];
#pragma unroll
  for (int i = 0; i < 4; ++i)
#pragma unroll
    for (int j = 0; j < 8; ++j) acc[i][j] = 0.f;
#pragma unroll 8
  for (int k = 0; k < K; ++k) {
    float a0 = sA[rg * 4 + 0][k], a1 = sA[rg * 4 + 1][k];
    float a2 = sA[rg * 4 + 2][k], a3 = sA[rg * 4 + 3][k];
    float4 wA = *(const float4*)&sW[k][cg * 8];
    float4 wB = *(const float4*)&sW[k][cg * 8 + 4];
#pragma unroll
    for (int i = 0; i < 4; ++i) {
      float a = i == 0 ? a0 : i == 1 ? a1 : i == 2 ? a2 : a3;
      acc[i][0] = fmaf(a, wA.x, acc[i][0]); acc[i][1] = fmaf(a, wA.y, acc[i][1]);
      acc[i][2] = fmaf(a, wA.z, acc[i][2]); acc[i][3] = fmaf(a, wA.w, acc[i][3]);
      acc[i][4] = fmaf(a, wB.x, acc[i][4]); acc[i][5] = fmaf(a, wB.y, acc[i][5]);
      acc[i][6] = fmaf(a, wB.z, acc[i][6]); acc[i][7] = fmaf(a, wB.w, acc[i][7]);
    }
  }
  float bv[8];
#pragma unroll
  for (int j = 0; j < 8; ++j) bv[j] = BIAS ? bb[cg * 8 + j] : 0.f;
#pragma unroll
  for (int i = 0; i < 4; ++i) {
    int r = r0 + rg * 4 + i;
    if (r < rows) {
      uint4 pv;
      pv.x = pack2(acc[i][0] + bv[0], acc[i][1] + bv[1]);
      pv.y = pack2(acc[i][2] + bv[2], acc[i][3] + bv[3]);
      pv.z = pack2(acc[i][4] + bv[4], acc[i][5] + bv[5]);
      pv.w = pack2(acc[i][6] + bv[6], acc[i][7] + bv[7]);
      *(uint4*)(out + (size_t)r * 64 + cg * 8) = pv;
    }
  }
}

// ---------------- edge GEMM + fused f_out epilogue (edges in dst-sorted order) -----------
template <int K, bool STORE, bool ABF>
__global__ __launch_bounds__(256, 2) void gemm_fout_kernel(
    const void* __restrict__ Ap, const float* __restrict__ W, const float* __restrict__ bias,
    const ush* __restrict__ hs, const ush* __restrict__ hd, const int* __restrict__ src_s,
    const int* __restrict__ dst_s, const float* __restrict__ attn, ush* __restrict__ fstore,
    float* __restrict__ logit) {
  __shared__ float sA[128][K + 1];
  __shared__ float sW[K][64];
  int t = threadIdx.x;
  int r0 = blockIdx.x * 128;
  for (int i = t; i < K * 16; i += 256) ((float4*)sW)[i] = ((const float4*)W)[i];
  if (ABF) {
    const ush* A = (const ush*)Ap;
    for (int i = t; i < 128 * (K / 8); i += 256) {
      int rr = i / (K / 8), cc = i % (K / 8);
      uint4 v = (r0 + rr < NE) ? ((const uint4*)(A + (size_t)(r0 + rr) * K))[cc]
                               : make_uint4(0, 0, 0, 0);
      float* dp = &sA[rr][cc * 8];
      dp[0] = bf2f(v.x & 0xffff); dp[1] = bf2f(v.x >> 16);
      dp[2] = bf2f(v.y & 0xffff); dp[3] = bf2f(v.y >> 16);
      dp[4] = bf2f(v.z & 0xffff); dp[5] = bf2f(v.z >> 16);
      dp[6] = bf2f(v.w & 0xffff); dp[7] = bf2f(v.w >> 16);
    }
  } else {
    const float* A = (const float*)Ap;
    for (int i = t; i < 128 * (K / 4); i += 256) {
      int rr = i / (K / 4), cc = i % (K / 4);
      float4 v = (r0 + rr < NE) ? ((const float4*)(A + (size_t)(r0 + rr) * K))[cc]
                                : make_float4(0.f, 0.f, 0.f, 0.f);
      sA[rr][cc * 4 + 0] = v.x;
      sA[rr][cc * 4 + 1] = v.y;
      sA[rr][cc * 4 + 2] = v.z;
      sA[rr][cc * 4 + 3] = v.w;
    }
  }
  __syncthreads();
  int rg = t >> 3, cg = t & 7;
  float acc[4][8];
#pragma unroll
  for (int i = 0; i < 4; ++i)
#pragma unroll
    for (int j = 0; j < 8; ++j) acc[i][j] = 0.f;
#pragma unroll 8
  for (int k = 0; k < K; ++k) {
    float a0 = sA[rg * 4 + 0][k], a1 = sA[rg * 4 + 1][k];
    float a2 = sA[rg * 4 + 2][k], a3 = sA[rg * 4 + 3][k];
    float4 wA = *(const float4*)&sW[k][cg * 8];
    float4 wB = *(const float4*)&sW[k][cg * 8 + 4];
#pragma unroll
    for (int i = 0; i < 4; ++i) {
      float a = i == 0 ? a0 : i == 1 ? a1 : i == 2 ? a2 : a3;
      acc[i][0] = fmaf(a, wA.x, acc[i][0]); acc[i][1] = fmaf(a, wA.y, acc[i][1]);
      acc[i][2] = fmaf(a, wA.z, acc[i][2]); acc[i][3] = fmaf(a, wA.w, acc[i][3]);
      acc[i][4] = fmaf(a, wB.x, acc[i][4]); acc[i][5] = fmaf(a, wB.y, acc[i][5]);
      acc[i][6] = fmaf(a, wB.z, acc[i][6]); acc[i][7] = fmaf(a, wB.w, acc[i][7]);
    }
  }
  float bv[8], av[8];
#pragma unroll
  for (int j = 0; j < 8; ++j) {
    bv[j] = bias[cg * 8 + j];
    av[j] = attn[cg * 8 + j];
  }
#pragma unroll
  for (int i = 0; i < 4; ++i) {
    int r = r0 + rg * 4 + i;
    if (r < NE) {
      int s = src_s[r], d = dst_s[r];
      uint4 hv = *(const uint4*)(hs + (size_t)s * 64 + cg * 8);
      uint4 dv = *(const uint4*)(hd + (size_t)d * 64 + cg * 8);
      float fo[8];
      fo[0] = acc[i][0] + bf2f(hv.x & 0xffff) + bf2f(dv.x & 0xffff) + bv[0];
      fo[1] = acc[i][1] + bf2f(hv.x >> 16)    + bf2f(dv.x >> 16)    + bv[1];
      fo[2] = acc[i][2] + bf2f(hv.y & 0xffff) + bf2f(dv.y & 0xffff) + bv[2];
      fo[3] = acc[i][3] + bf2f(hv.y >> 16)    + bf2f(dv.y >> 16)    + bv[3];
      fo[4] = acc[i][4] + bf2f(hv.z & 0xffff) + bf2f(dv.z & 0xffff) + bv[4];
      fo[5] = acc[i][5] + bf2f(hv.z >> 16)    + bf2f(dv.z >> 16)    + bv[5];
      fo[6] = acc[i][6] + bf2f(hv.w & 0xffff) + bf2f(dv.w & 0xffff) + bv[6];
      fo[7] = acc[i][7] + bf2f(hv.w >> 16)    + bf2f(dv.w >> 16)    + bv[7];
      float p = 0.f;
#pragma unroll
      for (int j = 0; j < 8; ++j) {
        fo[j] = fo[j] >= 0.f ? fo[j] : 0.01f * fo[j];  // LeakyReLU
        p = fmaf(fo[j], av[j], p);
      }
      if (STORE) {
        uint4 pv;
        pv.x = pack2(fo[0], fo[1]);
        pv.y = pack2(fo[2], fo[3]);
        pv.z = pack2(fo[4], fo[5]);
        pv.w = pack2(fo[6], fo[7]);
        *(uint4*)(fstore + (size_t)r * 64 + cg * 8) = pv;
      }
      p += __shfl_xor(p, 1, 64);
      p += __shfl_xor(p, 2, 64);
      p += __shfl_xor(p, 4, 64);
      if (cg == 0) logit[r] = p;
    }
  }
}

// ---------------- EGAT: gather-aggregate, no max pre-pass (logits ~O(1), exp f32-safe) ---
__global__ __launch_bounds__(256, 4) void agg_gather_kernel(
    const ush* __restrict__ hn, const float* __restrict__ logit, const int* __restrict__ rowptr,
    const int* __restrict__ deg, const int* __restrict__ src_s, float* __restrict__ hnew) {
  int wave = (blockIdx.x * blockDim.x + threadIdx.x) >> 6;
  int lane = threadIdx.x & 63;
  if (wave >= NN) return;
  int n = wave, d = deg[n], r0 = rowptr[n];
  if (d == 0) {
    hnew[(size_t)n * 64 + lane] = 0.f;
    return;
  }
  float sum = 0.f, acc0 = 0.f, acc1 = 0.f, acc2 = 0.f, acc3 = 0.f;
  int j = 0;
  for (; j + 3 < d; j += 4) {
    int jj = r0 + j;
    int s0 = src_s[jj + 0], s1 = src_s[jj + 1], s2 = src_s[jj + 2], s3 = src_s[jj + 3];
    float l0 = logit[jj + 0], l1 = logit[jj + 1], l2 = logit[jj + 2], l3 = logit[jj + 3];
    ush h0 = hn[(size_t)s0 * 64 + lane];
    ush h1 = hn[(size_t)s1 * 64 + lane];
    ush h2 = hn[(size_t)s2 * 64 + lane];
    ush h3 = hn[(size_t)s3 * 64 + lane];
    float w0 = __expf(l0), w1 = __expf(l1);
    float w2 = __expf(l2), w3 = __expf(l3);
    sum += (w0 + w1) + (w2 + w3);
    acc0 = fmaf(w0, bf2f(h0), acc0);
    acc1 = fmaf(w1, bf2f(h1), acc1);
    acc2 = fmaf(w2, bf2f(h2), acc2);
    acc3 = fmaf(w3, bf2f(h3), acc3);
  }
  for (; j < d; ++j) {
    int jj = r0 + j;
    float w = __expf(logit[jj]);
    sum += w;
    acc0 = fmaf(w, bf2f(hn[(size_t)src_s[jj] * 64 + lane]), acc0);
  }
  hnew[(size_t)n * 64 + lane] = ((acc0 + acc1) + (acc2 + acc3)) / sum;
}

// ---------------- NNConv phase A: per-node outer-product G accumulate (registers only) ---
__global__ __launch_bounds__(256, 4) void nnconv_G_kernel(
    const float* __restrict__ face, const float* __restrict__ ef_s,
    const int* __restrict__ rowptr, const int* __restrict__ deg, const int* __restrict__ src_s,
    ush* __restrict__ G) {
  int wave = (blockIdx.x * blockDim.x + threadIdx.x) >> 6;
  int lane = threadIdx.x & 63;
  if (wave >= NN) return;
  int n = wave, d = deg[n], r0 = rowptr[n];
  int k4 = lane >> 2, ib = lane & 3;
  float g[8], fs[8];
#pragma unroll
  for (int u = 0; u < 8; ++u) { g[u] = 0.f; fs[u] = 0.f; }
  int j = 0;
  for (; j + 1 < d; j += 2) {
    int jj = r0 + j;
    int s0 = src_s[jj], s1 = src_s[jj + 1];
    float ev0 = ef_s[(size_t)jj * 16 + k4];
    float ev1 = ef_s[(size_t)(jj + 1) * 16 + k4];
    const float4* fp0 = (const float4*)(face + (size_t)s0 * 32 + ib * 8);
    const float4* fp1 = (const float4*)(face + (size_t)s1 * 32 + ib * 8);
    float4 fa0 = fp0[0], fb0 = fp0[1];
    float4 fa1 = fp1[0], fb1 = fp1[1];
    g[0] = fmaf(ev0, fa0.x, g[0]); g[1] = fmaf(ev0, fa0.y, g[1]);
    g[2] = fmaf(ev0, fa0.z, g[2]); g[3] = fmaf(ev0, fa0.w, g[3]);
    g[4] = fmaf(ev0, fb0.x, g[4]); g[5] = fmaf(ev0, fb0.y, g[5]);
    g[6] = fmaf(ev0, fb0.z, g[6]); g[7] = fmaf(ev0, fb0.w, g[7]);
    g[0] = fmaf(ev1, fa1.x, g[0]); g[1] = fmaf(ev1, fa1.y, g[1]);
    g[2] = fmaf(ev1, fa1.z, g[2]); g[3] = fmaf(ev1, fa1.w, g[3]);
    g[4] = fmaf(ev1, fb1.x, g[4]); g[5] = fmaf(ev1, fb1.y, g[5]);
    g[6] = fmaf(ev1, fb1.z, g[6]); g[7] = fmaf(ev1, fb1.w, g[7]);
    if (k4 == 0) {
      fs[0] += fa0.x + fa1.x; fs[1] += fa0.y + fa1.y;
      fs[2] += fa0.z + fa1.z; fs[3] += fa0.w + fa1.w;
      fs[4] += fb0.x + fb1.x; fs[5] += fb0.y + fb1.y;
      fs[6] += fb0.z + fb1.z; fs[7] += fb0.w + fb1.w;
    }
  }
  if (j < d) {
    int jj = r0 + j;
    int s0 = src_s[jj];
    float ev0 = ef_s[(size_t)jj * 16 + k4];
    const float4* fp0 = (const float4*)(face + (size_t)s0 * 32 + ib * 8);
    float4 fa0 = fp0[0], fb0 = fp0[1];
    g[0] = fmaf(ev0, fa0.x, g[0]); g[1] = fmaf(ev0, fa0.y, g[1]);
    g[2] = fmaf(ev0, fa0.z, g[2]); g[3] = fmaf(ev0, fa0.w, g[3]);
    g[4] = fmaf(ev0, fb0.x, g[4]); g[5] = fmaf(ev0, fb0.y, g[5]);
    g[6] = fmaf(ev0, fb0.z, g[6]); g[7] = fmaf(ev0, fb0.w, g[7]);
    if (k4 == 0) {
      fs[0] += fa0.x; fs[1] += fa0.y; fs[2] += fa0.z; fs[3] += fa0.w;
      fs[4] += fb0.x; fs[5] += fb0.y; fs[6] += fb0.z; fs[7] += fb0.w;
    }
  }
  uint4 pv;
  pv.x = pack2(g[0], g[1]); pv.y = pack2(g[2], g[3]);
  pv.z = pack2(g[4], g[5]); pv.w = pack2(g[6], g[7]);
  *(uint4*)(G + (size_t)n * 544 + lane * 8) = pv;
  if (k4 == 0) {
    uint4 fv;
    fv.x = pack2(fs[0], fs[1]); fv.y = pack2(fs[2], fs[3]);
    fv.z = pack2(fs[4], fs[5]); fv.w = pack2(fs[6], fs[7]);
    *(uint4*)(G + (size_t)n * 544 + 512 + ib * 8) = fv;
  }
}

// ---------------- NNConv phase B: sArr = G(NNx544) @ W2bf(544x32) ----------------
// 64-row tiles (938 blocks), f32 LDS staging, thread tile 2x4, ~24.6 KB LDS.
__global__ __launch_bounds__(256, 4) void gemm_G_kernel(const ush* __restrict__ G,
                                                        const ush* __restrict__ W2bf,
                                                        float* __restrict__ sArr, int rows) {
  __shared__ float sA[64][65];  // 16.64 KB
  __shared__ float sW[64][32];  // 8 KB
  int t = threadIdx.x;
  int r0 = blockIdx.x * 64;
  int rg = t >> 3, cg = t & 7;  // 32 row-groups x 2 rows; 8 col-groups x 4 cols
  float acc[2][4];
#pragma unroll
  for (int i = 0; i < 2; ++i)
#pragma unroll
    for (int jc = 0; jc < 4; ++jc) acc[i][jc] = 0.f;
  for (int kc = 0; kc < 9; ++kc) {
    int width = (kc == 8) ? 32 : 64;
    __syncthreads();
    int nv = 64 * (width / 8);
    for (int i = t; i < nv; i += 256) {
      int rr = i / (width / 8), cc = i % (width / 8);
      uint4 v = (r0 + rr < rows)
                    ? *(const uint4*)(G + (size_t)(r0 + rr) * 544 + kc * 64 + cc * 8)
                    : make_uint4(0, 0, 0, 0);
      float* dp = &sA[rr][cc * 8];
      dp[0] = bf2f(v.x & 0xffff); dp[1] = bf2f(v.x >> 16);
      dp[2] = bf2f(v.y & 0xffff); dp[3] = bf2f(v.y >> 16);
      dp[4] = bf2f(v.z & 0xffff); dp[5] = bf2f(v.z >> 16);
      dp[6] = bf2f(v.w & 0xffff); dp[7] = bf2f(v.w >> 16);
    }
    int nw = width * 4;  // width*32/8 uint4 loads
    for (int i = t; i < nw; i += 256) {
      int kk = i >> 2, cc = i & 3;
      uint4 v = *(const uint4*)(W2bf + (size_t)(kc * 64 + kk) * 32 + cc * 8);
      float* dp = &sW[kk][cc * 8];
      dp[0] = bf2f(v.x & 0xffff); dp[1] = bf2f(v.x >> 16);
      dp[2] = bf2f(v.y & 0xffff); dp[3] = bf2f(v.y >> 16);
      dp[4] = bf2f(v.z & 0xffff); dp[5] = bf2f(v.z >> 16);
      dp[6] = bf2f(v.w & 0xffff); dp[7] = bf2f(v.w >> 16);
    }
    __syncthreads();
#pragma unroll 8
    for (int k = 0; k < width; ++k) {
      float a0 = sA[rg * 2 + 0][k];
      float a1 = sA[rg * 2 + 1][k];
      float4 wv = *(const float4*)&sW[k][cg * 4];
      acc[0][0] = fmaf(a0, wv.x, acc[0][0]); acc[0][1] = fmaf(a0, wv.y, acc[0][1]);
      acc[0][2] = fmaf(a0, wv.z, acc[0][2]); acc[0][3] = fmaf(a0, wv.w, acc[0][3]);
      acc[1][0] = fmaf(a1, wv.x, acc[1][0]); acc[1][1] = fmaf(a1, wv.y, acc[1][1]);
      acc[1][2] = fmaf(a1, wv.z, acc[1][2]); acc[1][3] = fmaf(a1, wv.w, acc[1][3]);
    }
  }
#pragma unroll
  for (int i = 0; i < 2; ++i) {
    int r = r0 + rg * 2 + i;
    if (r < rows)
      *(float4*)(sArr + (size_t)r * 32 + cg * 4) =
          make_float4(acc[i][0], acc[i][1], acc[i][2], acc[i][3]);
  }
}

// ---------------- combine node_features + gate logit (fused; wave per node) --------------
__global__ void combine_gate_kernel(const float* __restrict__ hfin, const float* __restrict__ sArr,
                                    const int* __restrict__ deg, const float* __restrict__ nn_bias,
                                    const float* __restrict__ gate_w, const float* __restrict__ gate_b,
                                    float* __restrict__ out, float* __restrict__ g) {
  int wave = (blockIdx.x * blockDim.x + threadIdx.x) >> 6;
  int lane = threadIdx.x & 63;
  if (wave >= NN) return;
  int n = wave;
  float v0 = hfin[(size_t)n * 64 + lane];
  int c1 = lane + 64;
  float v1 = (c1 < 96)
                 ? sArr[(size_t)n * 32 + (c1 - 64)] / fmaxf((float)deg[n], 1.0f) + nn_bias[c1 - 64]
                 : 0.f;
  out[(size_t)n * 128 + lane] = v0;
  out[(size_t)n * 128 + c1] = v1;
  float p = v0 * gate_w[lane] + ((c1 < 96) ? v1 * gate_w[c1] : 0.f);
#pragma unroll
  for (int off = 32; off; off >>= 1) p += __shfl_xor(p, off, 64);
  if (lane == 0) g[n] = p + gate_b[0];
}

// ---------------- max over g (block-reduced, 1 atomic per block) ----------------
__global__ void gate_max_kernel(const float* __restrict__ g, unsigned* __restrict__ gmax) {
  int tid = blockIdx.x * blockDim.x + threadIdx.x;
  int stride = gridDim.x * blockDim.x;
  float v = -3.0e38f;
  for (int n = tid; n < NN; n += stride) v = fmaxf(v, g[n]);
#pragma unroll
  for (int off = 32; off; off >>= 1) v = fmaxf(v, __shfl_xor(v, off, 64));
  __shared__ float sm[4];
  int lane = threadIdx.x & 63, wid = threadIdx.x >> 6;
  if (lane == 0) sm[wid] = v;
  __syncthreads();
  if (threadIdx.x == 0) {
    float m = fmaxf(fmaxf(sm[0], sm[1]), fmaxf(sm[2], sm[3]));
    atomicMax(gmax, ord_enc(m));
  }
}

// ---------------- pooling: exp + weighted accumulate (fused) ----------------
__global__ void pool_exp_kernel(const float* __restrict__ nf, const float* __restrict__ g,
                                const unsigned* __restrict__ gmax, float* __restrict__ gacc,
                                float* __restrict__ gsum) {
  int o = threadIdx.x;  // blockDim = 128
  float m = ord_dec(*gmax);
  float acc = 0.f, ws = 0.f;
  for (int n = blockIdx.x; n < NN; n += gridDim.x) {
    float w = __expf(g[n] - m);
    ws += w;
    acc += w * nf[(size_t)n * 128 + o];
  }
  atomicAdd(gacc + o, acc);
  if (o == 0) atomicAdd(gsum, ws);
}

__global__ void finalize_kernel(const float* __restrict__ gacc, const float* __restrict__ gsum,
                                float* __restrict__ out) {
  int o = threadIdx.x;
  if (o < 128) out[(size_t)NN * 128 + o] = gacc[o] / gsum[0];
}

extern "C" void kernel_launch(void* const* d_in, const int* in_sizes, int n_in,
                              void* d_out, int out_size, void* d_ws, size_t ws_size,
                              hipStream_t stream) {
  const float* face    = (const float*)d_in[0];
  const float* ef      = (const float*)d_in[1];
  const float* fp_w    = (const float*)d_in[2];
  const float* fp_b    = (const float*)d_in[3];
  const float* ep_w    = (const float*)d_in[4];
  const float* ep_b    = (const float*)d_in[5];
  const float* nn_w    = (const float*)d_in[6];
  const float* nn_b    = (const float*)d_in[7];
  const float* nn_bias = (const float*)d_in[8];
  const float* gate_w  = (const float*)d_in[9];
  const float* gate_b  = (const float*)d_in[10];
  const int*   src     = (const int*)d_in[11];
  const int*   dst     = (const int*)d_in[12];
  const float* e1_attn = (const float*)d_in[17];
  const float* e2_ni   = (const float*)d_in[19];
  const float* e2_nj   = (const float*)d_in[20];
  const float* e2_fij  = (const float*)d_in[21];
  const float* e2_node = (const float*)d_in[22];
  const float* e2_attn = (const float*)d_in[23];
  const float* e2_bias = (const float*)d_in[24];
  float* out = (float*)d_out;

  char* p = (char*)d_ws;
  auto alloc = [&](size_t nfloats) {
    float* r = (float*)p;
    p += ((nfloats * 4 + 255) / 256) * 256;
    return r;
  };
  float* h0 = alloc((size_t)NN * 64);   // layer-2 output
  float* h1 = alloc((size_t)NN * 64);   // layer-1 output
  // big region: G (NN*544 bf16 = 65.28 MB) aliases hs16|hd16|hn16|f116|logit (dead post-EGAT)
  char* bigreg = p;
  ush* hs16 = (ush*)alloc((size_t)NN * 32);   // NN*64 bf16
  ush* hd16 = (ush*)alloc((size_t)NN * 32);
  ush* hn16 = (ush*)alloc((size_t)NN * 32);
  ush* f116 = (ush*)alloc((size_t)NE * 32);   // NE*64 bf16 (dst-sorted order)
  float* logit = alloc(NE);                   // dst-sorted order
  {  // pad bigreg to >= NN*544*2 bytes for G
    size_t used = (size_t)(p - bigreg);
    size_t need = (size_t)NN * 544 * 2;
    if (used < need) p += ((need - used + 255) / 256) * 256;
  }
  ush* G = (ush*)bigreg;
  float* sArr  = alloc((size_t)NN * 32);
  float* g     = alloc(NN);
  float* gacc  = alloc(128);
  float* gsum  = alloc(1);
  unsigned* gmax = (unsigned*)alloc(1);
  float* fold  = alloc(7424);
  ush* W2bf    = (ush*)alloc(544 * 16);       // 544*32 bf16
  // dst-CSR
  int* deg    = (int*)alloc(NN);
  int* rowptr = (int*)alloc(NN);
  int* cursor = (int*)alloc(NN);
  int* partial = (int*)alloc(256);
  int* src_s  = (int*)alloc(NE);
  int* dst_s  = (int*)alloc(NE);
  float* ef_s = alloc((size_t)NE * 16);       // permuted edge features

  const float* Wf1  = fold;
  const float* b1f  = fold + 1024;
  const float* Wni1 = fold + 1088;
  const float* Wnj1 = fold + 3136;
  const float* Wno1 = fold + 5184;
  const float* bni1 = fold + 7232;
  const float* bnj1 = fold + 7296;
  const float* bno1 = fold + 7360;

  const int B = 256;
  const int NGB = cdiv(NN, 128);
  const int EGB = cdiv(NE, 128);
  const int NB256 = cdiv(NN, 256);

  // ---- CSR build (dst-sorted) + fused edge permutation ----
  hipMemsetAsync(deg, 0, NN * 4, stream);
  deg_kernel<<<cdiv(NE, B), B, 0, stream>>>(dst, deg);
  scan1_kernel<<<NB256, 256, 0, stream>>>(deg, rowptr, partial);
  scan2_kernel<<<1, 256, 0, stream>>>(partial, NB256);
  scan3_kernel<<<NB256, 256, 0, stream>>>(rowptr, partial, cursor);
  scatter_dst_kernel<<<cdiv(NE, B), B, 0, stream>>>(src, dst, ef, cursor, src_s, dst_s, ef_s);

  // folded weights + nn weight pack (tiny)
  fold_kernel<<<29, B, 0, stream>>>(fp_w, fp_b, ep_w, ep_b,
                                    (const float*)d_in[15], (const float*)d_in[18],
                                    (const float*)d_in[13], (const float*)d_in[14],
                                    (const float*)d_in[16], fold);
  nnwt_kernel<<<68, B, 0, stream>>>(nn_w, nn_b, W2bf);

  // ---- EGAT layer 1 (edges processed in dst-sorted order) ----
  gemm3_kernel<32, true><<<dim3(NGB, 3), B, 0, stream>>>(face, Wni1, Wnj1, Wno1, bni1, bnj1,
                                                         bno1, hs16, hd16, hn16, NN);
  gemm_fout_kernel<16, true, false><<<EGB, B, 0, stream>>>(ef_s, Wf1, b1f, hs16, hd16, src_s,
                                                           dst_s, e1_attn, f116, logit);
  agg_gather_kernel<<<cdiv(NN * 64, B), B, 0, stream>>>(hn16, logit, rowptr, deg, src_s, h1);

  // ---- EGAT layer 2 ----
  gemm3_kernel<64, false><<<dim3(NGB, 3), B, 0, stream>>>(h1, e2_ni, e2_nj, e2_node, nullptr,
                                                          nullptr, nullptr, hs16, hd16, hn16, NN);
  gemm_fout_kernel<64, false, true><<<EGB, B, 0, stream>>>(f116, e2_fij, e2_bias, hs16, hd16,
                                                           src_s, dst_s, e2_attn, nullptr, logit);
  agg_gather_kernel<<<cdiv(NN * 64, B), B, 0, stream>>>(hn16, logit, rowptr, deg, src_s, h0);

  // ---- NNConv (outer-product form; G aliases dead EGAT buffers — runs after EGAT) ----
  nnconv_G_kernel<<<cdiv(NN * 64, B), B, 0, stream>>>(face, ef_s, rowptr, deg, src_s, G);
  gemm_G_kernel<<<cdiv(NN, 64), B, 0, stream>>>(G, W2bf, sArr, NN);

  // ---- combine node features + gate logits ----
  hipMemsetAsync(gacc, 0, 128 * 4, stream);
  hipMemsetAsync(gsum, 0, 4, stream);
  hipMemsetAsync(gmax, 0, 4, stream);
  combine_gate_kernel<<<cdiv(NN * 64, B), B, 0, stream>>>(h0, sArr, deg, nn_bias, gate_w,
                                                          gate_b, out, g);
  gate_max_kernel<<<128, B, 0, stream>>>(g, gmax);
  pool_exp_kernel<<<512, 128, 0, stream>>>(out, g, gmax, gacc, gsum);
  finalize_kernel<<<1, 128, 0, stream>>>(gacc, gsum, out);
}

// Round 19
// 338.609 us; speedup vs baseline: 1.1870x; 1.0998x over previous
//
#include <hip/hip_runtime.h>

#define NN 60000
#define NE 300000
typedef unsigned short ush;
typedef __attribute__((ext_vector_type(8))) short bf16x8;
typedef __attribute__((ext_vector_type(4))) float f32x4;

static inline int cdiv(int a, int b) { return (a + b - 1) / b; }

__device__ inline unsigned ord_enc(float x) {
  unsigned u = __float_as_uint(x);
  return (u & 0x80000000u) ? ~u : (u | 0x80000000u);
}
__device__ inline float ord_dec(unsigned u) {
  return __uint_as_float((u & 0x80000000u) ? (u & 0x7fffffffu) : ~u);
}
__device__ inline float bf2f(unsigned u16) { return __uint_as_float(u16 << 16); }
__device__ inline ush f2bf(float x) {
  unsigned u = __float_as_uint(x);
  return (ush)((u + 0x7FFFu + ((u >> 16) & 1u)) >> 16);
}
__device__ inline unsigned pack2(float lo, float hi) {
  return ((unsigned)f2bf(hi) << 16) | (unsigned)f2bf(lo);
}

// ================= CSR build (dst-sorted) =================
__global__ void deg_kernel(const int* __restrict__ key, int* __restrict__ deg) {
  int e = blockIdx.x * blockDim.x + threadIdx.x;
  if (e < NE) atomicAdd(deg + key[e], 1);
}

__global__ void scan1_kernel(const int* __restrict__ deg, int* __restrict__ rowptr,
                             int* __restrict__ partial) {
  __shared__ int s[256];
  int i = blockIdx.x * 256 + threadIdx.x;
  int v = (i < NN) ? deg[i] : 0;
  s[threadIdx.x] = v;
  __syncthreads();
  for (int off = 1; off < 256; off <<= 1) {
    int t = (threadIdx.x >= off) ? s[threadIdx.x - off] : 0;
    __syncthreads();
    s[threadIdx.x] += t;
    __syncthreads();
  }
  if (i < NN) rowptr[i] = s[threadIdx.x] - v;
  if (threadIdx.x == 255) partial[blockIdx.x] = s[255];
}

__global__ void scan2_kernel(int* __restrict__ partial, int nb) {
  __shared__ int s[256];
  int v = (threadIdx.x < nb) ? partial[threadIdx.x] : 0;
  s[threadIdx.x] = v;
  __syncthreads();
  for (int off = 1; off < 256; off <<= 1) {
    int t = (threadIdx.x >= off) ? s[threadIdx.x - off] : 0;
    __syncthreads();
    s[threadIdx.x] += t;
    __syncthreads();
  }
  if (threadIdx.x < nb) partial[threadIdx.x] = s[threadIdx.x] - v;
}

__global__ void scan3_kernel(int* __restrict__ rowptr, const int* __restrict__ partial,
                             int* __restrict__ cursor) {
  int i = blockIdx.x * 256 + threadIdx.x;
  if (i < NN) {
    int r = rowptr[i] + partial[blockIdx.x];
    rowptr[i] = r;
    cursor[i] = r;
  }
}

// scatter + ef permutation fused (sequential ef read, random 64B write)
__global__ void scatter_dst_kernel(const int* __restrict__ src, const int* __restrict__ dst,
                                   const float* __restrict__ ef, int* __restrict__ cursor,
                                   int* __restrict__ src_s, int* __restrict__ dst_s,
                                   float* __restrict__ ef_s) {
  int e = blockIdx.x * blockDim.x + threadIdx.x;
  if (e >= NE) return;
  int d = dst[e];
  int j = atomicAdd(cursor + d, 1);
  src_s[j] = src[e];
  dst_s[j] = d;
  const float4* ep = (const float4*)(ef + (size_t)e * 16);
  float4 a = ep[0], b = ep[1], c = ep[2], dd = ep[3];
  float4* op = (float4*)(ef_s + (size_t)j * 16);
  op[0] = a; op[1] = b; op[2] = c; op[3] = dd;
}

// ---------------- fold: precompute folded weight products (7424 dots of length 64) -------
__global__ void fold_kernel(const float* __restrict__ fp_w, const float* __restrict__ fp_b,
                            const float* __restrict__ ep_w, const float* __restrict__ ep_b,
                            const float* __restrict__ fij, const float* __restrict__ ebias,
                            const float* __restrict__ ni, const float* __restrict__ nj,
                            const float* __restrict__ node, float* __restrict__ fold) {
  int t = blockIdx.x * blockDim.x + threadIdx.x;
  if (t >= 7424) return;
  int o = t & 63;
  const float* A;
  const float* B;
  float init = 0.f;
  if (t < 1024)      { A = ep_w + (size_t)(t >> 6) * 64; B = fij + o; }
  else if (t < 1088) { A = ep_b; B = fij + o; init = ebias[o]; }
  else if (t < 3136) { A = fp_w + (size_t)((t - 1088) >> 6) * 64; B = ni + o; }
  else if (t < 5184) { A = fp_w + (size_t)((t - 3136) >> 6) * 64; B = nj + o; }
  else if (t < 7232) { A = fp_w + (size_t)((t - 5184) >> 6) * 64; B = node + o; }
  else if (t < 7296) { A = fp_b; B = ni + o; }
  else if (t < 7360) { A = fp_b; B = nj + o; }
  else               { A = fp_b; B = node + o; }
  float a = init;
  for (int i = 0; i < 64; ++i) a = fmaf(A[i], B[(size_t)i * 64], a);
  fold[t] = a;
}

// ---------------- pack nn_w/nn_b into MFMA B-fragment order ----------------
// Wfrag[(kk*2+ct)*512 + lane*8 + i] = W2[k][o], k = kk*32 + (lane>>4)*8 + i,
// o = ct*16 + (lane&15);  W2[c][o]: c<512 -> nn_w[(c>>5)*1024 + (c&31)*32 + o],
// else nn_b[(c-512)*32 + o].  17 K-steps x 2 col tiles x 64 lanes x 8 = 17408.
__global__ void nnwt_frag_kernel(const float* __restrict__ nn_w, const float* __restrict__ nn_b,
                                 ush* __restrict__ Wfrag) {
  int t = blockIdx.x * blockDim.x + threadIdx.x;
  if (t >= 17408) return;
  int i = t & 7, lane = (t >> 3) & 63, ct = (t >> 9) & 1, kk = t >> 10;
  int k = kk * 32 + (lane >> 4) * 8 + i;
  int o = ct * 16 + (lane & 15);
  float v = (k < 512) ? nn_w[(size_t)(k >> 5) * 1024 + (k & 31) * 32 + o]
                      : nn_b[(k - 512) * 32 + o];
  Wfrag[t] = f2bf(v);
}

// ---------------- tiled GEMM (rows x K) @ (K x 64) -> bf16 out; 3 weight sets ------------
template <int K, bool BIAS>
__global__ __launch_bounds__(256, 2) void gemm3_kernel(
    const float* __restrict__ A, const float* __restrict__ W0, const float* __restrict__ W1,
    const float* __restrict__ W2, const float* __restrict__ b0, const float* __restrict__ b1,
    const float* __restrict__ b2, ush* __restrict__ o0, ush* __restrict__ o1,
    ush* __restrict__ o2, int rows) {
  __shared__ float sA[128][K + 1];
  __shared__ float sW[K][64];
  const float* W = blockIdx.y == 0 ? W0 : blockIdx.y == 1 ? W1 : W2;
  const float* bb = blockIdx.y == 0 ? b0 : blockIdx.y == 1 ? b1 : b2;
  ush* out = blockIdx.y == 0 ? o0 : blockIdx.y == 1 ? o1 : o2;
  int t = threadIdx.x;
  int r0 = blockIdx.x * 128;
  for (int i = t; i < K * 16; i += 256) ((float4*)sW)[i] = ((const float4*)W)[i];
  for (int i = t; i < 128 * (K / 4); i += 256) {
    int rr = i / (K / 4), cc = i % (K / 4);
    float4 v = (r0 + rr < rows) ? ((const float4*)(A + (size_t)(r0 + rr) * K))[cc]
                                : make_float4(0.f, 0.f, 0.f, 0.f);
    sA[rr][cc * 4 + 0] = v.x;
    sA[rr][cc * 4 + 1] = v.y;
    sA[rr][cc * 4 + 2] = v.z;
    sA[rr][cc * 4 + 3] = v.w;
  }
  __syncthreads();
  int rg = t >> 3, cg = t & 7;
  float acc[4][8];
#pragma unroll
  for (int i = 0; i < 4; ++i)
#pragma unroll
    for (int j = 0; j < 8; ++j) acc[i][j] = 0.f;
#pragma unroll 8
  for (int k = 0; k < K; ++k) {
    float a0 = sA[rg * 4 + 0][k], a1 = sA[rg * 4 + 1][k];
    float a2 = sA[rg * 4 + 2][k], a3 = sA[rg * 4 + 3][k];
    float4 wA = *(const float4*)&sW[k][cg * 8];
    float4 wB = *(const float4*)&sW[k][cg * 8 + 4];
#pragma unroll
    for (int i = 0; i < 4; ++i) {
      float a = i == 0 ? a0 : i == 1 ? a1 : i == 2 ? a2 : a3;
      acc[i][0] = fmaf(a, wA.x, acc[i][0]); acc[i][1] = fmaf(a, wA.y, acc[i][1]);
      acc[i][2] = fmaf(a, wA.z, acc[i][2]); acc[i][3] = fmaf(a, wA.w, acc[i][3]);
      acc[i][4] = fmaf(a, wB.x, acc[i][4]); acc[i][5] = fmaf(a, wB.y, acc[i][5]);
      acc[i][6] = fmaf(a, wB.z, acc[i][6]); acc[i][7] = fmaf(a, wB.w, acc[i][7]);
    }
  }
  float bv[8];
#pragma unroll
  for (int j = 0; j < 8; ++j) bv[j] = BIAS ? bb[cg * 8 + j] : 0.f;
#pragma unroll
  for (int i = 0; i < 4; ++i) {
    int r = r0 + rg * 4 + i;
    if (r < rows) {
      uint4 pv;
      pv.x = pack2(acc[i][0] + bv[0], acc[i][1] + bv[1]);
      pv.y = pack2(acc[i][2] + bv[2], acc[i][3] + bv[3]);
      pv.z = pack2(acc[i][4] + bv[4], acc[i][5] + bv[5]);
      pv.w = pack2(acc[i][6] + bv[6], acc[i][7] + bv[7]);
      *(uint4*)(out + (size_t)r * 64 + cg * 8) = pv;
    }
  }
}

// ---------------- edge GEMM + fused f_out epilogue (edges in dst-sorted order) -----------
template <int K, bool STORE, bool ABF>
__global__ __launch_bounds__(256, 2) void gemm_fout_kernel(
    const void* __restrict__ Ap, const float* __restrict__ W, const float* __restrict__ bias,
    const ush* __restrict__ hs, const ush* __restrict__ hd, const int* __restrict__ src_s,
    const int* __restrict__ dst_s, const float* __restrict__ attn, ush* __restrict__ fstore,
    float* __restrict__ logit) {
  __shared__ float sA[128][K + 1];
  __shared__ float sW[K][64];
  int t = threadIdx.x;
  int r0 = blockIdx.x * 128;
  for (int i = t; i < K * 16; i += 256) ((float4*)sW)[i] = ((const float4*)W)[i];
  if (ABF) {
    const ush* A = (const ush*)Ap;
    for (int i = t; i < 128 * (K / 8); i += 256) {
      int rr = i / (K / 8), cc = i % (K / 8);
      uint4 v = (r0 + rr < NE) ? ((const uint4*)(A + (size_t)(r0 + rr) * K))[cc]
                               : make_uint4(0, 0, 0, 0);
      float* dp = &sA[rr][cc * 8];
      dp[0] = bf2f(v.x & 0xffff); dp[1] = bf2f(v.x >> 16);
      dp[2] = bf2f(v.y & 0xffff); dp[3] = bf2f(v.y >> 16);
      dp[4] = bf2f(v.z & 0xffff); dp[5] = bf2f(v.z >> 16);
      dp[6] = bf2f(v.w & 0xffff); dp[7] = bf2f(v.w >> 16);
    }
  } else {
    const float* A = (const float*)Ap;
    for (int i = t; i < 128 * (K / 4); i += 256) {
      int rr = i / (K / 4), cc = i % (K / 4);
      float4 v = (r0 + rr < NE) ? ((const float4*)(A + (size_t)(r0 + rr) * K))[cc]
                                : make_float4(0.f, 0.f, 0.f, 0.f);
      sA[rr][cc * 4 + 0] = v.x;
      sA[rr][cc * 4 + 1] = v.y;
      sA[rr][cc * 4 + 2] = v.z;
      sA[rr][cc * 4 + 3] = v.w;
    }
  }
  __syncthreads();
  int rg = t >> 3, cg = t & 7;
  float acc[4][8];
#pragma unroll
  for (int i = 0; i < 4; ++i)
#pragma unroll
    for (int j = 0; j < 8; ++j) acc[i][j] = 0.f;
#pragma unroll 8
  for (int k = 0; k < K; ++k) {
    float a0 = sA[rg * 4 + 0][k], a1 = sA[rg * 4 + 1][k];
    float a2 = sA[rg * 4 + 2][k], a3 = sA[rg * 4 + 3][k];
    float4 wA = *(const float4*)&sW[k][cg * 8];
    float4 wB = *(const float4*)&sW[k][cg * 8 + 4];
#pragma unroll
    for (int i = 0; i < 4; ++i) {
      float a = i == 0 ? a0 : i == 1 ? a1 : i == 2 ? a2 : a3;
      acc[i][0] = fmaf(a, wA.x, acc[i][0]); acc[i][1] = fmaf(a, wA.y, acc[i][1]);
      acc[i][2] = fmaf(a, wA.z, acc[i][2]); acc[i][3] = fmaf(a, wA.w, acc[i][3]);
      acc[i][4] = fmaf(a, wB.x, acc[i][4]); acc[i][5] = fmaf(a, wB.y, acc[i][5]);
      acc[i][6] = fmaf(a, wB.z, acc[i][6]); acc[i][7] = fmaf(a, wB.w, acc[i][7]);
    }
  }
  float bv[8], av[8];
#pragma unroll
  for (int j = 0; j < 8; ++j) {
    bv[j] = bias[cg * 8 + j];
    av[j] = attn[cg * 8 + j];
  }
#pragma unroll
  for (int i = 0; i < 4; ++i) {
    int r = r0 + rg * 4 + i;
    if (r < NE) {
      int s = src_s[r], d = dst_s[r];
      uint4 hv = *(const uint4*)(hs + (size_t)s * 64 + cg * 8);
      uint4 dv = *(const uint4*)(hd + (size_t)d * 64 + cg * 8);
      float fo[8];
      fo[0] = acc[i][0] + bf2f(hv.x & 0xffff) + bf2f(dv.x & 0xffff) + bv[0];
      fo[1] = acc[i][1] + bf2f(hv.x >> 16)    + bf2f(dv.x >> 16)    + bv[1];
      fo[2] = acc[i][2] + bf2f(hv.y & 0xffff) + bf2f(dv.y & 0xffff) + bv[2];
      fo[3] = acc[i][3] + bf2f(hv.y >> 16)    + bf2f(dv.y >> 16)    + bv[3];
      fo[4] = acc[i][4] + bf2f(hv.z & 0xffff) + bf2f(dv.z & 0xffff) + bv[4];
      fo[5] = acc[i][5] + bf2f(hv.z >> 16)    + bf2f(dv.z >> 16)    + bv[5];
      fo[6] = acc[i][6] + bf2f(hv.w & 0xffff) + bf2f(dv.w & 0xffff) + bv[6];
      fo[7] = acc[i][7] + bf2f(hv.w >> 16)    + bf2f(dv.w >> 16)    + bv[7];
      float p = 0.f;
#pragma unroll
      for (int j = 0; j < 8; ++j) {
        fo[j] = fo[j] >= 0.f ? fo[j] : 0.01f * fo[j];  // LeakyReLU
        p = fmaf(fo[j], av[j], p);
      }
      if (STORE) {
        uint4 pv;
        pv.x = pack2(fo[0], fo[1]);
        pv.y = pack2(fo[2], fo[3]);
        pv.z = pack2(fo[4], fo[5]);
        pv.w = pack2(fo[6], fo[7]);
        *(uint4*)(fstore + (size_t)r * 64 + cg * 8) = pv;
      }
      p += __shfl_xor(p, 1, 64);
      p += __shfl_xor(p, 2, 64);
      p += __shfl_xor(p, 4, 64);
      if (cg == 0) logit[r] = p;
    }
  }
}

// ---------------- EGAT: gather-aggregate, no max pre-pass (logits ~O(1), exp f32-safe) ---
__global__ __launch_bounds__(256, 4) void agg_gather_kernel(
    const ush* __restrict__ hn, const float* __restrict__ logit, const int* __restrict__ rowptr,
    const int* __restrict__ deg, const int* __restrict__ src_s, float* __restrict__ hnew) {
  int wave = (blockIdx.x * blockDim.x + threadIdx.x) >> 6;
  int lane = threadIdx.x & 63;
  if (wave >= NN) return;
  int n = wave, d = deg[n], r0 = rowptr[n];
  if (d == 0) {
    hnew[(size_t)n * 64 + lane] = 0.f;
    return;
  }
  float sum = 0.f, acc0 = 0.f, acc1 = 0.f, acc2 = 0.f, acc3 = 0.f;
  int j = 0;
  for (; j + 3 < d; j += 4) {
    int jj = r0 + j;
    int s0 = src_s[jj + 0], s1 = src_s[jj + 1], s2 = src_s[jj + 2], s3 = src_s[jj + 3];
    float l0 = logit[jj + 0], l1 = logit[jj + 1], l2 = logit[jj + 2], l3 = logit[jj + 3];
    ush h0 = hn[(size_t)s0 * 64 + lane];
    ush h1 = hn[(size_t)s1 * 64 + lane];
    ush h2 = hn[(size_t)s2 * 64 + lane];
    ush h3 = hn[(size_t)s3 * 64 + lane];
    float w0 = __expf(l0), w1 = __expf(l1);
    float w2 = __expf(l2), w3 = __expf(l3);
    sum += (w0 + w1) + (w2 + w3);
    acc0 = fmaf(w0, bf2f(h0), acc0);
    acc1 = fmaf(w1, bf2f(h1), acc1);
    acc2 = fmaf(w2, bf2f(h2), acc2);
    acc3 = fmaf(w3, bf2f(h3), acc3);
  }
  for (; j < d; ++j) {
    int jj = r0 + j;
    float w = __expf(logit[jj]);
    sum += w;
    acc0 = fmaf(w, bf2f(hn[(size_t)src_s[jj] * 64 + lane]), acc0);
  }
  hnew[(size_t)n * 64 + lane] = ((acc0 + acc1) + (acc2 + acc3)) / sum;
}

// ---------------- NNConv phase A: per-node outer-product G accumulate (registers only) ---
__global__ __launch_bounds__(256, 4) void nnconv_G_kernel(
    const float* __restrict__ face, const float* __restrict__ ef_s,
    const int* __restrict__ rowptr, const int* __restrict__ deg, const int* __restrict__ src_s,
    ush* __restrict__ G) {
  int wave = (blockIdx.x * blockDim.x + threadIdx.x) >> 6;
  int lane = threadIdx.x & 63;
  if (wave >= NN) return;
  int n = wave, d = deg[n], r0 = rowptr[n];
  int k4 = lane >> 2, ib = lane & 3;
  float g[8], fs[8];
#pragma unroll
  for (int u = 0; u < 8; ++u) { g[u] = 0.f; fs[u] = 0.f; }
  int j = 0;
  for (; j + 1 < d; j += 2) {
    int jj = r0 + j;
    int s0 = src_s[jj], s1 = src_s[jj + 1];
    float ev0 = ef_s[(size_t)jj * 16 + k4];
    float ev1 = ef_s[(size_t)(jj + 1) * 16 + k4];
    const float4* fp0 = (const float4*)(face + (size_t)s0 * 32 + ib * 8);
    const float4* fp1 = (const float4*)(face + (size_t)s1 * 32 + ib * 8);
    float4 fa0 = fp0[0], fb0 = fp0[1];
    float4 fa1 = fp1[0], fb1 = fp1[1];
    g[0] = fmaf(ev0, fa0.x, g[0]); g[1] = fmaf(ev0, fa0.y, g[1]);
    g[2] = fmaf(ev0, fa0.z, g[2]); g[3] = fmaf(ev0, fa0.w, g[3]);
    g[4] = fmaf(ev0, fb0.x, g[4]); g[5] = fmaf(ev0, fb0.y, g[5]);
    g[6] = fmaf(ev0, fb0.z, g[6]); g[7] = fmaf(ev0, fb0.w, g[7]);
    g[0] = fmaf(ev1, fa1.x, g[0]); g[1] = fmaf(ev1, fa1.y, g[1]);
    g[2] = fmaf(ev1, fa1.z, g[2]); g[3] = fmaf(ev1, fa1.w, g[3]);
    g[4] = fmaf(ev1, fb1.x, g[4]); g[5] = fmaf(ev1, fb1.y, g[5]);
    g[6] = fmaf(ev1, fb1.z, g[6]); g[7] = fmaf(ev1, fb1.w, g[7]);
    if (k4 == 0) {
      fs[0] += fa0.x + fa1.x; fs[1] += fa0.y + fa1.y;
      fs[2] += fa0.z + fa1.z; fs[3] += fa0.w + fa1.w;
      fs[4] += fb0.x + fb1.x; fs[5] += fb0.y + fb1.y;
      fs[6] += fb0.z + fb1.z; fs[7] += fb0.w + fb1.w;
    }
  }
  if (j < d) {
    int jj = r0 + j;
    int s0 = src_s[jj];
    float ev0 = ef_s[(size_t)jj * 16 + k4];
    const float4* fp0 = (const float4*)(face + (size_t)s0 * 32 + ib * 8);
    float4 fa0 = fp0[0], fb0 = fp0[1];
    g[0] = fmaf(ev0, fa0.x, g[0]); g[1] = fmaf(ev0, fa0.y, g[1]);
    g[2] = fmaf(ev0, fa0.z, g[2]); g[3] = fmaf(ev0, fa0.w, g[3]);
    g[4] = fmaf(ev0, fb0.x, g[4]); g[5] = fmaf(ev0, fb0.y, g[5]);
    g[6] = fmaf(ev0, fb0.z, g[6]); g[7] = fmaf(ev0, fb0.w, g[7]);
    if (k4 == 0) {
      fs[0] += fa0.x; fs[1] += fa0.y; fs[2] += fa0.z; fs[3] += fa0.w;
      fs[4] += fb0.x; fs[5] += fb0.y; fs[6] += fb0.z; fs[7] += fb0.w;
    }
  }
  uint4 pv;
  pv.x = pack2(g[0], g[1]); pv.y = pack2(g[2], g[3]);
  pv.z = pack2(g[4], g[5]); pv.w = pack2(g[6], g[7]);
  *(uint4*)(G + (size_t)n * 544 + lane * 8) = pv;
  if (k4 == 0) {
    uint4 fv;
    fv.x = pack2(fs[0], fs[1]); fv.y = pack2(fs[2], fs[3]);
    fv.z = pack2(fs[4], fs[5]); fv.w = pack2(fs[6], fs[7]);
    *(uint4*)(G + (size_t)n * 544 + 512 + ib * 8) = fv;
  }
}

// ---------------- NNConv phase B: MFMA GEMM sArr = G(NNx544) @ W(544x32) ----------------
// One wave per 16-row tile. A frag: row=lane&15, k=(lane>>4)*8+i (uint4 from G row).
// B frag: pre-packed Wfrag, coalesced uint4 per lane. C/D: col=lane&15, row=(lane>>4)*4+j.
__global__ __launch_bounds__(256, 4) void gemm_G_mfma_kernel(const ush* __restrict__ G,
                                                             const ush* __restrict__ Wfrag,
                                                             float* __restrict__ sArr,
                                                             int rows) {
  int wave = (blockIdx.x * blockDim.x + threadIdx.x) >> 6;
  int lane = threadIdx.x & 63;
  int m0 = wave * 16;
  if (m0 >= rows) return;
  int arow = lane & 15;
  int aoff = (lane >> 4) * 8;
  const ush* gp = G + (size_t)(m0 + arow) * 544 + aoff;
  const ush* wp = Wfrag + lane * 8;
  f32x4 acc0 = {0.f, 0.f, 0.f, 0.f};
  f32x4 acc1 = {0.f, 0.f, 0.f, 0.f};
#pragma unroll 4
  for (int kk = 0; kk < 17; ++kk) {
    bf16x8 a = *(const bf16x8*)(gp + kk * 32);
    bf16x8 b0 = *(const bf16x8*)(wp + (size_t)(kk * 2 + 0) * 512);
    bf16x8 b1 = *(const bf16x8*)(wp + (size_t)(kk * 2 + 1) * 512);
    acc0 = __builtin_amdgcn_mfma_f32_16x16x32_bf16(a, b0, acc0, 0, 0, 0);
    acc1 = __builtin_amdgcn_mfma_f32_16x16x32_bf16(a, b1, acc1, 0, 0, 0);
  }
  int ccol = lane & 15;
  int crow = (lane >> 4) * 4;
#pragma unroll
  for (int j = 0; j < 4; ++j) {
    int r = m0 + crow + j;
    sArr[(size_t)r * 32 + ccol] = acc0[j];
    sArr[(size_t)r * 32 + 16 + ccol] = acc1[j];
  }
}

// ---------------- combine node_features + gate logit (fused; wave per node) --------------
__global__ void combine_gate_kernel(const float* __restrict__ hfin, const float* __restrict__ sArr,
                                    const int* __restrict__ deg, const float* __restrict__ nn_bias,
                                    const float* __restrict__ gate_w, const float* __restrict__ gate_b,
                                    float* __restrict__ out, float* __restrict__ g) {
  int wave = (blockIdx.x * blockDim.x + threadIdx.x) >> 6;
  int lane = threadIdx.x & 63;
  if (wave >= NN) return;
  int n = wave;
  float v0 = hfin[(size_t)n * 64 + lane];
  int c1 = lane + 64;
  float v1 = (c1 < 96)
                 ? sArr[(size_t)n * 32 + (c1 - 64)] / fmaxf((float)deg[n], 1.0f) + nn_bias[c1 - 64]
                 : 0.f;
  out[(size_t)n * 128 + lane] = v0;
  out[(size_t)n * 128 + c1] = v1;
  float p = v0 * gate_w[lane] + ((c1 < 96) ? v1 * gate_w[c1] : 0.f);
#pragma unroll
  for (int off = 32; off; off >>= 1) p += __shfl_xor(p, off, 64);
  if (lane == 0) g[n] = p + gate_b[0];
}

// ---------------- max over g (block-reduced, 1 atomic per block) ----------------
__global__ void gate_max_kernel(const float* __restrict__ g, unsigned* __restrict__ gmax) {
  int tid = blockIdx.x * blockDim.x + threadIdx.x;
  int stride = gridDim.x * blockDim.x;
  float v = -3.0e38f;
  for (int n = tid; n < NN; n += stride) v = fmaxf(v, g[n]);
#pragma unroll
  for (int off = 32; off; off >>= 1) v = fmaxf(v, __shfl_xor(v, off, 64));
  __shared__ float sm[4];
  int lane = threadIdx.x & 63, wid = threadIdx.x >> 6;
  if (lane == 0) sm[wid] = v;
  __syncthreads();
  if (threadIdx.x == 0) {
    float m = fmaxf(fmaxf(sm[0], sm[1]), fmaxf(sm[2], sm[3]));
    atomicMax(gmax, ord_enc(m));
  }
}

// ---------------- pooling: exp + weighted accumulate (fused) ----------------
__global__ void pool_exp_kernel(const float* __restrict__ nf, const float* __restrict__ g,
                                const unsigned* __restrict__ gmax, float* __restrict__ gacc,
                                float* __restrict__ gsum) {
  int o = threadIdx.x;  // blockDim = 128
  float m = ord_dec(*gmax);
  float acc = 0.f, ws = 0.f;
  for (int n = blockIdx.x; n < NN; n += gridDim.x) {
    float w = __expf(g[n] - m);
    ws += w;
    acc += w * nf[(size_t)n * 128 + o];
  }
  atomicAdd(gacc + o, acc);
  if (o == 0) atomicAdd(gsum, ws);
}

__global__ void finalize_kernel(const float* __restrict__ gacc, const float* __restrict__ gsum,
                                float* __restrict__ out) {
  int o = threadIdx.x;
  if (o < 128) out[(size_t)NN * 128 + o] = gacc[o] / gsum[0];
}

extern "C" void kernel_launch(void* const* d_in, const int* in_sizes, int n_in,
                              void* d_out, int out_size, void* d_ws, size_t ws_size,
                              hipStream_t stream) {
  const float* face    = (const float*)d_in[0];
  const float* ef      = (const float*)d_in[1];
  const float* fp_w    = (const float*)d_in[2];
  const float* fp_b    = (const float*)d_in[3];
  const float* ep_w    = (const float*)d_in[4];
  const float* ep_b    = (const float*)d_in[5];
  const float* nn_w    = (const float*)d_in[6];
  const float* nn_b    = (const float*)d_in[7];
  const float* nn_bias = (const float*)d_in[8];
  const float* gate_w  = (const float*)d_in[9];
  const float* gate_b  = (const float*)d_in[10];
  const int*   src     = (const int*)d_in[11];
  const int*   dst     = (const int*)d_in[12];
  const float* e1_attn = (const float*)d_in[17];
  const float* e2_ni   = (const float*)d_in[19];
  const float* e2_nj   = (const float*)d_in[20];
  const float* e2_fij  = (const float*)d_in[21];
  const float* e2_node = (const float*)d_in[22];
  const float* e2_attn = (const float*)d_in[23];
  const float* e2_bias = (const float*)d_in[24];
  float* out = (float*)d_out;

  char* p = (char*)d_ws;
  auto alloc = [&](size_t nfloats) {
    float* r = (float*)p;
    p += ((nfloats * 4 + 255) / 256) * 256;
    return r;
  };
  float* h0 = alloc((size_t)NN * 64);   // layer-2 output
  float* h1 = alloc((size_t)NN * 64);   // layer-1 output
  // big region: G (NN*544 bf16 = 65.28 MB) aliases hs16|hd16|hn16|f116|logit (dead post-EGAT)
  char* bigreg = p;
  ush* hs16 = (ush*)alloc((size_t)NN * 32);   // NN*64 bf16
  ush* hd16 = (ush*)alloc((size_t)NN * 32);
  ush* hn16 = (ush*)alloc((size_t)NN * 32);
  ush* f116 = (ush*)alloc((size_t)NE * 32);   // NE*64 bf16 (dst-sorted order)
  float* logit = alloc(NE);                   // dst-sorted order
  {  // pad bigreg to >= NN*544*2 bytes for G
    size_t used = (size_t)(p - bigreg);
    size_t need = (size_t)NN * 544 * 2;
    if (used < need) p += ((need - used + 255) / 256) * 256;
  }
  ush* G = (ush*)bigreg;
  float* sArr  = alloc((size_t)NN * 32);
  float* g     = alloc(NN);
  float* gacc  = alloc(128);
  float* gsum  = alloc(1);
  unsigned* gmax = (unsigned*)alloc(1);
  float* fold  = alloc(7424);
  ush* Wfrag   = (ush*)alloc(17408 / 2);      // 17408 bf16 (MFMA B-fragment order)
  // dst-CSR
  int* deg    = (int*)alloc(NN);
  int* rowptr = (int*)alloc(NN);
  int* cursor = (int*)alloc(NN);
  int* partial = (int*)alloc(256);
  int* src_s  = (int*)alloc(NE);
  int* dst_s  = (int*)alloc(NE);
  float* ef_s = alloc((size_t)NE * 16);       // permuted edge features

  const float* Wf1  = fold;
  const float* b1f  = fold + 1024;
  const float* Wni1 = fold + 1088;
  const float* Wnj1 = fold + 3136;
  const float* Wno1 = fold + 5184;
  const float* bni1 = fold + 7232;
  const float* bnj1 = fold + 7296;
  const float* bno1 = fold + 7360;

  const int B = 256;
  const int NGB = cdiv(NN, 128);
  const int EGB = cdiv(NE, 128);
  const int NB256 = cdiv(NN, 256);

  // ---- CSR build (dst-sorted) + fused edge permutation ----
  hipMemsetAsync(deg, 0, NN * 4, stream);
  deg_kernel<<<cdiv(NE, B), B, 0, stream>>>(dst, deg);
  scan1_kernel<<<NB256, 256, 0, stream>>>(deg, rowptr, partial);
  scan2_kernel<<<1, 256, 0, stream>>>(partial, NB256);
  scan3_kernel<<<NB256, 256, 0, stream>>>(rowptr, partial, cursor);
  scatter_dst_kernel<<<cdiv(NE, B), B, 0, stream>>>(src, dst, ef, cursor, src_s, dst_s, ef_s);

  // folded weights + nn weight fragment pack (tiny)
  fold_kernel<<<29, B, 0, stream>>>(fp_w, fp_b, ep_w, ep_b,
                                    (const float*)d_in[15], (const float*)d_in[18],
                                    (const float*)d_in[13], (const float*)d_in[14],
                                    (const float*)d_in[16], fold);
  nnwt_frag_kernel<<<68, B, 0, stream>>>(nn_w, nn_b, Wfrag);

  // ---- EGAT layer 1 (edges processed in dst-sorted order) ----
  gemm3_kernel<32, true><<<dim3(NGB, 3), B, 0, stream>>>(face, Wni1, Wnj1, Wno1, bni1, bnj1,
                                                         bno1, hs16, hd16, hn16, NN);
  gemm_fout_kernel<16, true, false><<<EGB, B, 0, stream>>>(ef_s, Wf1, b1f, hs16, hd16, src_s,
                                                           dst_s, e1_attn, f116, logit);
  agg_gather_kernel<<<cdiv(NN * 64, B), B, 0, stream>>>(hn16, logit, rowptr, deg, src_s, h1);

  // ---- EGAT layer 2 ----
  gemm3_kernel<64, false><<<dim3(NGB, 3), B, 0, stream>>>(h1, e2_ni, e2_nj, e2_node, nullptr,
                                                          nullptr, nullptr, hs16, hd16, hn16, NN);
  gemm_fout_kernel<64, false, true><<<EGB, B, 0, stream>>>(f116, e2_fij, e2_bias, hs16, hd16,
                                                           src_s, dst_s, e2_attn, nullptr, logit);
  agg_gather_kernel<<<cdiv(NN * 64, B), B, 0, stream>>>(hn16, logit, rowptr, deg, src_s, h0);

  // ---- NNConv (outer-product form; G aliases dead EGAT buffers — runs after EGAT) ----
  nnconv_G_kernel<<<cdiv(NN * 64, B), B, 0, stream>>>(face, ef_s, rowptr, deg, src_s, G);
  gemm_G_mfma_kernel<<<cdiv(NN * 4, B), B, 0, stream>>>(G, Wfrag, sArr, NN);

  // ---- combine node features + gate logits ----
  hipMemsetAsync(gacc, 0, 128 * 4, stream);
  hipMemsetAsync(gsum, 0, 4, stream);
  hipMemsetAsync(gmax, 0, 4, stream);
  combine_gate_kernel<<<cdiv(NN * 64, B), B, 0, stream>>>(h0, sArr, deg, nn_bias, gate_w,
                                                          gate_b, out, g);
  gate_max_kernel<<<128, B, 0, stream>>>(g, gmax);
  pool_exp_kernel<<<512, 128, 0, stream>>>(out, g, gmax, gacc, gsum);
  finalize_kernel<<<1, 128, 0, stream>>>(gacc, gsum, out);
}

// Round 20
// 315.964 us; speedup vs baseline: 1.2721x; 1.0717x over previous
//
#include <hip/hip_runtime.h>

#define NN 60000
#define NE 300000
typedef unsigned short ush;
typedef __attribute__((ext_vector_type(8))) short bf16x8;
typedef __attribute__((ext_vector_type(4))) float f32x4;

static inline int cdiv(int a, int b) { return (a + b - 1) / b; }

__device__ inline unsigned ord_enc(float x) {
  unsigned u = __float_as_uint(x);
  return (u & 0x80000000u) ? ~u : (u | 0x80000000u);
}
__device__ inline float ord_dec(unsigned u) {
  return __uint_as_float((u & 0x80000000u) ? (u & 0x7fffffffu) : ~u);
}
__device__ inline float bf2f(unsigned u16) { return __uint_as_float(u16 << 16); }
__device__ inline ush f2bf(float x) {
  unsigned u = __float_as_uint(x);
  return (ush)((u + 0x7FFFu + ((u >> 16) & 1u)) >> 16);
}
__device__ inline unsigned pack2(float lo, float hi) {
  return ((unsigned)f2bf(hi) << 16) | (unsigned)f2bf(lo);
}

// ================= CSR build (dst-sorted) =================
__global__ void deg_kernel(const int* __restrict__ key, int* __restrict__ deg) {
  int e = blockIdx.x * blockDim.x + threadIdx.x;
  if (e < NE) atomicAdd(deg + key[e], 1);
}

__global__ void scan1_kernel(const int* __restrict__ deg, int* __restrict__ rowptr,
                             int* __restrict__ partial) {
  __shared__ int s[256];
  int i = blockIdx.x * 256 + threadIdx.x;
  int v = (i < NN) ? deg[i] : 0;
  s[threadIdx.x] = v;
  __syncthreads();
  for (int off = 1; off < 256; off <<= 1) {
    int t = (threadIdx.x >= off) ? s[threadIdx.x - off] : 0;
    __syncthreads();
    s[threadIdx.x] += t;
    __syncthreads();
  }
  if (i < NN) rowptr[i] = s[threadIdx.x] - v;
  if (threadIdx.x == 255) partial[blockIdx.x] = s[255];
}

__global__ void scan2_kernel(int* __restrict__ partial, int nb) {
  __shared__ int s[256];
  int v = (threadIdx.x < nb) ? partial[threadIdx.x] : 0;
  s[threadIdx.x] = v;
  __syncthreads();
  for (int off = 1; off < 256; off <<= 1) {
    int t = (threadIdx.x >= off) ? s[threadIdx.x - off] : 0;
    __syncthreads();
    s[threadIdx.x] += t;
    __syncthreads();
  }
  if (threadIdx.x < nb) partial[threadIdx.x] = s[threadIdx.x] - v;
}

__global__ void scan3_kernel(int* __restrict__ rowptr, const int* __restrict__ partial,
                             int* __restrict__ cursor) {
  int i = blockIdx.x * 256 + threadIdx.x;
  if (i < NN) {
    int r = rowptr[i] + partial[blockIdx.x];
    rowptr[i] = r;
    cursor[i] = r;
  }
}

// scatter + ef permutation fused (sequential ef read, random 64B write)
__global__ void scatter_dst_kernel(const int* __restrict__ src, const int* __restrict__ dst,
                                   const float* __restrict__ ef, int* __restrict__ cursor,
                                   int* __restrict__ src_s, int* __restrict__ dst_s,
                                   float* __restrict__ ef_s) {
  int e = blockIdx.x * blockDim.x + threadIdx.x;
  if (e >= NE) return;
  int d = dst[e];
  int j = atomicAdd(cursor + d, 1);
  src_s[j] = src[e];
  dst_s[j] = d;
  const float4* ep = (const float4*)(ef + (size_t)e * 16);
  float4 a = ep[0], b = ep[1], c = ep[2], dd = ep[3];
  float4* op = (float4*)(ef_s + (size_t)j * 16);
  op[0] = a; op[1] = b; op[2] = c; op[3] = dd;
}

// ---------------- fold: precompute folded weight products (7424 dots of length 64) -------
__global__ void fold_kernel(const float* __restrict__ fp_w, const float* __restrict__ fp_b,
                            const float* __restrict__ ep_w, const float* __restrict__ ep_b,
                            const float* __restrict__ fij, const float* __restrict__ ebias,
                            const float* __restrict__ ni, const float* __restrict__ nj,
                            const float* __restrict__ node, float* __restrict__ fold) {
  int t = blockIdx.x * blockDim.x + threadIdx.x;
  if (t >= 7424) return;
  int o = t & 63;
  const float* A;
  const float* B;
  float init = 0.f;
  if (t < 1024)      { A = ep_w + (size_t)(t >> 6) * 64; B = fij + o; }
  else if (t < 1088) { A = ep_b; B = fij + o; init = ebias[o]; }
  else if (t < 3136) { A = fp_w + (size_t)((t - 1088) >> 6) * 64; B = ni + o; }
  else if (t < 5184) { A = fp_w + (size_t)((t - 3136) >> 6) * 64; B = nj + o; }
  else if (t < 7232) { A = fp_w + (size_t)((t - 5184) >> 6) * 64; B = node + o; }
  else if (t < 7296) { A = fp_b; B = ni + o; }
  else if (t < 7360) { A = fp_b; B = nj + o; }
  else               { A = fp_b; B = node + o; }
  float a = init;
  for (int i = 0; i < 64; ++i) a = fmaf(A[i], B[(size_t)i * 64], a);
  fold[t] = a;
}

// ---------------- pack nn_w/nn_b into MFMA B-fragment order (17 K-steps x 2 col tiles) ---
__global__ void nnwt_frag_kernel(const float* __restrict__ nn_w, const float* __restrict__ nn_b,
                                 ush* __restrict__ Wfrag) {
  int t = blockIdx.x * blockDim.x + threadIdx.x;
  if (t >= 17408) return;
  int i = t & 7, lane = (t >> 3) & 63, ct = (t >> 9) & 1, kk = t >> 10;
  int k = kk * 32 + (lane >> 4) * 8 + i;
  int o = ct * 16 + (lane & 15);
  float v = (k < 512) ? nn_w[(size_t)(k >> 5) * 1024 + (k & 31) * 32 + o]
                      : nn_b[(k - 512) * 32 + o];
  Wfrag[t] = f2bf(v);
}

// ---------------- pack e2_fij (64x64 f32) into MFMA B-frag order (2 kk x 4 col tiles) ----
__global__ void fij_frag_kernel(const float* __restrict__ fij, ush* __restrict__ Wfrag2) {
  int t = blockIdx.x * blockDim.x + threadIdx.x;
  if (t >= 4096) return;
  int i = t & 7, lane = (t >> 3) & 63, ct = (t >> 9) & 3, kk = t >> 11;
  int k = kk * 32 + (lane >> 4) * 8 + i;
  int o = ct * 16 + (lane & 15);
  Wfrag2[t] = f2bf(fij[(size_t)k * 64 + o]);
}

// ---------------- tiled GEMM (rows x K) @ (K x 64) -> bf16 out; 3 weight sets ------------
template <int K, bool BIAS>
__global__ __launch_bounds__(256, 2) void gemm3_kernel(
    const float* __restrict__ A, const float* __restrict__ W0, const float* __restrict__ W1,
    const float* __restrict__ W2, const float* __restrict__ b0, const float* __restrict__ b1,
    const float* __restrict__ b2, ush* __restrict__ o0, ush* __restrict__ o1,
    ush* __restrict__ o2, int rows) {
  __shared__ float sA[128][K + 1];
  __shared__ float sW[K][64];
  const float* W = blockIdx.y == 0 ? W0 : blockIdx.y == 1 ? W1 : W2;
  const float* bb = blockIdx.y == 0 ? b0 : blockIdx.y == 1 ? b1 : b2;
  ush* out = blockIdx.y == 0 ? o0 : blockIdx.y == 1 ? o1 : o2;
  int t = threadIdx.x;
  int r0 = blockIdx.x * 128;
  for (int i = t; i < K * 16; i += 256) ((float4*)sW)[i] = ((const float4*)W)[i];
  for (int i = t; i < 128 * (K / 4); i += 256) {
    int rr = i / (K / 4), cc = i % (K / 4);
    float4 v = (r0 + rr < rows) ? ((const float4*)(A + (size_t)(r0 + rr) * K))[cc]
                                : make_float4(0.f, 0.f, 0.f, 0.f);
    sA[rr][cc * 4 + 0] = v.x;
    sA[rr][cc * 4 + 1] = v.y;
    sA[rr][cc * 4 + 2] = v.z;
    sA[rr][cc * 4 + 3] = v.w;
  }
  __syncthreads();
  int rg = t >> 3, cg = t & 7;
  float acc[4][8];
#pragma unroll
  for (int i = 0; i < 4; ++i)
#pragma unroll
    for (int j = 0; j < 8; ++j) acc[i][j] = 0.f;
#pragma unroll 8
  for (int k = 0; k < K; ++k) {
    float a0 = sA[rg * 4 + 0][k], a1 = sA[rg * 4 + 1][k];
    float a2 = sA[rg * 4 + 2][k], a3 = sA[rg * 4 + 3][k];
    float4 wA = *(const float4*)&sW[k][cg * 8];
    float4 wB = *(const float4*)&sW[k][cg * 8 + 4];
#pragma unroll
    for (int i = 0; i < 4; ++i) {
      float a = i == 0 ? a0 : i == 1 ? a1 : i == 2 ? a2 : a3;
      acc[i][0] = fmaf(a, wA.x, acc[i][0]); acc[i][1] = fmaf(a, wA.y, acc[i][1]);
      acc[i][2] = fmaf(a, wA.z, acc[i][2]); acc[i][3] = fmaf(a, wA.w, acc[i][3]);
      acc[i][4] = fmaf(a, wB.x, acc[i][4]); acc[i][5] = fmaf(a, wB.y, acc[i][5]);
      acc[i][6] = fmaf(a, wB.z, acc[i][6]); acc[i][7] = fmaf(a, wB.w, acc[i][7]);
    }
  }
  float bv[8];
#pragma unroll
  for (int j = 0; j < 8; ++j) bv[j] = BIAS ? bb[cg * 8 + j] : 0.f;
#pragma unroll
  for (int i = 0; i < 4; ++i) {
    int r = r0 + rg * 4 + i;
    if (r < rows) {
      uint4 pv;
      pv.x = pack2(acc[i][0] + bv[0], acc[i][1] + bv[1]);
      pv.y = pack2(acc[i][2] + bv[2], acc[i][3] + bv[3]);
      pv.z = pack2(acc[i][4] + bv[4], acc[i][5] + bv[5]);
      pv.w = pack2(acc[i][6] + bv[6], acc[i][7] + bv[7]);
      *(uint4*)(out + (size_t)r * 64 + cg * 8) = pv;
    }
  }
}

// ---------------- layer-1 edge GEMM (K=16, f32 A) + fused f_out epilogue -----------------
template <int K, bool STORE>
__global__ __launch_bounds__(256, 2) void gemm_fout_kernel(
    const float* __restrict__ A, const float* __restrict__ W, const float* __restrict__ bias,
    const ush* __restrict__ hs, const ush* __restrict__ hd, const int* __restrict__ src_s,
    const int* __restrict__ dst_s, const float* __restrict__ attn, ush* __restrict__ fstore,
    float* __restrict__ logit) {
  __shared__ float sA[128][K + 1];
  __shared__ float sW[K][64];
  int t = threadIdx.x;
  int r0 = blockIdx.x * 128;
  for (int i = t; i < K * 16; i += 256) ((float4*)sW)[i] = ((const float4*)W)[i];
  for (int i = t; i < 128 * (K / 4); i += 256) {
    int rr = i / (K / 4), cc = i % (K / 4);
    float4 v = (r0 + rr < NE) ? ((const float4*)(A + (size_t)(r0 + rr) * K))[cc]
                              : make_float4(0.f, 0.f, 0.f, 0.f);
    sA[rr][cc * 4 + 0] = v.x;
    sA[rr][cc * 4 + 1] = v.y;
    sA[rr][cc * 4 + 2] = v.z;
    sA[rr][cc * 4 + 3] = v.w;
  }
  __syncthreads();
  int rg = t >> 3, cg = t & 7;
  float acc[4][8];
#pragma unroll
  for (int i = 0; i < 4; ++i)
#pragma unroll
    for (int j = 0; j < 8; ++j) acc[i][j] = 0.f;
#pragma unroll 8
  for (int k = 0; k < K; ++k) {
    float a0 = sA[rg * 4 + 0][k], a1 = sA[rg * 4 + 1][k];
    float a2 = sA[rg * 4 + 2][k], a3 = sA[rg * 4 + 3][k];
    float4 wA = *(const float4*)&sW[k][cg * 8];
    float4 wB = *(const float4*)&sW[k][cg * 8 + 4];
#pragma unroll
    for (int i = 0; i < 4; ++i) {
      float a = i == 0 ? a0 : i == 1 ? a1 : i == 2 ? a2 : a3;
      acc[i][0] = fmaf(a, wA.x, acc[i][0]); acc[i][1] = fmaf(a, wA.y, acc[i][1]);
      acc[i][2] = fmaf(a, wA.z, acc[i][2]); acc[i][3] = fmaf(a, wA.w, acc[i][3]);
      acc[i][4] = fmaf(a, wB.x, acc[i][4]); acc[i][5] = fmaf(a, wB.y, acc[i][5]);
      acc[i][6] = fmaf(a, wB.z, acc[i][6]); acc[i][7] = fmaf(a, wB.w, acc[i][7]);
    }
  }
  float bv[8], av[8];
#pragma unroll
  for (int j = 0; j < 8; ++j) {
    bv[j] = bias[cg * 8 + j];
    av[j] = attn[cg * 8 + j];
  }
#pragma unroll
  for (int i = 0; i < 4; ++i) {
    int r = r0 + rg * 4 + i;
    if (r < NE) {
      int s = src_s[r], d = dst_s[r];
      uint4 hv = *(const uint4*)(hs + (size_t)s * 64 + cg * 8);
      uint4 dv = *(const uint4*)(hd + (size_t)d * 64 + cg * 8);
      float fo[8];
      fo[0] = acc[i][0] + bf2f(hv.x & 0xffff) + bf2f(dv.x & 0xffff) + bv[0];
      fo[1] = acc[i][1] + bf2f(hv.x >> 16)    + bf2f(dv.x >> 16)    + bv[1];
      fo[2] = acc[i][2] + bf2f(hv.y & 0xffff) + bf2f(dv.y & 0xffff) + bv[2];
      fo[3] = acc[i][3] + bf2f(hv.y >> 16)    + bf2f(dv.y >> 16)    + bv[3];
      fo[4] = acc[i][4] + bf2f(hv.z & 0xffff) + bf2f(dv.z & 0xffff) + bv[4];
      fo[5] = acc[i][5] + bf2f(hv.z >> 16)    + bf2f(dv.z >> 16)    + bv[5];
      fo[6] = acc[i][6] + bf2f(hv.w & 0xffff) + bf2f(dv.w & 0xffff) + bv[6];
      fo[7] = acc[i][7] + bf2f(hv.w >> 16)    + bf2f(dv.w >> 16)    + bv[7];
      float p = 0.f;
#pragma unroll
      for (int j = 0; j < 8; ++j) {
        fo[j] = fo[j] >= 0.f ? fo[j] : 0.01f * fo[j];  // LeakyReLU
        p = fmaf(fo[j], av[j], p);
      }
      if (STORE) {
        uint4 pv;
        pv.x = pack2(fo[0], fo[1]);
        pv.y = pack2(fo[2], fo[3]);
        pv.z = pack2(fo[4], fo[5]);
        pv.w = pack2(fo[6], fo[7]);
        *(uint4*)(fstore + (size_t)r * 64 + cg * 8) = pv;
      }
      p += __shfl_xor(p, 1, 64);
      p += __shfl_xor(p, 2, 64);
      p += __shfl_xor(p, 4, 64);
      if (cg == 0) logit[r] = p;
    }
  }
}

// ---------------- layer-2 edge GEMM via MFMA: f116(NEx64 bf16) @ fij(64x64) --------------
// Wave per 16 edges; 2 K-steps x 4 col-tiles; fused epilogue; no LDS, no barriers.
__global__ __launch_bounds__(256, 4) void mfma_fout_kernel(
    const ush* __restrict__ f116, const ush* __restrict__ Wfrag2, const float* __restrict__ bias,
    const ush* __restrict__ hs, const ush* __restrict__ hd, const int* __restrict__ src_s,
    const int* __restrict__ dst_s, const float* __restrict__ attn, float* __restrict__ logit) {
  int wave = (blockIdx.x * blockDim.x + threadIdx.x) >> 6;
  int lane = threadIdx.x & 63;
  int m0 = wave * 16;
  if (m0 >= NE) return;
  int arow = lane & 15;
  int aoff = (lane >> 4) * 8;
  const ush* ap = f116 + (size_t)(m0 + arow) * 64 + aoff;
  const ush* wp = Wfrag2 + lane * 8;
  f32x4 acc0 = {0.f, 0.f, 0.f, 0.f};
  f32x4 acc1 = {0.f, 0.f, 0.f, 0.f};
  f32x4 acc2 = {0.f, 0.f, 0.f, 0.f};
  f32x4 acc3 = {0.f, 0.f, 0.f, 0.f};
#pragma unroll
  for (int kk = 0; kk < 2; ++kk) {
    bf16x8 a = *(const bf16x8*)(ap + kk * 32);
    bf16x8 b0 = *(const bf16x8*)(wp + (size_t)(kk * 4 + 0) * 512);
    bf16x8 b1 = *(const bf16x8*)(wp + (size_t)(kk * 4 + 1) * 512);
    bf16x8 b2 = *(const bf16x8*)(wp + (size_t)(kk * 4 + 2) * 512);
    bf16x8 b3 = *(const bf16x8*)(wp + (size_t)(kk * 4 + 3) * 512);
    acc0 = __builtin_amdgcn_mfma_f32_16x16x32_bf16(a, b0, acc0, 0, 0, 0);
    acc1 = __builtin_amdgcn_mfma_f32_16x16x32_bf16(a, b1, acc1, 0, 0, 0);
    acc2 = __builtin_amdgcn_mfma_f32_16x16x32_bf16(a, b2, acc2, 0, 0, 0);
    acc3 = __builtin_amdgcn_mfma_f32_16x16x32_bf16(a, b3, acc3, 0, 0, 0);
  }
  int ccol = lane & 15;
  int crow = (lane >> 4) * 4;
  float av0 = attn[ccol], av1 = attn[16 + ccol], av2 = attn[32 + ccol], av3 = attn[48 + ccol];
  float bv0 = bias[ccol], bv1 = bias[16 + ccol], bv2 = bias[32 + ccol], bv3 = bias[48 + ccol];
#pragma unroll
  for (int j = 0; j < 4; ++j) {
    int r = m0 + crow + j;
    int s = src_s[r], d = dst_s[r];
    const ush* hsp = hs + (size_t)s * 64;
    const ush* hdp = hd + (size_t)d * 64;
    float f0 = acc0[j] + bf2f(hsp[ccol]) + bf2f(hdp[ccol]) + bv0;
    float f1 = acc1[j] + bf2f(hsp[16 + ccol]) + bf2f(hdp[16 + ccol]) + bv1;
    float f2 = acc2[j] + bf2f(hsp[32 + ccol]) + bf2f(hdp[32 + ccol]) + bv2;
    float f3 = acc3[j] + bf2f(hsp[48 + ccol]) + bf2f(hdp[48 + ccol]) + bv3;
    f0 = f0 >= 0.f ? f0 : 0.01f * f0;
    f1 = f1 >= 0.f ? f1 : 0.01f * f1;
    f2 = f2 >= 0.f ? f2 : 0.01f * f2;
    f3 = f3 >= 0.f ? f3 : 0.01f * f3;
    float p = fmaf(f0, av0, fmaf(f1, av1, fmaf(f2, av2, f3 * av3)));
    p += __shfl_xor(p, 1, 64);
    p += __shfl_xor(p, 2, 64);
    p += __shfl_xor(p, 4, 64);
    p += __shfl_xor(p, 8, 64);
    if (ccol == 0) logit[r] = p;
  }
}

// ---------------- EGAT: gather-aggregate, no max pre-pass (logits ~O(1), exp f32-safe) ---
__global__ __launch_bounds__(256, 4) void agg_gather_kernel(
    const ush* __restrict__ hn, const float* __restrict__ logit, const int* __restrict__ rowptr,
    const int* __restrict__ deg, const int* __restrict__ src_s, float* __restrict__ hnew) {
  int wave = (blockIdx.x * blockDim.x + threadIdx.x) >> 6;
  int lane = threadIdx.x & 63;
  if (wave >= NN) return;
  int n = wave, d = deg[n], r0 = rowptr[n];
  if (d == 0) {
    hnew[(size_t)n * 64 + lane] = 0.f;
    return;
  }
  float sum = 0.f, acc0 = 0.f, acc1 = 0.f, acc2 = 0.f, acc3 = 0.f;
  int j = 0;
  for (; j + 3 < d; j += 4) {
    int jj = r0 + j;
    int s0 = src_s[jj + 0], s1 = src_s[jj + 1], s2 = src_s[jj + 2], s3 = src_s[jj + 3];
    float l0 = logit[jj + 0], l1 = logit[jj + 1], l2 = logit[jj + 2], l3 = logit[jj + 3];
    ush h0 = hn[(size_t)s0 * 64 + lane];
    ush h1 = hn[(size_t)s1 * 64 + lane];
    ush h2 = hn[(size_t)s2 * 64 + lane];
    ush h3 = hn[(size_t)s3 * 64 + lane];
    float w0 = __expf(l0), w1 = __expf(l1);
    float w2 = __expf(l2), w3 = __expf(l3);
    sum += (w0 + w1) + (w2 + w3);
    acc0 = fmaf(w0, bf2f(h0), acc0);
    acc1 = fmaf(w1, bf2f(h1), acc1);
    acc2 = fmaf(w2, bf2f(h2), acc2);
    acc3 = fmaf(w3, bf2f(h3), acc3);
  }
  for (; j < d; ++j) {
    int jj = r0 + j;
    float w = __expf(logit[jj]);
    sum += w;
    acc0 = fmaf(w, bf2f(hn[(size_t)src_s[jj] * 64 + lane]), acc0);
  }
  hnew[(size_t)n * 64 + lane] = ((acc0 + acc1) + (acc2 + acc3)) / sum;
}

// ---------------- NNConv phase A: per-node outer-product G accumulate (registers only) ---
__global__ __launch_bounds__(256, 4) void nnconv_G_kernel(
    const float* __restrict__ face, const float* __restrict__ ef_s,
    const int* __restrict__ rowptr, const int* __restrict__ deg, const int* __restrict__ src_s,
    ush* __restrict__ G) {
  int wave = (blockIdx.x * blockDim.x + threadIdx.x) >> 6;
  int lane = threadIdx.x & 63;
  if (wave >= NN) return;
  int n = wave, d = deg[n], r0 = rowptr[n];
  int k4 = lane >> 2, ib = lane & 3;
  float g[8], fs[8];
#pragma unroll
  for (int u = 0; u < 8; ++u) { g[u] = 0.f; fs[u] = 0.f; }
  int j = 0;
  for (; j + 1 < d; j += 2) {
    int jj = r0 + j;
    int s0 = src_s[jj], s1 = src_s[jj + 1];
    float ev0 = ef_s[(size_t)jj * 16 + k4];
    float ev1 = ef_s[(size_t)(jj + 1) * 16 + k4];
    const float4* fp0 = (const float4*)(face + (size_t)s0 * 32 + ib * 8);
    const float4* fp1 = (const float4*)(face + (size_t)s1 * 32 + ib * 8);
    float4 fa0 = fp0[0], fb0 = fp0[1];
    float4 fa1 = fp1[0], fb1 = fp1[1];
    g[0] = fmaf(ev0, fa0.x, g[0]); g[1] = fmaf(ev0, fa0.y, g[1]);
    g[2] = fmaf(ev0, fa0.z, g[2]); g[3] = fmaf(ev0, fa0.w, g[3]);
    g[4] = fmaf(ev0, fb0.x, g[4]); g[5] = fmaf(ev0, fb0.y, g[5]);
    g[6] = fmaf(ev0, fb0.z, g[6]); g[7] = fmaf(ev0, fb0.w, g[7]);
    g[0] = fmaf(ev1, fa1.x, g[0]); g[1] = fmaf(ev1, fa1.y, g[1]);
    g[2] = fmaf(ev1, fa1.z, g[2]); g[3] = fmaf(ev1, fa1.w, g[3]);
    g[4] = fmaf(ev1, fb1.x, g[4]); g[5] = fmaf(ev1, fb1.y, g[5]);
    g[6] = fmaf(ev1, fb1.z, g[6]); g[7] = fmaf(ev1, fb1.w, g[7]);
    if (k4 == 0) {
      fs[0] += fa0.x + fa1.x; fs[1] += fa0.y + fa1.y;
      fs[2] += fa0.z + fa1.z; fs[3] += fa0.w + fa1.w;
      fs[4] += fb0.x + fb1.x; fs[5] += fb0.y + fb1.y;
      fs[6] += fb0.z + fb1.z; fs[7] += fb0.w + fb1.w;
    }
  }
  if (j < d) {
    int jj = r0 + j;
    int s0 = src_s[jj];
    float ev0 = ef_s[(size_t)jj * 16 + k4];
    const float4* fp0 = (const float4*)(face + (size_t)s0 * 32 + ib * 8);
    float4 fa0 = fp0[0], fb0 = fp0[1];
    g[0] = fmaf(ev0, fa0.x, g[0]); g[1] = fmaf(ev0, fa0.y, g[1]);
    g[2] = fmaf(ev0, fa0.z, g[2]); g[3] = fmaf(ev0, fa0.w, g[3]);
    g[4] = fmaf(ev0, fb0.x, g[4]); g[5] = fmaf(ev0, fb0.y, g[5]);
    g[6] = fmaf(ev0, fb0.z, g[6]); g[7] = fmaf(ev0, fb0.w, g[7]);
    if (k4 == 0) {
      fs[0] += fa0.x; fs[1] += fa0.y; fs[2] += fa0.z; fs[3] += fa0.w;
      fs[4] += fb0.x; fs[5] += fb0.y; fs[6] += fb0.z; fs[7] += fb0.w;
    }
  }
  uint4 pv;
  pv.x = pack2(g[0], g[1]); pv.y = pack2(g[2], g[3]);
  pv.z = pack2(g[4], g[5]); pv.w = pack2(g[6], g[7]);
  *(uint4*)(G + (size_t)n * 544 + lane * 8) = pv;
  if (k4 == 0) {
    uint4 fv;
    fv.x = pack2(fs[0], fs[1]); fv.y = pack2(fs[2], fs[3]);
    fv.z = pack2(fs[4], fs[5]); fv.w = pack2(fs[6], fs[7]);
    *(uint4*)(G + (size_t)n * 544 + 512 + ib * 8) = fv;
  }
}

// ---------------- NNConv phase B: MFMA GEMM sArr = G(NNx544) @ W(544x32) ----------------
__global__ __launch_bounds__(256, 4) void gemm_G_mfma_kernel(const ush* __restrict__ G,
                                                             const ush* __restrict__ Wfrag,
                                                             float* __restrict__ sArr,
                                                             int rows) {
  int wave = (blockIdx.x * blockDim.x + threadIdx.x) >> 6;
  int lane = threadIdx.x & 63;
  int m0 = wave * 16;
  if (m0 >= rows) return;
  int arow = lane & 15;
  int aoff = (lane >> 4) * 8;
  const ush* gp = G + (size_t)(m0 + arow) * 544 + aoff;
  const ush* wp = Wfrag + lane * 8;
  f32x4 acc0 = {0.f, 0.f, 0.f, 0.f};
  f32x4 acc1 = {0.f, 0.f, 0.f, 0.f};
#pragma unroll 4
  for (int kk = 0; kk < 17; ++kk) {
    bf16x8 a = *(const bf16x8*)(gp + kk * 32);
    bf16x8 b0 = *(const bf16x8*)(wp + (size_t)(kk * 2 + 0) * 512);
    bf16x8 b1 = *(const bf16x8*)(wp + (size_t)(kk * 2 + 1) * 512);
    acc0 = __builtin_amdgcn_mfma_f32_16x16x32_bf16(a, b0, acc0, 0, 0, 0);
    acc1 = __builtin_amdgcn_mfma_f32_16x16x32_bf16(a, b1, acc1, 0, 0, 0);
  }
  int ccol = lane & 15;
  int crow = (lane >> 4) * 4;
#pragma unroll
  for (int j = 0; j < 4; ++j) {
    int r = m0 + crow + j;
    sArr[(size_t)r * 32 + ccol] = acc0[j];
    sArr[(size_t)r * 32 + 16 + ccol] = acc1[j];
  }
}

// ---------------- combine node_features + gate logit (fused; wave per node) --------------
__global__ void combine_gate_kernel(const float* __restrict__ hfin, const float* __restrict__ sArr,
                                    const int* __restrict__ deg, const float* __restrict__ nn_bias,
                                    const float* __restrict__ gate_w, const float* __restrict__ gate_b,
                                    float* __restrict__ out, float* __restrict__ g) {
  int wave = (blockIdx.x * blockDim.x + threadIdx.x) >> 6;
  int lane = threadIdx.x & 63;
  if (wave >= NN) return;
  int n = wave;
  float v0 = hfin[(size_t)n * 64 + lane];
  int c1 = lane + 64;
  float v1 = (c1 < 96)
                 ? sArr[(size_t)n * 32 + (c1 - 64)] / fmaxf((float)deg[n], 1.0f) + nn_bias[c1 - 64]
                 : 0.f;
  out[(size_t)n * 128 + lane] = v0;
  out[(size_t)n * 128 + c1] = v1;
  float p = v0 * gate_w[lane] + ((c1 < 96) ? v1 * gate_w[c1] : 0.f);
#pragma unroll
  for (int off = 32; off; off >>= 1) p += __shfl_xor(p, off, 64);
  if (lane == 0) g[n] = p + gate_b[0];
}

// ---------------- max over g (block-reduced, 1 atomic per block) ----------------
__global__ void gate_max_kernel(const float* __restrict__ g, unsigned* __restrict__ gmax) {
  int tid = blockIdx.x * blockDim.x + threadIdx.x;
  int stride = gridDim.x * blockDim.x;
  float v = -3.0e38f;
  for (int n = tid; n < NN; n += stride) v = fmaxf(v, g[n]);
#pragma unroll
  for (int off = 32; off; off >>= 1) v = fmaxf(v, __shfl_xor(v, off, 64));
  __shared__ float sm[4];
  int lane = threadIdx.x & 63, wid = threadIdx.x >> 6;
  if (lane == 0) sm[wid] = v;
  __syncthreads();
  if (threadIdx.x == 0) {
    float m = fmaxf(fmaxf(sm[0], sm[1]), fmaxf(sm[2], sm[3]));
    atomicMax(gmax, ord_enc(m));
  }
}

// ---------------- pooling: exp + weighted accumulate (fused) ----------------
__global__ void pool_exp_kernel(const float* __restrict__ nf, const float* __restrict__ g,
                                const unsigned* __restrict__ gmax, float* __restrict__ gacc,
                                float* __restrict__ gsum) {
  int o = threadIdx.x;  // blockDim = 128
  float m = ord_dec(*gmax);
  float acc = 0.f, ws = 0.f;
  for (int n = blockIdx.x; n < NN; n += gridDim.x) {
    float w = __expf(g[n] - m);
    ws += w;
    acc += w * nf[(size_t)n * 128 + o];
  }
  atomicAdd(gacc + o, acc);
  if (o == 0) atomicAdd(gsum, ws);
}

__global__ void finalize_kernel(const float* __restrict__ gacc, const float* __restrict__ gsum,
                                float* __restrict__ out) {
  int o = threadIdx.x;
  if (o < 128) out[(size_t)NN * 128 + o] = gacc[o] / gsum[0];
}

extern "C" void kernel_launch(void* const* d_in, const int* in_sizes, int n_in,
                              void* d_out, int out_size, void* d_ws, size_t ws_size,
                              hipStream_t stream) {
  const float* face    = (const float*)d_in[0];
  const float* ef      = (const float*)d_in[1];
  const float* fp_w    = (const float*)d_in[2];
  const float* fp_b    = (const float*)d_in[3];
  const float* ep_w    = (const float*)d_in[4];
  const float* ep_b    = (const float*)d_in[5];
  const float* nn_w    = (const float*)d_in[6];
  const float* nn_b    = (const float*)d_in[7];
  const float* nn_bias = (const float*)d_in[8];
  const float* gate_w  = (const float*)d_in[9];
  const float* gate_b  = (const float*)d_in[10];
  const int*   src     = (const int*)d_in[11];
  const int*   dst     = (const int*)d_in[12];
  const float* e1_attn = (const float*)d_in[17];
  const float* e2_ni   = (const float*)d_in[19];
  const float* e2_nj   = (const float*)d_in[20];
  const float* e2_fij  = (const float*)d_in[21];
  const float* e2_node = (const float*)d_in[22];
  const float* e2_attn = (const float*)d_in[23];
  const float* e2_bias = (const float*)d_in[24];
  float* out = (float*)d_out;

  char* p = (char*)d_ws;
  auto alloc = [&](size_t nfloats) {
    float* r = (float*)p;
    p += ((nfloats * 4 + 255) / 256) * 256;
    return r;
  };
  float* h0 = alloc((size_t)NN * 64);   // layer-2 output
  float* h1 = alloc((size_t)NN * 64);   // layer-1 output
  // big region: G (NN*544 bf16 = 65.28 MB) aliases hs16|hd16|hn16|f116|logit (dead post-EGAT)
  char* bigreg = p;
  ush* hs16 = (ush*)alloc((size_t)NN * 32);   // NN*64 bf16
  ush* hd16 = (ush*)alloc((size_t)NN * 32);
  ush* hn16 = (ush*)alloc((size_t)NN * 32);
  ush* f116 = (ush*)alloc((size_t)NE * 32);   // NE*64 bf16 (dst-sorted order)
  float* logit = alloc(NE);                   // dst-sorted order
  {  // pad bigreg to >= NN*544*2 bytes for G
    size_t used = (size_t)(p - bigreg);
    size_t need = (size_t)NN * 544 * 2;
    if (used < need) p += ((need - used + 255) / 256) * 256;
  }
  ush* G = (ush*)bigreg;
  float* sArr  = alloc((size_t)NN * 32);
  float* g     = alloc(NN);
  float* gacc  = alloc(128);
  float* gsum  = alloc(1);
  unsigned* gmax = (unsigned*)alloc(1);
  float* fold  = alloc(7424);
  ush* Wfrag   = (ush*)alloc(17408 / 2);      // 17408 bf16 (nn MFMA B-fragments)
  ush* Wfrag2  = (ush*)alloc(4096 / 2);       // 4096 bf16 (e2_fij MFMA B-fragments)
  // dst-CSR
  int* deg    = (int*)alloc(NN);
  int* rowptr = (int*)alloc(NN);
  int* cursor = (int*)alloc(NN);
  int* partial = (int*)alloc(256);
  int* src_s  = (int*)alloc(NE);
  int* dst_s  = (int*)alloc(NE);
  float* ef_s = alloc((size_t)NE * 16);       // permuted edge features

  const float* Wf1  = fold;
  const float* b1f  = fold + 1024;
  const float* Wni1 = fold + 1088;
  const float* Wnj1 = fold + 3136;
  const float* Wno1 = fold + 5184;
  const float* bni1 = fold + 7232;
  const float* bnj1 = fold + 7296;
  const float* bno1 = fold + 7360;

  const int B = 256;
  const int NGB = cdiv(NN, 128);
  const int EGB = cdiv(NE, 128);
  const int NB256 = cdiv(NN, 256);

  // ---- CSR build (dst-sorted) + fused edge permutation ----
  hipMemsetAsync(deg, 0, NN * 4, stream);
  deg_kernel<<<cdiv(NE, B), B, 0, stream>>>(dst, deg);
  scan1_kernel<<<NB256, 256, 0, stream>>>(deg, rowptr, partial);
  scan2_kernel<<<1, 256, 0, stream>>>(partial, NB256);
  scan3_kernel<<<NB256, 256, 0, stream>>>(rowptr, partial, cursor);
  scatter_dst_kernel<<<cdiv(NE, B), B, 0, stream>>>(src, dst, ef, cursor, src_s, dst_s, ef_s);

  // folded weights + MFMA fragment packs (tiny)
  fold_kernel<<<29, B, 0, stream>>>(fp_w, fp_b, ep_w, ep_b,
                                    (const float*)d_in[15], (const float*)d_in[18],
                                    (const float*)d_in[13], (const float*)d_in[14],
                                    (const float*)d_in[16], fold);
  nnwt_frag_kernel<<<68, B, 0, stream>>>(nn_w, nn_b, Wfrag);
  fij_frag_kernel<<<16, B, 0, stream>>>(e2_fij, Wfrag2);

  // ---- EGAT layer 1 (edges processed in dst-sorted order) ----
  gemm3_kernel<32, true><<<dim3(NGB, 3), B, 0, stream>>>(face, Wni1, Wnj1, Wno1, bni1, bnj1,
                                                         bno1, hs16, hd16, hn16, NN);
  gemm_fout_kernel<16, true><<<EGB, B, 0, stream>>>(ef_s, Wf1, b1f, hs16, hd16, src_s,
                                                    dst_s, e1_attn, f116, logit);
  agg_gather_kernel<<<cdiv(NN * 64, B), B, 0, stream>>>(hn16, logit, rowptr, deg, src_s, h1);

  // ---- EGAT layer 2 (edge GEMM on matrix cores) ----
  gemm3_kernel<64, false><<<dim3(NGB, 3), B, 0, stream>>>(h1, e2_ni, e2_nj, e2_node, nullptr,
                                                          nullptr, nullptr, hs16, hd16, hn16, NN);
  mfma_fout_kernel<<<cdiv(NE * 4, B), B, 0, stream>>>(f116, Wfrag2, e2_bias, hs16, hd16,
                                                      src_s, dst_s, e2_attn, logit);
  agg_gather_kernel<<<cdiv(NN * 64, B), B, 0, stream>>>(hn16, logit, rowptr, deg, src_s, h0);

  // ---- NNConv (outer-product form; G aliases dead EGAT buffers — runs after EGAT) ----
  nnconv_G_kernel<<<cdiv(NN * 64, B), B, 0, stream>>>(face, ef_s, rowptr, deg, src_s, G);
  gemm_G_mfma_kernel<<<cdiv(NN * 4, B), B, 0, stream>>>(G, Wfrag, sArr, NN);

  // ---- combine node features + gate logits ----
  hipMemsetAsync(gacc, 0, 128 * 4, stream);
  hipMemsetAsync(gsum, 0, 4, stream);
  hipMemsetAsync(gmax, 0, 4, stream);
  combine_gate_kernel<<<cdiv(NN * 64, B), B, 0, stream>>>(h0, sArr, deg, nn_bias, gate_w,
                                                          gate_b, out, g);
  gate_max_kernel<<<128, B, 0, stream>>>(g, gmax);
  pool_exp_kernel<<<512, 128, 0, stream>>>(out, g, gmax, gacc, gsum);
  finalize_kernel<<<1, 128, 0, stream>>>(gacc, gsum, out);
}

// Round 21
// 265.373 us; speedup vs baseline: 1.5146x; 1.1906x over previous
//
#include <hip/hip_runtime.h>

#define NN 60000
#define NE 300000
#define PB 768
typedef unsigned short ush;
typedef __attribute__((ext_vector_type(8))) short bf16x8;
typedef __attribute__((ext_vector_type(4))) float f32x4;

static inline int cdiv(int a, int b) { return (a + b - 1) / b; }

__device__ inline unsigned ord_enc(float x) {
  unsigned u = __float_as_uint(x);
  return (u & 0x80000000u) ? ~u : (u | 0x80000000u);
}
__device__ inline float ord_dec(unsigned u) {
  return __uint_as_float((u & 0x80000000u) ? (u & 0x7fffffffu) : ~u);
}
__device__ inline float bf2f(unsigned u16) { return __uint_as_float(u16 << 16); }
__device__ inline ush f2bf(float x) {
  unsigned u = __float_as_uint(x);
  return (ush)((u + 0x7FFFu + ((u >> 16) & 1u)) >> 16);
}
__device__ inline unsigned pack2(float lo, float hi) {
  return ((unsigned)f2bf(hi) << 16) | (unsigned)f2bf(lo);
}

// ================= CSR build (dst-sorted) =================
__global__ void deg_kernel(const int* __restrict__ key, int* __restrict__ deg) {
  int e = blockIdx.x * blockDim.x + threadIdx.x;
  if (e < NE) atomicAdd(deg + key[e], 1);
}

__global__ void scan1_kernel(const int* __restrict__ deg, int* __restrict__ rowptr,
                             int* __restrict__ partial) {
  __shared__ int s[256];
  int i = blockIdx.x * 256 + threadIdx.x;
  int v = (i < NN) ? deg[i] : 0;
  s[threadIdx.x] = v;
  __syncthreads();
  for (int off = 1; off < 256; off <<= 1) {
    int t = (threadIdx.x >= off) ? s[threadIdx.x - off] : 0;
    __syncthreads();
    s[threadIdx.x] += t;
    __syncthreads();
  }
  if (i < NN) rowptr[i] = s[threadIdx.x] - v;
  if (threadIdx.x == 255) partial[blockIdx.x] = s[255];
}

__global__ void scan2_kernel(int* __restrict__ partial, int nb) {
  __shared__ int s[256];
  int v = (threadIdx.x < nb) ? partial[threadIdx.x] : 0;
  s[threadIdx.x] = v;
  __syncthreads();
  for (int off = 1; off < 256; off <<= 1) {
    int t = (threadIdx.x >= off) ? s[threadIdx.x - off] : 0;
    __syncthreads();
    s[threadIdx.x] += t;
    __syncthreads();
  }
  if (threadIdx.x < nb) partial[threadIdx.x] = s[threadIdx.x] - v;
}

__global__ void scan3_kernel(int* __restrict__ rowptr, const int* __restrict__ partial,
                             int* __restrict__ cursor) {
  int i = blockIdx.x * 256 + threadIdx.x;
  if (i < NN) {
    int r = rowptr[i] + partial[blockIdx.x];
    rowptr[i] = r;
    cursor[i] = r;
  }
}

// scatter + ef permutation fused (sequential ef read, random 64B write)
__global__ void scatter_dst_kernel(const int* __restrict__ src, const int* __restrict__ dst,
                                   const float* __restrict__ ef, int* __restrict__ cursor,
                                   int* __restrict__ src_s, int* __restrict__ dst_s,
                                   float* __restrict__ ef_s) {
  int e = blockIdx.x * blockDim.x + threadIdx.x;
  if (e >= NE) return;
  int d = dst[e];
  int j = atomicAdd(cursor + d, 1);
  src_s[j] = src[e];
  dst_s[j] = d;
  const float4* ep = (const float4*)(ef + (size_t)e * 16);
  float4 a = ep[0], b = ep[1], c = ep[2], dd = ep[3];
  float4* op = (float4*)(ef_s + (size_t)j * 16);
  op[0] = a; op[1] = b; op[2] = c; op[3] = dd;
}

// ---------------- fold: precompute folded weight products (7424 dots of length 64) -------
__global__ void fold_kernel(const float* __restrict__ fp_w, const float* __restrict__ fp_b,
                            const float* __restrict__ ep_w, const float* __restrict__ ep_b,
                            const float* __restrict__ fij, const float* __restrict__ ebias,
                            const float* __restrict__ ni, const float* __restrict__ nj,
                            const float* __restrict__ node, float* __restrict__ fold) {
  int t = blockIdx.x * blockDim.x + threadIdx.x;
  if (t >= 7424) return;
  int o = t & 63;
  const float* A;
  const float* B;
  float init = 0.f;
  if (t < 1024)      { A = ep_w + (size_t)(t >> 6) * 64; B = fij + o; }
  else if (t < 1088) { A = ep_b; B = fij + o; init = ebias[o]; }
  else if (t < 3136) { A = fp_w + (size_t)((t - 1088) >> 6) * 64; B = ni + o; }
  else if (t < 5184) { A = fp_w + (size_t)((t - 3136) >> 6) * 64; B = nj + o; }
  else if (t < 7232) { A = fp_w + (size_t)((t - 5184) >> 6) * 64; B = node + o; }
  else if (t < 7296) { A = fp_b; B = ni + o; }
  else if (t < 7360) { A = fp_b; B = nj + o; }
  else               { A = fp_b; B = node + o; }
  float a = init;
  for (int i = 0; i < 64; ++i) a = fmaf(A[i], B[(size_t)i * 64], a);
  fold[t] = a;
}

// ---------------- pack nn_w/nn_b into MFMA B-fragment order (17 K-steps x 2 col tiles) ---
__global__ void nnwt_frag_kernel(const float* __restrict__ nn_w, const float* __restrict__ nn_b,
                                 ush* __restrict__ Wfrag) {
  int t = blockIdx.x * blockDim.x + threadIdx.x;
  if (t >= 17408) return;
  int i = t & 7, lane = (t >> 3) & 63, ct = (t >> 9) & 1, kk = t >> 10;
  int k = kk * 32 + (lane >> 4) * 8 + i;
  int o = ct * 16 + (lane & 15);
  float v = (k < 512) ? nn_w[(size_t)(k >> 5) * 1024 + (k & 31) * 32 + o]
                      : nn_b[(k - 512) * 32 + o];
  Wfrag[t] = f2bf(v);
}

// ---------------- pack e2_fij (64x64 f32) into MFMA B-frag order (2 kk x 4 col tiles) ----
__global__ void fij_frag_kernel(const float* __restrict__ fij, ush* __restrict__ Wfrag2) {
  int t = blockIdx.x * blockDim.x + threadIdx.x;
  if (t >= 4096) return;
  int i = t & 7, lane = (t >> 3) & 63, ct = (t >> 9) & 3, kk = t >> 11;
  int k = kk * 32 + (lane >> 4) * 8 + i;
  int o = ct * 16 + (lane & 15);
  Wfrag2[t] = f2bf(fij[(size_t)k * 64 + o]);
}

// ---------------- pack e2_{ni,nj,node} into MFMA B-frag order (3 mats x 2 kk x 4 ct) -----
__global__ void hproj_frag_kernel(const float* __restrict__ ni, const float* __restrict__ nj,
                                  const float* __restrict__ node, ush* __restrict__ WfragH) {
  int t = blockIdx.x * blockDim.x + threadIdx.x;
  if (t >= 12288) return;
  int i = t & 7, lane = (t >> 3) & 63, ct = (t >> 9) & 3, kk = (t >> 11) & 1, m = t >> 12;
  int k = kk * 32 + (lane >> 4) * 8 + i;
  int o = ct * 16 + (lane & 15);
  const float* W = (m == 0) ? ni : (m == 1) ? nj : node;
  WfragH[t] = f2bf(W[(size_t)k * 64 + o]);
}

// ---------------- tiled GEMM (rows x K) @ (K x 64) -> bf16 out; 3 weight sets ------------
template <int K, bool BIAS>
__global__ __launch_bounds__(256, 2) void gemm3_kernel(
    const float* __restrict__ A, const float* __restrict__ W0, const float* __restrict__ W1,
    const float* __restrict__ W2, const float* __restrict__ b0, const float* __restrict__ b1,
    const float* __restrict__ b2, ush* __restrict__ o0, ush* __restrict__ o1,
    ush* __restrict__ o2, int rows) {
  __shared__ float sA[128][K + 1];
  __shared__ float sW[K][64];
  const float* W = blockIdx.y == 0 ? W0 : blockIdx.y == 1 ? W1 : W2;
  const float* bb = blockIdx.y == 0 ? b0 : blockIdx.y == 1 ? b1 : b2;
  ush* out = blockIdx.y == 0 ? o0 : blockIdx.y == 1 ? o1 : o2;
  int t = threadIdx.x;
  int r0 = blockIdx.x * 128;
  for (int i = t; i < K * 16; i += 256) ((float4*)sW)[i] = ((const float4*)W)[i];
  for (int i = t; i < 128 * (K / 4); i += 256) {
    int rr = i / (K / 4), cc = i % (K / 4);
    float4 v = (r0 + rr < rows) ? ((const float4*)(A + (size_t)(r0 + rr) * K))[cc]
                                : make_float4(0.f, 0.f, 0.f, 0.f);
    sA[rr][cc * 4 + 0] = v.x;
    sA[rr][cc * 4 + 1] = v.y;
    sA[rr][cc * 4 + 2] = v.z;
    sA[rr][cc * 4 + 3] = v.w;
  }
  __syncthreads();
  int rg = t >> 3, cg = t & 7;
  float acc[4][8];
#pragma unroll
  for (int i = 0; i < 4; ++i)
#pragma unroll
    for (int j = 0; j < 8; ++j) acc[i][j] = 0.f;
#pragma unroll 8
  for (int k = 0; k < K; ++k) {
    float a0 = sA[rg * 4 + 0][k], a1 = sA[rg * 4 + 1][k];
    float a2 = sA[rg * 4 + 2][k], a3 = sA[rg * 4 + 3][k];
    float4 wA = *(const float4*)&sW[k][cg * 8];
    float4 wB = *(const float4*)&sW[k][cg * 8 + 4];
#pragma unroll
    for (int i = 0; i < 4; ++i) {
      float a = i == 0 ? a0 : i == 1 ? a1 : i == 2 ? a2 : a3;
      acc[i][0] = fmaf(a, wA.x, acc[i][0]); acc[i][1] = fmaf(a, wA.y, acc[i][1]);
      acc[i][2] = fmaf(a, wA.z, acc[i][2]); acc[i][3] = fmaf(a, wA.w, acc[i][3]);
      acc[i][4] = fmaf(a, wB.x, acc[i][4]); acc[i][5] = fmaf(a, wB.y, acc[i][5]);
      acc[i][6] = fmaf(a, wB.z, acc[i][6]); acc[i][7] = fmaf(a, wB.w, acc[i][7]);
    }
  }
  float bv[8];
#pragma unroll
  for (int j = 0; j < 8; ++j) bv[j] = BIAS ? bb[cg * 8 + j] : 0.f;
#pragma unroll
  for (int i = 0; i < 4; ++i) {
    int r = r0 + rg * 4 + i;
    if (r < rows) {
      uint4 pv;
      pv.x = pack2(acc[i][0] + bv[0], acc[i][1] + bv[1]);
      pv.y = pack2(acc[i][2] + bv[2], acc[i][3] + bv[3]);
      pv.z = pack2(acc[i][4] + bv[4], acc[i][5] + bv[5]);
      pv.w = pack2(acc[i][6] + bv[6], acc[i][7] + bv[7]);
      *(uint4*)(out + (size_t)r * 64 + cg * 8) = pv;
    }
  }
}

// ---------------- layer-1 edge GEMM (K=16, f32 A) + fused f_out epilogue -----------------
template <int K, bool STORE>
__global__ __launch_bounds__(256, 2) void gemm_fout_kernel(
    const float* __restrict__ A, const float* __restrict__ W, const float* __restrict__ bias,
    const ush* __restrict__ hs, const ush* __restrict__ hd, const int* __restrict__ src_s,
    const int* __restrict__ dst_s, const float* __restrict__ attn, ush* __restrict__ fstore,
    float* __restrict__ logit) {
  __shared__ float sA[128][K + 1];
  __shared__ float sW[K][64];
  int t = threadIdx.x;
  int r0 = blockIdx.x * 128;
  for (int i = t; i < K * 16; i += 256) ((float4*)sW)[i] = ((const float4*)W)[i];
  for (int i = t; i < 128 * (K / 4); i += 256) {
    int rr = i / (K / 4), cc = i % (K / 4);
    float4 v = (r0 + rr < NE) ? ((const float4*)(A + (size_t)(r0 + rr) * K))[cc]
                              : make_float4(0.f, 0.f, 0.f, 0.f);
    sA[rr][cc * 4 + 0] = v.x;
    sA[rr][cc * 4 + 1] = v.y;
    sA[rr][cc * 4 + 2] = v.z;
    sA[rr][cc * 4 + 3] = v.w;
  }
  __syncthreads();
  int rg = t >> 3, cg = t & 7;
  float acc[4][8];
#pragma unroll
  for (int i = 0; i < 4; ++i)
#pragma unroll
    for (int j = 0; j < 8; ++j) acc[i][j] = 0.f;
#pragma unroll 8
  for (int k = 0; k < K; ++k) {
    float a0 = sA[rg * 4 + 0][k], a1 = sA[rg * 4 + 1][k];
    float a2 = sA[rg * 4 + 2][k], a3 = sA[rg * 4 + 3][k];
    float4 wA = *(const float4*)&sW[k][cg * 8];
    float4 wB = *(const float4*)&sW[k][cg * 8 + 4];
#pragma unroll
    for (int i = 0; i < 4; ++i) {
      float a = i == 0 ? a0 : i == 1 ? a1 : i == 2 ? a2 : a3;
      acc[i][0] = fmaf(a, wA.x, acc[i][0]); acc[i][1] = fmaf(a, wA.y, acc[i][1]);
      acc[i][2] = fmaf(a, wA.z, acc[i][2]); acc[i][3] = fmaf(a, wA.w, acc[i][3]);
      acc[i][4] = fmaf(a, wB.x, acc[i][4]); acc[i][5] = fmaf(a, wB.y, acc[i][5]);
      acc[i][6] = fmaf(a, wB.z, acc[i][6]); acc[i][7] = fmaf(a, wB.w, acc[i][7]);
    }
  }
  float bv[8], av[8];
#pragma unroll
  for (int j = 0; j < 8; ++j) {
    bv[j] = bias[cg * 8 + j];
    av[j] = attn[cg * 8 + j];
  }
#pragma unroll
  for (int i = 0; i < 4; ++i) {
    int r = r0 + rg * 4 + i;
    if (r < NE) {
      int s = src_s[r], d = dst_s[r];
      uint4 hv = *(const uint4*)(hs + (size_t)s * 64 + cg * 8);
      uint4 dv = *(const uint4*)(hd + (size_t)d * 64 + cg * 8);
      float fo[8];
      fo[0] = acc[i][0] + bf2f(hv.x & 0xffff) + bf2f(dv.x & 0xffff) + bv[0];
      fo[1] = acc[i][1] + bf2f(hv.x >> 16)    + bf2f(dv.x >> 16)    + bv[1];
      fo[2] = acc[i][2] + bf2f(hv.y & 0xffff) + bf2f(dv.y & 0xffff) + bv[2];
      fo[3] = acc[i][3] + bf2f(hv.y >> 16)    + bf2f(dv.y >> 16)    + bv[3];
      fo[4] = acc[i][4] + bf2f(hv.z & 0xffff) + bf2f(dv.z & 0xffff) + bv[4];
      fo[5] = acc[i][5] + bf2f(hv.z >> 16)    + bf2f(dv.z >> 16)    + bv[5];
      fo[6] = acc[i][6] + bf2f(hv.w & 0xffff) + bf2f(dv.w & 0xffff) + bv[6];
      fo[7] = acc[i][7] + bf2f(hv.w >> 16)    + bf2f(dv.w >> 16)    + bv[7];
      float p = 0.f;
#pragma unroll
      for (int j = 0; j < 8; ++j) {
        fo[j] = fo[j] >= 0.f ? fo[j] : 0.01f * fo[j];  // LeakyReLU
        p = fmaf(fo[j], av[j], p);
      }
      if (STORE) {
        uint4 pv;
        pv.x = pack2(fo[0], fo[1]);
        pv.y = pack2(fo[2], fo[3]);
        pv.z = pack2(fo[4], fo[5]);
        pv.w = pack2(fo[6], fo[7]);
        *(uint4*)(fstore + (size_t)r * 64 + cg * 8) = pv;
      }
      p += __shfl_xor(p, 1, 64);
      p += __shfl_xor(p, 2, 64);
      p += __shfl_xor(p, 4, 64);
      if (cg == 0) logit[r] = p;
    }
  }
}

// ---------------- layer-2 hproj via MFMA: h1bf(NNx64) @ {ni,nj,node}(64x64) --------------
__global__ __launch_bounds__(256, 4) void mfma_hproj_kernel(
    const ush* __restrict__ h1bf, const ush* __restrict__ WfragH, ush* __restrict__ hs,
    ush* __restrict__ hd, ush* __restrict__ hn) {
  int wave = (blockIdx.x * blockDim.x + threadIdx.x) >> 6;
  int lane = threadIdx.x & 63;
  int m0 = wave * 16;
  if (m0 >= NN) return;
  int arow = lane & 15;
  int aoff = (lane >> 4) * 8;
  const ush* ap = h1bf + (size_t)(m0 + arow) * 64 + aoff;
  bf16x8 a0 = *(const bf16x8*)(ap);
  bf16x8 a1 = *(const bf16x8*)(ap + 32);
  const ush* wp = WfragH + lane * 8;
  int ccol = lane & 15;
  int crow = (lane >> 4) * 4;
#pragma unroll
  for (int m = 0; m < 3; ++m) {
    f32x4 acc0 = {0.f, 0.f, 0.f, 0.f};
    f32x4 acc1 = {0.f, 0.f, 0.f, 0.f};
    f32x4 acc2 = {0.f, 0.f, 0.f, 0.f};
    f32x4 acc3 = {0.f, 0.f, 0.f, 0.f};
    const ush* wm = wp + (size_t)m * 8 * 512;
    bf16x8 b0 = *(const bf16x8*)(wm + 0 * 512);
    bf16x8 b1 = *(const bf16x8*)(wm + 1 * 512);
    bf16x8 b2 = *(const bf16x8*)(wm + 2 * 512);
    bf16x8 b3 = *(const bf16x8*)(wm + 3 * 512);
    acc0 = __builtin_amdgcn_mfma_f32_16x16x32_bf16(a0, b0, acc0, 0, 0, 0);
    acc1 = __builtin_amdgcn_mfma_f32_16x16x32_bf16(a0, b1, acc1, 0, 0, 0);
    acc2 = __builtin_amdgcn_mfma_f32_16x16x32_bf16(a0, b2, acc2, 0, 0, 0);
    acc3 = __builtin_amdgcn_mfma_f32_16x16x32_bf16(a0, b3, acc3, 0, 0, 0);
    b0 = *(const bf16x8*)(wm + 4 * 512);
    b1 = *(const bf16x8*)(wm + 5 * 512);
    b2 = *(const bf16x8*)(wm + 6 * 512);
    b3 = *(const bf16x8*)(wm + 7 * 512);
    acc0 = __builtin_amdgcn_mfma_f32_16x16x32_bf16(a1, b0, acc0, 0, 0, 0);
    acc1 = __builtin_amdgcn_mfma_f32_16x16x32_bf16(a1, b1, acc1, 0, 0, 0);
    acc2 = __builtin_amdgcn_mfma_f32_16x16x32_bf16(a1, b2, acc2, 0, 0, 0);
    acc3 = __builtin_amdgcn_mfma_f32_16x16x32_bf16(a1, b3, acc3, 0, 0, 0);
    ush* outm = (m == 0) ? hs : (m == 1) ? hd : hn;
#pragma unroll
    for (int j = 0; j < 4; ++j) {
      ush* op = outm + (size_t)(m0 + crow + j) * 64;
      op[ccol] = f2bf(acc0[j]);
      op[16 + ccol] = f2bf(acc1[j]);
      op[32 + ccol] = f2bf(acc2[j]);
      op[48 + ccol] = f2bf(acc3[j]);
    }
  }
}

// ---------------- layer-2 edge GEMM via MFMA: f116(NEx64 bf16) @ fij(64x64) --------------
__global__ __launch_bounds__(256, 4) void mfma_fout_kernel(
    const ush* __restrict__ f116, const ush* __restrict__ Wfrag2, const float* __restrict__ bias,
    const ush* __restrict__ hs, const ush* __restrict__ hd, const int* __restrict__ src_s,
    const int* __restrict__ dst_s, const float* __restrict__ attn, float* __restrict__ logit) {
  int wave = (blockIdx.x * blockDim.x + threadIdx.x) >> 6;
  int lane = threadIdx.x & 63;
  int m0 = wave * 16;
  if (m0 >= NE) return;
  int arow = lane & 15;
  int aoff = (lane >> 4) * 8;
  const ush* ap = f116 + (size_t)(m0 + arow) * 64 + aoff;
  const ush* wp = Wfrag2 + lane * 8;
  f32x4 acc0 = {0.f, 0.f, 0.f, 0.f};
  f32x4 acc1 = {0.f, 0.f, 0.f, 0.f};
  f32x4 acc2 = {0.f, 0.f, 0.f, 0.f};
  f32x4 acc3 = {0.f, 0.f, 0.f, 0.f};
#pragma unroll
  for (int kk = 0; kk < 2; ++kk) {
    bf16x8 a = *(const bf16x8*)(ap + kk * 32);
    bf16x8 b0 = *(const bf16x8*)(wp + (size_t)(kk * 4 + 0) * 512);
    bf16x8 b1 = *(const bf16x8*)(wp + (size_t)(kk * 4 + 1) * 512);
    bf16x8 b2 = *(const bf16x8*)(wp + (size_t)(kk * 4 + 2) * 512);
    bf16x8 b3 = *(const bf16x8*)(wp + (size_t)(kk * 4 + 3) * 512);
    acc0 = __builtin_amdgcn_mfma_f32_16x16x32_bf16(a, b0, acc0, 0, 0, 0);
    acc1 = __builtin_amdgcn_mfma_f32_16x16x32_bf16(a, b1, acc1, 0, 0, 0);
    acc2 = __builtin_amdgcn_mfma_f32_16x16x32_bf16(a, b2, acc2, 0, 0, 0);
    acc3 = __builtin_amdgcn_mfma_f32_16x16x32_bf16(a, b3, acc3, 0, 0, 0);
  }
  int ccol = lane & 15;
  int crow = (lane >> 4) * 4;
  float av0 = attn[ccol], av1 = attn[16 + ccol], av2 = attn[32 + ccol], av3 = attn[48 + ccol];
  float bv0 = bias[ccol], bv1 = bias[16 + ccol], bv2 = bias[32 + ccol], bv3 = bias[48 + ccol];
#pragma unroll
  for (int j = 0; j < 4; ++j) {
    int r = m0 + crow + j;
    int s = src_s[r], d = dst_s[r];
    const ush* hsp = hs + (size_t)s * 64;
    const ush* hdp = hd + (size_t)d * 64;
    float f0 = acc0[j] + bf2f(hsp[ccol]) + bf2f(hdp[ccol]) + bv0;
    float f1 = acc1[j] + bf2f(hsp[16 + ccol]) + bf2f(hdp[16 + ccol]) + bv1;
    float f2 = acc2[j] + bf2f(hsp[32 + ccol]) + bf2f(hdp[32 + ccol]) + bv2;
    float f3 = acc3[j] + bf2f(hsp[48 + ccol]) + bf2f(hdp[48 + ccol]) + bv3;
    f0 = f0 >= 0.f ? f0 : 0.01f * f0;
    f1 = f1 >= 0.f ? f1 : 0.01f * f1;
    f2 = f2 >= 0.f ? f2 : 0.01f * f2;
    f3 = f3 >= 0.f ? f3 : 0.01f * f3;
    float p = fmaf(f0, av0, fmaf(f1, av1, fmaf(f2, av2, f3 * av3)));
    p += __shfl_xor(p, 1, 64);
    p += __shfl_xor(p, 2, 64);
    p += __shfl_xor(p, 4, 64);
    p += __shfl_xor(p, 8, 64);
    if (ccol == 0) logit[r] = p;
  }
}

// ---------------- EGAT: gather-aggregate (BF16OUT: h_out stored as bf16) -----------------
template <bool BF16OUT>
__global__ __launch_bounds__(256, 4) void agg_gather_kernel(
    const ush* __restrict__ hn, const float* __restrict__ logit, const int* __restrict__ rowptr,
    const int* __restrict__ deg, const int* __restrict__ src_s, void* __restrict__ hnew) {
  int wave = (blockIdx.x * blockDim.x + threadIdx.x) >> 6;
  int lane = threadIdx.x & 63;
  if (wave >= NN) return;
  int n = wave, d = deg[n], r0 = rowptr[n];
  if (d == 0) {
    if (BF16OUT) ((ush*)hnew)[(size_t)n * 64 + lane] = 0;
    else ((float*)hnew)[(size_t)n * 64 + lane] = 0.f;
    return;
  }
  float sum = 0.f, acc0 = 0.f, acc1 = 0.f, acc2 = 0.f, acc3 = 0.f;
  int j = 0;
  for (; j + 3 < d; j += 4) {
    int jj = r0 + j;
    int s0 = src_s[jj + 0], s1 = src_s[jj + 1], s2 = src_s[jj + 2], s3 = src_s[jj + 3];
    float l0 = logit[jj + 0], l1 = logit[jj + 1], l2 = logit[jj + 2], l3 = logit[jj + 3];
    ush h0 = hn[(size_t)s0 * 64 + lane];
    ush h1 = hn[(size_t)s1 * 64 + lane];
    ush h2 = hn[(size_t)s2 * 64 + lane];
    ush h3 = hn[(size_t)s3 * 64 + lane];
    float w0 = __expf(l0), w1 = __expf(l1);
    float w2 = __expf(l2), w3 = __expf(l3);
    sum += (w0 + w1) + (w2 + w3);
    acc0 = fmaf(w0, bf2f(h0), acc0);
    acc1 = fmaf(w1, bf2f(h1), acc1);
    acc2 = fmaf(w2, bf2f(h2), acc2);
    acc3 = fmaf(w3, bf2f(h3), acc3);
  }
  for (; j < d; ++j) {
    int jj = r0 + j;
    float w = __expf(logit[jj]);
    sum += w;
    acc0 = fmaf(w, bf2f(hn[(size_t)src_s[jj] * 64 + lane]), acc0);
  }
  float r = ((acc0 + acc1) + (acc2 + acc3)) / sum;
  if (BF16OUT) ((ush*)hnew)[(size_t)n * 64 + lane] = f2bf(r);
  else ((float*)hnew)[(size_t)n * 64 + lane] = r;
}

// ---------------- NNConv phase A: per-node outer-product G accumulate (registers only) ---
__global__ __launch_bounds__(256, 4) void nnconv_G_kernel(
    const float* __restrict__ face, const float* __restrict__ ef_s,
    const int* __restrict__ rowptr, const int* __restrict__ deg, const int* __restrict__ src_s,
    ush* __restrict__ G) {
  int wave = (blockIdx.x * blockDim.x + threadIdx.x) >> 6;
  int lane = threadIdx.x & 63;
  if (wave >= NN) return;
  int n = wave, d = deg[n], r0 = rowptr[n];
  int k4 = lane >> 2, ib = lane & 3;
  float g[8], fs[8];
#pragma unroll
  for (int u = 0; u < 8; ++u) { g[u] = 0.f; fs[u] = 0.f; }
  int j = 0;
  for (; j + 1 < d; j += 2) {
    int jj = r0 + j;
    int s0 = src_s[jj], s1 = src_s[jj + 1];
    float ev0 = ef_s[(size_t)jj * 16 + k4];
    float ev1 = ef_s[(size_t)(jj + 1) * 16 + k4];
    const float4* fp0 = (const float4*)(face + (size_t)s0 * 32 + ib * 8);
    const float4* fp1 = (const float4*)(face + (size_t)s1 * 32 + ib * 8);
    float4 fa0 = fp0[0], fb0 = fp0[1];
    float4 fa1 = fp1[0], fb1 = fp1[1];
    g[0] = fmaf(ev0, fa0.x, g[0]); g[1] = fmaf(ev0, fa0.y, g[1]);
    g[2] = fmaf(ev0, fa0.z, g[2]); g[3] = fmaf(ev0, fa0.w, g[3]);
    g[4] = fmaf(ev0, fb0.x, g[4]); g[5] = fmaf(ev0, fb0.y, g[5]);
    g[6] = fmaf(ev0, fb0.z, g[6]); g[7] = fmaf(ev0, fb0.w, g[7]);
    g[0] = fmaf(ev1, fa1.x, g[0]); g[1] = fmaf(ev1, fa1.y, g[1]);
    g[2] = fmaf(ev1, fa1.z, g[2]); g[3] = fmaf(ev1, fa1.w, g[3]);
    g[4] = fmaf(ev1, fb1.x, g[4]); g[5] = fmaf(ev1, fb1.y, g[5]);
    g[6] = fmaf(ev1, fb1.z, g[6]); g[7] = fmaf(ev1, fb1.w, g[7]);
    if (k4 == 0) {
      fs[0] += fa0.x + fa1.x; fs[1] += fa0.y + fa1.y;
      fs[2] += fa0.z + fa1.z; fs[3] += fa0.w + fa1.w;
      fs[4] += fb0.x + fb1.x; fs[5] += fb0.y + fb1.y;
      fs[6] += fb0.z + fb1.z; fs[7] += fb0.w + fb1.w;
    }
  }
  if (j < d) {
    int jj = r0 + j;
    int s0 = src_s[jj];
    float ev0 = ef_s[(size_t)jj * 16 + k4];
    const float4* fp0 = (const float4*)(face + (size_t)s0 * 32 + ib * 8);
    float4 fa0 = fp0[0], fb0 = fp0[1];
    g[0] = fmaf(ev0, fa0.x, g[0]); g[1] = fmaf(ev0, fa0.y, g[1]);
    g[2] = fmaf(ev0, fa0.z, g[2]); g[3] = fmaf(ev0, fa0.w, g[3]);
    g[4] = fmaf(ev0, fb0.x, g[4]); g[5] = fmaf(ev0, fb0.y, g[5]);
    g[6] = fmaf(ev0, fb0.z, g[6]); g[7] = fmaf(ev0, fb0.w, g[7]);
    if (k4 == 0) {
      fs[0] += fa0.x; fs[1] += fa0.y; fs[2] += fa0.z; fs[3] += fa0.w;
      fs[4] += fb0.x; fs[5] += fb0.y; fs[6] += fb0.z; fs[7] += fb0.w;
    }
  }
  uint4 pv;
  pv.x = pack2(g[0], g[1]); pv.y = pack2(g[2], g[3]);
  pv.z = pack2(g[4], g[5]); pv.w = pack2(g[6], g[7]);
  *(uint4*)(G + (size_t)n * 544 + lane * 8) = pv;
  if (k4 == 0) {
    uint4 fv;
    fv.x = pack2(fs[0], fs[1]); fv.y = pack2(fs[2], fs[3]);
    fv.z = pack2(fs[4], fs[5]); fv.w = pack2(fs[6], fs[7]);
    *(uint4*)(G + (size_t)n * 544 + 512 + ib * 8) = fv;
  }
}

// ---------------- NNConv phase B: MFMA GEMM sArr = G(NNx544) @ W(544x32) ----------------
__global__ __launch_bounds__(256, 4) void gemm_G_mfma_kernel(const ush* __restrict__ G,
                                                             const ush* __restrict__ Wfrag,
                                                             float* __restrict__ sArr,
                                                             int rows) {
  int wave = (blockIdx.x * blockDim.x + threadIdx.x) >> 6;
  int lane = threadIdx.x & 63;
  int m0 = wave * 16;
  if (m0 >= rows) return;
  int arow = lane & 15;
  int aoff = (lane >> 4) * 8;
  const ush* gp = G + (size_t)(m0 + arow) * 544 + aoff;
  const ush* wp = Wfrag + lane * 8;
  f32x4 acc0 = {0.f, 0.f, 0.f, 0.f};
  f32x4 acc1 = {0.f, 0.f, 0.f, 0.f};
#pragma unroll 4
  for (int kk = 0; kk < 17; ++kk) {
    bf16x8 a = *(const bf16x8*)(gp + kk * 32);
    bf16x8 b0 = *(const bf16x8*)(wp + (size_t)(kk * 2 + 0) * 512);
    bf16x8 b1 = *(const bf16x8*)(wp + (size_t)(kk * 2 + 1) * 512);
    acc0 = __builtin_amdgcn_mfma_f32_16x16x32_bf16(a, b0, acc0, 0, 0, 0);
    acc1 = __builtin_amdgcn_mfma_f32_16x16x32_bf16(a, b1, acc1, 0, 0, 0);
  }
  int ccol = lane & 15;
  int crow = (lane >> 4) * 4;
#pragma unroll
  for (int j = 0; j < 4; ++j) {
    int r = m0 + crow + j;
    sArr[(size_t)r * 32 + ccol] = acc0[j];
    sArr[(size_t)r * 32 + 16 + ccol] = acc1[j];
  }
}

// ---------------- combine node_features + gate logit (fused; wave per node) --------------
__global__ void combine_gate_kernel(const float* __restrict__ hfin, const float* __restrict__ sArr,
                                    const int* __restrict__ deg, const float* __restrict__ nn_bias,
                                    const float* __restrict__ gate_w, const float* __restrict__ gate_b,
                                    float* __restrict__ out, float* __restrict__ g) {
  int wave = (blockIdx.x * blockDim.x + threadIdx.x) >> 6;
  int lane = threadIdx.x & 63;
  if (wave >= NN) return;
  int n = wave;
  float v0 = hfin[(size_t)n * 64 + lane];
  int c1 = lane + 64;
  float v1 = (c1 < 96)
                 ? sArr[(size_t)n * 32 + (c1 - 64)] / fmaxf((float)deg[n], 1.0f) + nn_bias[c1 - 64]
                 : 0.f;
  out[(size_t)n * 128 + lane] = v0;
  out[(size_t)n * 128 + c1] = v1;
  float p = v0 * gate_w[lane] + ((c1 < 96) ? v1 * gate_w[c1] : 0.f);
#pragma unroll
  for (int off = 32; off; off >>= 1) p += __shfl_xor(p, off, 64);
  if (lane == 0) g[n] = p + gate_b[0];
}

// ---------------- max over g (block-reduced, 1 atomic per block) ----------------
__global__ void gate_max_kernel(const float* __restrict__ g, unsigned* __restrict__ gmax) {
  int tid = blockIdx.x * blockDim.x + threadIdx.x;
  int stride = gridDim.x * blockDim.x;
  float v = -3.0e38f;
  for (int n = tid; n < NN; n += stride) v = fmaxf(v, g[n]);
#pragma unroll
  for (int off = 32; off; off >>= 1) v = fmaxf(v, __shfl_xor(v, off, 64));
  __shared__ float sm[4];
  int lane = threadIdx.x & 63, wid = threadIdx.x >> 6;
  if (lane == 0) sm[wid] = v;
  __syncthreads();
  if (threadIdx.x == 0) {
    float m = fmaxf(fmaxf(sm[0], sm[1]), fmaxf(sm[2], sm[3]));
    atomicMax(gmax, ord_enc(m));
  }
}

// ---------------- pooling: exp + weighted accumulate into per-row-stream partials --------
// block = 256 (two node-streams of 128 threads); grid = PB; no atomics.
__global__ __launch_bounds__(256, 4) void pool_exp_kernel(
    const float* __restrict__ nf, const float* __restrict__ g, const unsigned* __restrict__ gmax,
    float* __restrict__ pacc, float* __restrict__ wsb) {
  int o = threadIdx.x & 127;
  int half = threadIdx.x >> 7;
  int ri = blockIdx.x * 2 + half;   // 0 .. 2*PB-1
  float m = ord_dec(*gmax);
  float acc0 = 0.f, acc1 = 0.f, ws = 0.f;
  int n = ri;
  const int STR = PB * 2;
  for (; n + STR < NN; n += STR * 2) {
    float w0 = __expf(g[n] - m);
    float w1 = __expf(g[n + STR] - m);
    float v0 = nf[(size_t)n * 128 + o];
    float v1 = nf[(size_t)(n + STR) * 128 + o];
    ws += w0 + w1;
    acc0 = fmaf(w0, v0, acc0);
    acc1 = fmaf(w1, v1, acc1);
  }
  if (n < NN) {
    float w = __expf(g[n] - m);
    ws += w;
    acc0 = fmaf(w, nf[(size_t)n * 128 + o], acc0);
  }
  pacc[(size_t)ri * 128 + o] = acc0 + acc1;
  if (o == 0) wsb[ri] = ws;
}

// reduce partials: 129 blocks; block o<128 sums pacc column o; block 128 sums wsb.
__global__ void pool_reduce_kernel(const float* __restrict__ pacc, const float* __restrict__ wsb,
                                   float* __restrict__ gacc, float* __restrict__ gsum) {
  int b = blockIdx.x;
  int t = threadIdx.x;  // 256
  float v = 0.f;
  if (b < 128) {
    for (int ri = t; ri < PB * 2; ri += 256) v += pacc[(size_t)ri * 128 + b];
  } else {
    for (int ri = t; ri < PB * 2; ri += 256) v += wsb[ri];
  }
#pragma unroll
  for (int off = 32; off; off >>= 1) v += __shfl_xor(v, off, 64);
  __shared__ float sm[4];
  int lane = t & 63, wid = t >> 6;
  if (lane == 0) sm[wid] = v;
  __syncthreads();
  if (t == 0) {
    float s = (sm[0] + sm[1]) + (sm[2] + sm[3]);
    if (b < 128) gacc[b] = s;
    else gsum[0] = s;
  }
}

__global__ void finalize_kernel(const float* __restrict__ gacc, const float* __restrict__ gsum,
                                float* __restrict__ out) {
  int o = threadIdx.x;
  if (o < 128) out[(size_t)NN * 128 + o] = gacc[o] / gsum[0];
}

extern "C" void kernel_launch(void* const* d_in, const int* in_sizes, int n_in,
                              void* d_out, int out_size, void* d_ws, size_t ws_size,
                              hipStream_t stream) {
  const float* face    = (const float*)d_in[0];
  const float* ef      = (const float*)d_in[1];
  const float* fp_w    = (const float*)d_in[2];
  const float* fp_b    = (const float*)d_in[3];
  const float* ep_w    = (const float*)d_in[4];
  const float* ep_b    = (const float*)d_in[5];
  const float* nn_w    = (const float*)d_in[6];
  const float* nn_b    = (const float*)d_in[7];
  const float* nn_bias = (const float*)d_in[8];
  const float* gate_w  = (const float*)d_in[9];
  const float* gate_b  = (const float*)d_in[10];
  const int*   src     = (const int*)d_in[11];
  const int*   dst     = (const int*)d_in[12];
  const float* e1_attn = (const float*)d_in[17];
  const float* e2_ni   = (const float*)d_in[19];
  const float* e2_nj   = (const float*)d_in[20];
  const float* e2_fij  = (const float*)d_in[21];
  const float* e2_attn = (const float*)d_in[23];
  const float* e2_bias = (const float*)d_in[24];
  float* out = (float*)d_out;

  char* p = (char*)d_ws;
  auto alloc = [&](size_t nfloats) {
    float* r = (float*)p;
    p += ((nfloats * 4 + 255) / 256) * 256;
    return r;
  };
  float* h0 = alloc((size_t)NN * 64);         // layer-2 output (f32)
  ush* h1bf = (ush*)alloc((size_t)NN * 32);   // layer-1 output (bf16)
  // big region: G (NN*544 bf16 = 65.28 MB) aliases hs16|hd16|hn16|f116|logit (dead post-EGAT)
  char* bigreg = p;
  ush* hs16 = (ush*)alloc((size_t)NN * 32);   // NN*64 bf16
  ush* hd16 = (ush*)alloc((size_t)NN * 32);
  ush* hn16 = (ush*)alloc((size_t)NN * 32);
  ush* f116 = (ush*)alloc((size_t)NE * 32);   // NE*64 bf16 (dst-sorted order)
  float* logit = alloc(NE);                   // dst-sorted order
  {  // pad bigreg to >= NN*544*2 bytes for G
    size_t used = (size_t)(p - bigreg);
    size_t need = (size_t)NN * 544 * 2;
    if (used < need) p += ((need - used + 255) / 256) * 256;
  }
  ush* G = (ush*)bigreg;
  float* sArr  = alloc((size_t)NN * 32);
  float* g     = alloc(NN);
  float* gacc  = alloc(128);
  float* gsum  = alloc(1);
  unsigned* gmax = (unsigned*)alloc(1);
  float* fold  = alloc(7424);
  ush* Wfrag   = (ush*)alloc(17408 / 2);      // nn MFMA B-fragments
  ush* Wfrag2  = (ush*)alloc(4096 / 2);       // e2_fij MFMA B-fragments
  ush* WfragH  = (ush*)alloc(12288 / 2);      // e2_{ni,nj,node} MFMA B-fragments
  float* pacc  = alloc((size_t)PB * 2 * 128); // pooling partials
  float* wsb   = alloc(PB * 2);
  // dst-CSR
  int* deg    = (int*)alloc(NN);
  int* rowptr = (int*)alloc(NN);
  int* cursor = (int*)alloc(NN);
  int* partial = (int*)alloc(256);
  int* src_s  = (int*)alloc(NE);
  int* dst_s  = (int*)alloc(NE);
  float* ef_s = alloc((size_t)NE * 16);       // permuted edge features

  const float* Wf1  = fold;
  const float* b1f  = fold + 1024;
  const float* Wni1 = fold + 1088;
  const float* Wnj1 = fold + 3136;
  const float* Wno1 = fold + 5184;
  const float* bni1 = fold + 7232;
  const float* bnj1 = fold + 7296;
  const float* bno1 = fold + 7360;

  const int B = 256;
  const int NGB = cdiv(NN, 128);
  const int EGB = cdiv(NE, 128);
  const int NB256 = cdiv(NN, 256);

  // ---- CSR build (dst-sorted) + fused edge permutation ----
  hipMemsetAsync(deg, 0, NN * 4, stream);
  deg_kernel<<<cdiv(NE, B), B, 0, stream>>>(dst, deg);
  scan1_kernel<<<NB256, 256, 0, stream>>>(deg, rowptr, partial);
  scan2_kernel<<<1, 256, 0, stream>>>(partial, NB256);
  scan3_kernel<<<NB256, 256, 0, stream>>>(rowptr, partial, cursor);
  scatter_dst_kernel<<<cdiv(NE, B), B, 0, stream>>>(src, dst, ef, cursor, src_s, dst_s, ef_s);

  // folded weights + MFMA fragment packs (tiny)
  fold_kernel<<<29, B, 0, stream>>>(fp_w, fp_b, ep_w, ep_b,
                                    (const float*)d_in[15], (const float*)d_in[18],
                                    (const float*)d_in[13], (const float*)d_in[14],
                                    (const float*)d_in[16], fold);
  nnwt_frag_kernel<<<68, B, 0, stream>>>(nn_w, nn_b, Wfrag);
  fij_frag_kernel<<<16, B, 0, stream>>>(e2_fij, Wfrag2);
  hproj_frag_kernel<<<48, B, 0, stream>>>(e2_ni, e2_nj, (const float*)d_in[22], WfragH);

  // ---- EGAT layer 1 (edges processed in dst-sorted order) ----
  gemm3_kernel<32, true><<<dim3(NGB, 3), B, 0, stream>>>(face, Wni1, Wnj1, Wno1, bni1, bnj1,
                                                         bno1, hs16, hd16, hn16, NN);
  gemm_fout_kernel<16, true><<<EGB, B, 0, stream>>>(ef_s, Wf1, b1f, hs16, hd16, src_s,
                                                    dst_s, e1_attn, f116, logit);
  agg_gather_kernel<true><<<cdiv(NN * 64, B), B, 0, stream>>>(hn16, logit, rowptr, deg,
                                                              src_s, h1bf);

  // ---- EGAT layer 2 (hproj + edge GEMM on matrix cores) ----
  mfma_hproj_kernel<<<cdiv(NN * 4, B), B, 0, stream>>>(h1bf, WfragH, hs16, hd16, hn16);
  mfma_fout_kernel<<<cdiv(NE * 4, B), B, 0, stream>>>(f116, Wfrag2, e2_bias, hs16, hd16,
                                                      src_s, dst_s, e2_attn, logit);
  agg_gather_kernel<false><<<cdiv(NN * 64, B), B, 0, stream>>>(hn16, logit, rowptr, deg,
                                                               src_s, h0);

  // ---- NNConv (outer-product form; G aliases dead EGAT buffers — runs after EGAT) ----
  nnconv_G_kernel<<<cdiv(NN * 64, B), B, 0, stream>>>(face, ef_s, rowptr, deg, src_s, G);
  gemm_G_mfma_kernel<<<cdiv(NN * 4, B), B, 0, stream>>>(G, Wfrag, sArr, NN);

  // ---- combine node features + gate logits ----
  hipMemsetAsync(gmax, 0, 4, stream);
  combine_gate_kernel<<<cdiv(NN * 64, B), B, 0, stream>>>(h0, sArr, deg, nn_bias, gate_w,
                                                          gate_b, out, g);
  gate_max_kernel<<<128, B, 0, stream>>>(g, gmax);
  pool_exp_kernel<<<PB, B, 0, stream>>>(out, g, gmax, pacc, wsb);
  pool_reduce_kernel<<<129, B, 0, stream>>>(pacc, wsb, gacc, gsum);
  finalize_kernel<<<1, 128, 0, stream>>>(gacc, gsum, out);
}

// Round 22
// 259.089 us; speedup vs baseline: 1.5513x; 1.0243x over previous
//
#include <hip/hip_runtime.h>

#define NN 60000
#define NE 300000
#define PB 768
typedef unsigned short ush;
typedef __attribute__((ext_vector_type(8))) short bf16x8;
typedef __attribute__((ext_vector_type(4))) float f32x4;

static inline int cdiv(int a, int b) { return (a + b - 1) / b; }

__device__ inline unsigned ord_enc(float x) {
  unsigned u = __float_as_uint(x);
  return (u & 0x80000000u) ? ~u : (u | 0x80000000u);
}
__device__ inline float ord_dec(unsigned u) {
  return __uint_as_float((u & 0x80000000u) ? (u & 0x7fffffffu) : ~u);
}
__device__ inline float bf2f(unsigned u16) { return __uint_as_float(u16 << 16); }
__device__ inline ush f2bf(float x) {
  unsigned u = __float_as_uint(x);
  return (ush)((u + 0x7FFFu + ((u >> 16) & 1u)) >> 16);
}
__device__ inline unsigned pack2(float lo, float hi) {
  return ((unsigned)f2bf(hi) << 16) | (unsigned)f2bf(lo);
}

// ================= CSR build (dst-sorted) =================
__global__ void deg_kernel(const int* __restrict__ key, int* __restrict__ deg) {
  int e = blockIdx.x * blockDim.x + threadIdx.x;
  if (e < NE) atomicAdd(deg + key[e], 1);
}

__global__ void scan1_kernel(const int* __restrict__ deg, int* __restrict__ rowptr,
                             int* __restrict__ partial) {
  __shared__ int s[256];
  int i = blockIdx.x * 256 + threadIdx.x;
  int v = (i < NN) ? deg[i] : 0;
  s[threadIdx.x] = v;
  __syncthreads();
  for (int off = 1; off < 256; off <<= 1) {
    int t = (threadIdx.x >= off) ? s[threadIdx.x - off] : 0;
    __syncthreads();
    s[threadIdx.x] += t;
    __syncthreads();
  }
  if (i < NN) rowptr[i] = s[threadIdx.x] - v;
  if (threadIdx.x == 255) partial[blockIdx.x] = s[255];
}

__global__ void scan2_kernel(int* __restrict__ partial, int nb) {
  __shared__ int s[256];
  int v = (threadIdx.x < nb) ? partial[threadIdx.x] : 0;
  s[threadIdx.x] = v;
  __syncthreads();
  for (int off = 1; off < 256; off <<= 1) {
    int t = (threadIdx.x >= off) ? s[threadIdx.x - off] : 0;
    __syncthreads();
    s[threadIdx.x] += t;
    __syncthreads();
  }
  if (threadIdx.x < nb) partial[threadIdx.x] = s[threadIdx.x] - v;
}

__global__ void scan3_kernel(int* __restrict__ rowptr, const int* __restrict__ partial,
                             int* __restrict__ cursor) {
  int i = blockIdx.x * 256 + threadIdx.x;
  if (i < NN) {
    int r = rowptr[i] + partial[blockIdx.x];
    rowptr[i] = r;
    cursor[i] = r;
  }
}

// scatter + ef permutation fused; also emits ef16 (NEx32 bf16, k>=16 zero)
__global__ void scatter_dst_kernel(const int* __restrict__ src, const int* __restrict__ dst,
                                   const float* __restrict__ ef, int* __restrict__ cursor,
                                   int* __restrict__ src_s, int* __restrict__ dst_s,
                                   float* __restrict__ ef_s, ush* __restrict__ ef16) {
  int e = blockIdx.x * blockDim.x + threadIdx.x;
  if (e >= NE) return;
  int d = dst[e];
  int j = atomicAdd(cursor + d, 1);
  src_s[j] = src[e];
  dst_s[j] = d;
  const float4* ep = (const float4*)(ef + (size_t)e * 16);
  float4 a = ep[0], b = ep[1], c = ep[2], dd = ep[3];
  float4* op = (float4*)(ef_s + (size_t)j * 16);
  op[0] = a; op[1] = b; op[2] = c; op[3] = dd;
  uint4* bp = (uint4*)(ef16 + (size_t)j * 32);
  uint4 p0, p1;
  p0.x = pack2(a.x, a.y); p0.y = pack2(a.z, a.w);
  p0.z = pack2(b.x, b.y); p0.w = pack2(b.z, b.w);
  p1.x = pack2(c.x, c.y); p1.y = pack2(c.z, c.w);
  p1.z = pack2(dd.x, dd.y); p1.w = pack2(dd.z, dd.w);
  bp[0] = p0; bp[1] = p1;
  bp[2] = make_uint4(0, 0, 0, 0);
  bp[3] = make_uint4(0, 0, 0, 0);
}

// ---------------- convert face f32 -> bf16 (NNx32) ----------------
__global__ void face16_kernel(const float* __restrict__ face, ush* __restrict__ face16) {
  int t = blockIdx.x * blockDim.x + threadIdx.x;
  if (t >= NN * 8) return;  // each handles 4 floats
  const float4 v = ((const float4*)face)[t];
  ((uint2*)face16)[t] = make_uint2(pack2(v.x, v.y), pack2(v.z, v.w));
}

// ---------------- fold: precompute folded weight products (7424 dots of length 64) -------
__global__ void fold_kernel(const float* __restrict__ fp_w, const float* __restrict__ fp_b,
                            const float* __restrict__ ep_w, const float* __restrict__ ep_b,
                            const float* __restrict__ fij, const float* __restrict__ ebias,
                            const float* __restrict__ ni, const float* __restrict__ nj,
                            const float* __restrict__ node, float* __restrict__ fold) {
  int t = blockIdx.x * blockDim.x + threadIdx.x;
  if (t >= 7424) return;
  int o = t & 63;
  const float* A;
  const float* B;
  float init = 0.f;
  if (t < 1024)      { A = ep_w + (size_t)(t >> 6) * 64; B = fij + o; }
  else if (t < 1088) { A = ep_b; B = fij + o; init = ebias[o]; }
  else if (t < 3136) { A = fp_w + (size_t)((t - 1088) >> 6) * 64; B = ni + o; }
  else if (t < 5184) { A = fp_w + (size_t)((t - 3136) >> 6) * 64; B = nj + o; }
  else if (t < 7232) { A = fp_w + (size_t)((t - 5184) >> 6) * 64; B = node + o; }
  else if (t < 7296) { A = fp_b; B = ni + o; }
  else if (t < 7360) { A = fp_b; B = nj + o; }
  else               { A = fp_b; B = node + o; }
  float a = init;
  for (int i = 0; i < 64; ++i) a = fmaf(A[i], B[(size_t)i * 64], a);
  fold[t] = a;
}

// ---------------- pack folded layer-1 weights into MFMA B-frag order ----------------
// Wf1frag: 4 ct x 512 (K=32, k>=16 zero) from fold[0..1024) [k][o]
// WfragH1: 3 mats x 4 ct x 512 (K=32) from fold[1088 + m*2048 + k*64 + o]
__global__ void fold1_frag_kernel(const float* __restrict__ fold, ush* __restrict__ Wf1frag,
                                  ush* __restrict__ WfragH1) {
  int t = blockIdx.x * blockDim.x + threadIdx.x;
  if (t >= 2048 + 6144) return;
  if (t < 2048) {
    int i = t & 7, lane = (t >> 3) & 63, ct = t >> 9;
    int k = (lane >> 4) * 8 + i;
    int o = ct * 16 + (lane & 15);
    Wf1frag[t] = (k < 16) ? f2bf(fold[(size_t)k * 64 + o]) : 0;
  } else {
    int idx = t - 2048;
    int i = idx & 7, lane = (idx >> 3) & 63, ct = (idx >> 9) & 3, m = idx >> 11;
    int k = (lane >> 4) * 8 + i;
    int o = ct * 16 + (lane & 15);
    WfragH1[idx] = f2bf(fold[1088 + (size_t)m * 2048 + (size_t)k * 64 + o]);
  }
}

// ---------------- pack nn_w/nn_b into MFMA B-fragment order (17 K-steps x 2 col tiles) ---
__global__ void nnwt_frag_kernel(const float* __restrict__ nn_w, const float* __restrict__ nn_b,
                                 ush* __restrict__ Wfrag) {
  int t = blockIdx.x * blockDim.x + threadIdx.x;
  if (t >= 17408) return;
  int i = t & 7, lane = (t >> 3) & 63, ct = (t >> 9) & 1, kk = t >> 10;
  int k = kk * 32 + (lane >> 4) * 8 + i;
  int o = ct * 16 + (lane & 15);
  float v = (k < 512) ? nn_w[(size_t)(k >> 5) * 1024 + (k & 31) * 32 + o]
                      : nn_b[(k - 512) * 32 + o];
  Wfrag[t] = f2bf(v);
}

// ---------------- pack e2_fij (64x64 f32) into MFMA B-frag order (2 kk x 4 col tiles) ----
__global__ void fij_frag_kernel(const float* __restrict__ fij, ush* __restrict__ Wfrag2) {
  int t = blockIdx.x * blockDim.x + threadIdx.x;
  if (t >= 4096) return;
  int i = t & 7, lane = (t >> 3) & 63, ct = (t >> 9) & 3, kk = t >> 11;
  int k = kk * 32 + (lane >> 4) * 8 + i;
  int o = ct * 16 + (lane & 15);
  Wfrag2[t] = f2bf(fij[(size_t)k * 64 + o]);
}

// ---------------- pack e2_{ni,nj,node} into MFMA B-frag order (3 mats x 2 kk x 4 ct) -----
__global__ void hproj_frag_kernel(const float* __restrict__ ni, const float* __restrict__ nj,
                                  const float* __restrict__ node, ush* __restrict__ WfragH) {
  int t = blockIdx.x * blockDim.x + threadIdx.x;
  if (t >= 12288) return;
  int i = t & 7, lane = (t >> 3) & 63, ct = (t >> 9) & 3, kk = (t >> 11) & 1, m = t >> 12;
  int k = kk * 32 + (lane >> 4) * 8 + i;
  int o = ct * 16 + (lane & 15);
  const float* W = (m == 0) ? ni : (m == 1) ? nj : node;
  WfragH[t] = f2bf(W[(size_t)k * 64 + o]);
}

// ---------------- layer-1 hproj via MFMA: face16(NNx32) @ folded {ni,nj,node}(32x64) -----
__global__ __launch_bounds__(256, 4) void mfma_hproj1_kernel(
    const ush* __restrict__ face16, const ush* __restrict__ WfragH1,
    const float* __restrict__ fold, ush* __restrict__ hs, ush* __restrict__ hd,
    ush* __restrict__ hn) {
  int wave = (blockIdx.x * blockDim.x + threadIdx.x) >> 6;
  int lane = threadIdx.x & 63;
  int m0 = wave * 16;
  if (m0 >= NN) return;
  int arow = lane & 15;
  int aoff = (lane >> 4) * 8;
  bf16x8 a = *(const bf16x8*)(face16 + (size_t)(m0 + arow) * 32 + aoff);
  int ccol = lane & 15;
  int crow = (lane >> 4) * 4;
#pragma unroll
  for (int m = 0; m < 3; ++m) {
    const ush* wm = WfragH1 + (size_t)m * 2048 + lane * 8;
    bf16x8 b0 = *(const bf16x8*)(wm + 0 * 512);
    bf16x8 b1 = *(const bf16x8*)(wm + 1 * 512);
    bf16x8 b2 = *(const bf16x8*)(wm + 2 * 512);
    bf16x8 b3 = *(const bf16x8*)(wm + 3 * 512);
    f32x4 acc0 = {0.f, 0.f, 0.f, 0.f};
    f32x4 acc1 = {0.f, 0.f, 0.f, 0.f};
    f32x4 acc2 = {0.f, 0.f, 0.f, 0.f};
    f32x4 acc3 = {0.f, 0.f, 0.f, 0.f};
    acc0 = __builtin_amdgcn_mfma_f32_16x16x32_bf16(a, b0, acc0, 0, 0, 0);
    acc1 = __builtin_amdgcn_mfma_f32_16x16x32_bf16(a, b1, acc1, 0, 0, 0);
    acc2 = __builtin_amdgcn_mfma_f32_16x16x32_bf16(a, b2, acc2, 0, 0, 0);
    acc3 = __builtin_amdgcn_mfma_f32_16x16x32_bf16(a, b3, acc3, 0, 0, 0);
    float bv0 = fold[7232 + m * 64 + ccol];
    float bv1 = fold[7232 + m * 64 + 16 + ccol];
    float bv2 = fold[7232 + m * 64 + 32 + ccol];
    float bv3 = fold[7232 + m * 64 + 48 + ccol];
    ush* outm = (m == 0) ? hs : (m == 1) ? hd : hn;
#pragma unroll
    for (int j = 0; j < 4; ++j) {
      ush* op = outm + (size_t)(m0 + crow + j) * 64;
      op[ccol] = f2bf(acc0[j] + bv0);
      op[16 + ccol] = f2bf(acc1[j] + bv1);
      op[32 + ccol] = f2bf(acc2[j] + bv2);
      op[48 + ccol] = f2bf(acc3[j] + bv3);
    }
  }
}

// ---------------- layer-1 edge GEMM via MFMA: ef16(NEx32) @ Wf1(32x64, folded) -----------
// Fused epilogue: + hs[src] + hd[dst] + b1f, leaky, store f116, attn logit.
__global__ __launch_bounds__(256, 4) void mfma_fout1_kernel(
    const ush* __restrict__ ef16, const ush* __restrict__ Wf1frag, const float* __restrict__ fold,
    const ush* __restrict__ hs, const ush* __restrict__ hd, const int* __restrict__ src_s,
    const int* __restrict__ dst_s, const float* __restrict__ attn, ush* __restrict__ f116,
    float* __restrict__ logit) {
  int wave = (blockIdx.x * blockDim.x + threadIdx.x) >> 6;
  int lane = threadIdx.x & 63;
  int m0 = wave * 16;
  if (m0 >= NE) return;
  int arow = lane & 15;
  int aoff = (lane >> 4) * 8;
  bf16x8 a = *(const bf16x8*)(ef16 + (size_t)(m0 + arow) * 32 + aoff);
  const ush* wp = Wf1frag + lane * 8;
  bf16x8 b0 = *(const bf16x8*)(wp + 0 * 512);
  bf16x8 b1 = *(const bf16x8*)(wp + 1 * 512);
  bf16x8 b2 = *(const bf16x8*)(wp + 2 * 512);
  bf16x8 b3 = *(const bf16x8*)(wp + 3 * 512);
  f32x4 acc0 = {0.f, 0.f, 0.f, 0.f};
  f32x4 acc1 = {0.f, 0.f, 0.f, 0.f};
  f32x4 acc2 = {0.f, 0.f, 0.f, 0.f};
  f32x4 acc3 = {0.f, 0.f, 0.f, 0.f};
  acc0 = __builtin_amdgcn_mfma_f32_16x16x32_bf16(a, b0, acc0, 0, 0, 0);
  acc1 = __builtin_amdgcn_mfma_f32_16x16x32_bf16(a, b1, acc1, 0, 0, 0);
  acc2 = __builtin_amdgcn_mfma_f32_16x16x32_bf16(a, b2, acc2, 0, 0, 0);
  acc3 = __builtin_amdgcn_mfma_f32_16x16x32_bf16(a, b3, acc3, 0, 0, 0);
  int ccol = lane & 15;
  int crow = (lane >> 4) * 4;
  float av0 = attn[ccol], av1 = attn[16 + ccol], av2 = attn[32 + ccol], av3 = attn[48 + ccol];
  float bv0 = fold[1024 + ccol], bv1 = fold[1024 + 16 + ccol];
  float bv2 = fold[1024 + 32 + ccol], bv3 = fold[1024 + 48 + ccol];
#pragma unroll
  for (int j = 0; j < 4; ++j) {
    int r = m0 + crow + j;
    int s = src_s[r], d = dst_s[r];
    const ush* hsp = hs + (size_t)s * 64;
    const ush* hdp = hd + (size_t)d * 64;
    float f0 = acc0[j] + bf2f(hsp[ccol]) + bf2f(hdp[ccol]) + bv0;
    float f1 = acc1[j] + bf2f(hsp[16 + ccol]) + bf2f(hdp[16 + ccol]) + bv1;
    float f2 = acc2[j] + bf2f(hsp[32 + ccol]) + bf2f(hdp[32 + ccol]) + bv2;
    float f3 = acc3[j] + bf2f(hsp[48 + ccol]) + bf2f(hdp[48 + ccol]) + bv3;
    f0 = f0 >= 0.f ? f0 : 0.01f * f0;
    f1 = f1 >= 0.f ? f1 : 0.01f * f1;
    f2 = f2 >= 0.f ? f2 : 0.01f * f2;
    f3 = f3 >= 0.f ? f3 : 0.01f * f3;
    ush* fp = f116 + (size_t)r * 64;
    fp[ccol] = f2bf(f0);
    fp[16 + ccol] = f2bf(f1);
    fp[32 + ccol] = f2bf(f2);
    fp[48 + ccol] = f2bf(f3);
    float p = fmaf(f0, av0, fmaf(f1, av1, fmaf(f2, av2, f3 * av3)));
    p += __shfl_xor(p, 1, 64);
    p += __shfl_xor(p, 2, 64);
    p += __shfl_xor(p, 4, 64);
    p += __shfl_xor(p, 8, 64);
    if (ccol == 0) logit[r] = p;
  }
}

// ---------------- layer-2 hproj via MFMA: h1bf(NNx64) @ {ni,nj,node}(64x64) --------------
__global__ __launch_bounds__(256, 4) void mfma_hproj_kernel(
    const ush* __restrict__ h1bf, const ush* __restrict__ WfragH, ush* __restrict__ hs,
    ush* __restrict__ hd, ush* __restrict__ hn) {
  int wave = (blockIdx.x * blockDim.x + threadIdx.x) >> 6;
  int lane = threadIdx.x & 63;
  int m0 = wave * 16;
  if (m0 >= NN) return;
  int arow = lane & 15;
  int aoff = (lane >> 4) * 8;
  const ush* ap = h1bf + (size_t)(m0 + arow) * 64 + aoff;
  bf16x8 a0 = *(const bf16x8*)(ap);
  bf16x8 a1 = *(const bf16x8*)(ap + 32);
  const ush* wp = WfragH + lane * 8;
  int ccol = lane & 15;
  int crow = (lane >> 4) * 4;
#pragma unroll
  for (int m = 0; m < 3; ++m) {
    f32x4 acc0 = {0.f, 0.f, 0.f, 0.f};
    f32x4 acc1 = {0.f, 0.f, 0.f, 0.f};
    f32x4 acc2 = {0.f, 0.f, 0.f, 0.f};
    f32x4 acc3 = {0.f, 0.f, 0.f, 0.f};
    const ush* wm = wp + (size_t)m * 8 * 512;
    bf16x8 b0 = *(const bf16x8*)(wm + 0 * 512);
    bf16x8 b1 = *(const bf16x8*)(wm + 1 * 512);
    bf16x8 b2 = *(const bf16x8*)(wm + 2 * 512);
    bf16x8 b3 = *(const bf16x8*)(wm + 3 * 512);
    acc0 = __builtin_amdgcn_mfma_f32_16x16x32_bf16(a0, b0, acc0, 0, 0, 0);
    acc1 = __builtin_amdgcn_mfma_f32_16x16x32_bf16(a0, b1, acc1, 0, 0, 0);
    acc2 = __builtin_amdgcn_mfma_f32_16x16x32_bf16(a0, b2, acc2, 0, 0, 0);
    acc3 = __builtin_amdgcn_mfma_f32_16x16x32_bf16(a0, b3, acc3, 0, 0, 0);
    b0 = *(const bf16x8*)(wm + 4 * 512);
    b1 = *(const bf16x8*)(wm + 5 * 512);
    b2 = *(const bf16x8*)(wm + 6 * 512);
    b3 = *(const bf16x8*)(wm + 7 * 512);
    acc0 = __builtin_amdgcn_mfma_f32_16x16x32_bf16(a1, b0, acc0, 0, 0, 0);
    acc1 = __builtin_amdgcn_mfma_f32_16x16x32_bf16(a1, b1, acc1, 0, 0, 0);
    acc2 = __builtin_amdgcn_mfma_f32_16x16x32_bf16(a1, b2, acc2, 0, 0, 0);
    acc3 = __builtin_amdgcn_mfma_f32_16x16x32_bf16(a1, b3, acc3, 0, 0, 0);
    ush* outm = (m == 0) ? hs : (m == 1) ? hd : hn;
#pragma unroll
    for (int j = 0; j < 4; ++j) {
      ush* op = outm + (size_t)(m0 + crow + j) * 64;
      op[ccol] = f2bf(acc0[j]);
      op[16 + ccol] = f2bf(acc1[j]);
      op[32 + ccol] = f2bf(acc2[j]);
      op[48 + ccol] = f2bf(acc3[j]);
    }
  }
}

// ---------------- layer-2 edge GEMM via MFMA: f116(NEx64 bf16) @ fij(64x64) --------------
__global__ __launch_bounds__(256, 4) void mfma_fout_kernel(
    const ush* __restrict__ f116, const ush* __restrict__ Wfrag2, const float* __restrict__ bias,
    const ush* __restrict__ hs, const ush* __restrict__ hd, const int* __restrict__ src_s,
    const int* __restrict__ dst_s, const float* __restrict__ attn, float* __restrict__ logit) {
  int wave = (blockIdx.x * blockDim.x + threadIdx.x) >> 6;
  int lane = threadIdx.x & 63;
  int m0 = wave * 16;
  if (m0 >= NE) return;
  int arow = lane & 15;
  int aoff = (lane >> 4) * 8;
  const ush* ap = f116 + (size_t)(m0 + arow) * 64 + aoff;
  const ush* wp = Wfrag2 + lane * 8;
  f32x4 acc0 = {0.f, 0.f, 0.f, 0.f};
  f32x4 acc1 = {0.f, 0.f, 0.f, 0.f};
  f32x4 acc2 = {0.f, 0.f, 0.f, 0.f};
  f32x4 acc3 = {0.f, 0.f, 0.f, 0.f};
#pragma unroll
  for (int kk = 0; kk < 2; ++kk) {
    bf16x8 a = *(const bf16x8*)(ap + kk * 32);
    bf16x8 b0 = *(const bf16x8*)(wp + (size_t)(kk * 4 + 0) * 512);
    bf16x8 b1 = *(const bf16x8*)(wp + (size_t)(kk * 4 + 1) * 512);
    bf16x8 b2 = *(const bf16x8*)(wp + (size_t)(kk * 4 + 2) * 512);
    bf16x8 b3 = *(const bf16x8*)(wp + (size_t)(kk * 4 + 3) * 512);
    acc0 = __builtin_amdgcn_mfma_f32_16x16x32_bf16(a, b0, acc0, 0, 0, 0);
    acc1 = __builtin_amdgcn_mfma_f32_16x16x32_bf16(a, b1, acc1, 0, 0, 0);
    acc2 = __builtin_amdgcn_mfma_f32_16x16x32_bf16(a, b2, acc2, 0, 0, 0);
    acc3 = __builtin_amdgcn_mfma_f32_16x16x32_bf16(a, b3, acc3, 0, 0, 0);
  }
  int ccol = lane & 15;
  int crow = (lane >> 4) * 4;
  float av0 = attn[ccol], av1 = attn[16 + ccol], av2 = attn[32 + ccol], av3 = attn[48 + ccol];
  float bv0 = bias[ccol], bv1 = bias[16 + ccol], bv2 = bias[32 + ccol], bv3 = bias[48 + ccol];
#pragma unroll
  for (int j = 0; j < 4; ++j) {
    int r = m0 + crow + j;
    int s = src_s[r], d = dst_s[r];
    const ush* hsp = hs + (size_t)s * 64;
    const ush* hdp = hd + (size_t)d * 64;
    float f0 = acc0[j] + bf2f(hsp[ccol]) + bf2f(hdp[ccol]) + bv0;
    float f1 = acc1[j] + bf2f(hsp[16 + ccol]) + bf2f(hdp[16 + ccol]) + bv1;
    float f2 = acc2[j] + bf2f(hsp[32 + ccol]) + bf2f(hdp[32 + ccol]) + bv2;
    float f3 = acc3[j] + bf2f(hsp[48 + ccol]) + bf2f(hdp[48 + ccol]) + bv3;
    f0 = f0 >= 0.f ? f0 : 0.01f * f0;
    f1 = f1 >= 0.f ? f1 : 0.01f * f1;
    f2 = f2 >= 0.f ? f2 : 0.01f * f2;
    f3 = f3 >= 0.f ? f3 : 0.01f * f3;
    float p = fmaf(f0, av0, fmaf(f1, av1, fmaf(f2, av2, f3 * av3)));
    p += __shfl_xor(p, 1, 64);
    p += __shfl_xor(p, 2, 64);
    p += __shfl_xor(p, 4, 64);
    p += __shfl_xor(p, 8, 64);
    if (ccol == 0) logit[r] = p;
  }
}

// ---------------- EGAT: gather-aggregate (BF16OUT: h_out stored as bf16) -----------------
template <bool BF16OUT>
__global__ __launch_bounds__(256, 4) void agg_gather_kernel(
    const ush* __restrict__ hn, const float* __restrict__ logit, const int* __restrict__ rowptr,
    const int* __restrict__ deg, const int* __restrict__ src_s, void* __restrict__ hnew) {
  int wave = (blockIdx.x * blockDim.x + threadIdx.x) >> 6;
  int lane = threadIdx.x & 63;
  if (wave >= NN) return;
  int n = wave, d = deg[n], r0 = rowptr[n];
  if (d == 0) {
    if (BF16OUT) ((ush*)hnew)[(size_t)n * 64 + lane] = 0;
    else ((float*)hnew)[(size_t)n * 64 + lane] = 0.f;
    return;
  }
  float sum = 0.f, acc0 = 0.f, acc1 = 0.f, acc2 = 0.f, acc3 = 0.f;
  int j = 0;
  for (; j + 3 < d; j += 4) {
    int jj = r0 + j;
    int s0 = src_s[jj + 0], s1 = src_s[jj + 1], s2 = src_s[jj + 2], s3 = src_s[jj + 3];
    float l0 = logit[jj + 0], l1 = logit[jj + 1], l2 = logit[jj + 2], l3 = logit[jj + 3];
    ush h0 = hn[(size_t)s0 * 64 + lane];
    ush h1 = hn[(size_t)s1 * 64 + lane];
    ush h2 = hn[(size_t)s2 * 64 + lane];
    ush h3 = hn[(size_t)s3 * 64 + lane];
    float w0 = __expf(l0), w1 = __expf(l1);
    float w2 = __expf(l2), w3 = __expf(l3);
    sum += (w0 + w1) + (w2 + w3);
    acc0 = fmaf(w0, bf2f(h0), acc0);
    acc1 = fmaf(w1, bf2f(h1), acc1);
    acc2 = fmaf(w2, bf2f(h2), acc2);
    acc3 = fmaf(w3, bf2f(h3), acc3);
  }
  for (; j < d; ++j) {
    int jj = r0 + j;
    float w = __expf(logit[jj]);
    sum += w;
    acc0 = fmaf(w, bf2f(hn[(size_t)src_s[jj] * 64 + lane]), acc0);
  }
  float r = ((acc0 + acc1) + (acc2 + acc3)) / sum;
  if (BF16OUT) ((ush*)hnew)[(size_t)n * 64 + lane] = f2bf(r);
  else ((float*)hnew)[(size_t)n * 64 + lane] = r;
}

// ---------------- NNConv phase A: per-node outer-product G accumulate (registers only) ---
__global__ __launch_bounds__(256, 4) void nnconv_G_kernel(
    const float* __restrict__ face, const float* __restrict__ ef_s,
    const int* __restrict__ rowptr, const int* __restrict__ deg, const int* __restrict__ src_s,
    ush* __restrict__ G) {
  int wave = (blockIdx.x * blockDim.x + threadIdx.x) >> 6;
  int lane = threadIdx.x & 63;
  if (wave >= NN) return;
  int n = wave, d = deg[n], r0 = rowptr[n];
  int k4 = lane >> 2, ib = lane & 3;
  float g[8], fs[8];
#pragma unroll
  for (int u = 0; u < 8; ++u) { g[u] = 0.f; fs[u] = 0.f; }
  int j = 0;
  for (; j + 1 < d; j += 2) {
    int jj = r0 + j;
    int s0 = src_s[jj], s1 = src_s[jj + 1];
    float ev0 = ef_s[(size_t)jj * 16 + k4];
    float ev1 = ef_s[(size_t)(jj + 1) * 16 + k4];
    const float4* fp0 = (const float4*)(face + (size_t)s0 * 32 + ib * 8);
    const float4* fp1 = (const float4*)(face + (size_t)s1 * 32 + ib * 8);
    float4 fa0 = fp0[0], fb0 = fp0[1];
    float4 fa1 = fp1[0], fb1 = fp1[1];
    g[0] = fmaf(ev0, fa0.x, g[0]); g[1] = fmaf(ev0, fa0.y, g[1]);
    g[2] = fmaf(ev0, fa0.z, g[2]); g[3] = fmaf(ev0, fa0.w, g[3]);
    g[4] = fmaf(ev0, fb0.x, g[4]); g[5] = fmaf(ev0, fb0.y, g[5]);
    g[6] = fmaf(ev0, fb0.z, g[6]); g[7] = fmaf(ev0, fb0.w, g[7]);
    g[0] = fmaf(ev1, fa1.x, g[0]); g[1] = fmaf(ev1, fa1.y, g[1]);
    g[2] = fmaf(ev1, fa1.z, g[2]); g[3] = fmaf(ev1, fa1.w, g[3]);
    g[4] = fmaf(ev1, fb1.x, g[4]); g[5] = fmaf(ev1, fb1.y, g[5]);
    g[6] = fmaf(ev1, fb1.z, g[6]); g[7] = fmaf(ev1, fb1.w, g[7]);
    if (k4 == 0) {
      fs[0] += fa0.x + fa1.x; fs[1] += fa0.y + fa1.y;
      fs[2] += fa0.z + fa1.z; fs[3] += fa0.w + fa1.w;
      fs[4] += fb0.x + fb1.x; fs[5] += fb0.y + fb1.y;
      fs[6] += fb0.z + fb1.z; fs[7] += fb0.w + fb1.w;
    }
  }
  if (j < d) {
    int jj = r0 + j;
    int s0 = src_s[jj];
    float ev0 = ef_s[(size_t)jj * 16 + k4];
    const float4* fp0 = (const float4*)(face + (size_t)s0 * 32 + ib * 8);
    float4 fa0 = fp0[0], fb0 = fp0[1];
    g[0] = fmaf(ev0, fa0.x, g[0]); g[1] = fmaf(ev0, fa0.y, g[1]);
    g[2] = fmaf(ev0, fa0.z, g[2]); g[3] = fmaf(ev0, fa0.w, g[3]);
    g[4] = fmaf(ev0, fb0.x, g[4]); g[5] = fmaf(ev0, fb0.y, g[5]);
    g[6] = fmaf(ev0, fb0.z, g[6]); g[7] = fmaf(ev0, fb0.w, g[7]);
    if (k4 == 0) {
      fs[0] += fa0.x; fs[1] += fa0.y; fs[2] += fa0.z; fs[3] += fa0.w;
      fs[4] += fb0.x; fs[5] += fb0.y; fs[6] += fb0.z; fs[7] += fb0.w;
    }
  }
  uint4 pv;
  pv.x = pack2(g[0], g[1]); pv.y = pack2(g[2], g[3]);
  pv.z = pack2(g[4], g[5]); pv.w = pack2(g[6], g[7]);
  *(uint4*)(G + (size_t)n * 544 + lane * 8) = pv;
  if (k4 == 0) {
    uint4 fv;
    fv.x = pack2(fs[0], fs[1]); fv.y = pack2(fs[2], fs[3]);
    fv.z = pack2(fs[4], fs[5]); fv.w = pack2(fs[6], fs[7]);
    *(uint4*)(G + (size_t)n * 544 + 512 + ib * 8) = fv;
  }
}

// ---------------- NNConv phase B: MFMA GEMM sArr = G(NNx544) @ W(544x32) ----------------
__global__ __launch_bounds__(256, 4) void gemm_G_mfma_kernel(const ush* __restrict__ G,
                                                             const ush* __restrict__ Wfrag,
                                                             float* __restrict__ sArr,
                                                             int rows) {
  int wave = (blockIdx.x * blockDim.x + threadIdx.x) >> 6;
  int lane = threadIdx.x & 63;
  int m0 = wave * 16;
  if (m0 >= rows) return;
  int arow = lane & 15;
  int aoff = (lane >> 4) * 8;
  const ush* gp = G + (size_t)(m0 + arow) * 544 + aoff;
  const ush* wp = Wfrag + lane * 8;
  f32x4 acc0 = {0.f, 0.f, 0.f, 0.f};
  f32x4 acc1 = {0.f, 0.f, 0.f, 0.f};
#pragma unroll 4
  for (int kk = 0; kk < 17; ++kk) {
    bf16x8 a = *(const bf16x8*)(gp + kk * 32);
    bf16x8 b0 = *(const bf16x8*)(wp + (size_t)(kk * 2 + 0) * 512);
    bf16x8 b1 = *(const bf16x8*)(wp + (size_t)(kk * 2 + 1) * 512);
    acc0 = __builtin_amdgcn_mfma_f32_16x16x32_bf16(a, b0, acc0, 0, 0, 0);
    acc1 = __builtin_amdgcn_mfma_f32_16x16x32_bf16(a, b1, acc1, 0, 0, 0);
  }
  int ccol = lane & 15;
  int crow = (lane >> 4) * 4;
#pragma unroll
  for (int j = 0; j < 4; ++j) {
    int r = m0 + crow + j;
    sArr[(size_t)r * 32 + ccol] = acc0[j];
    sArr[(size_t)r * 32 + 16 + ccol] = acc1[j];
  }
}

// ---------------- combine node_features + gate logit (fused; wave per node) --------------
__global__ void combine_gate_kernel(const float* __restrict__ hfin, const float* __restrict__ sArr,
                                    const int* __restrict__ deg, const float* __restrict__ nn_bias,
                                    const float* __restrict__ gate_w, const float* __restrict__ gate_b,
                                    float* __restrict__ out, float* __restrict__ g) {
  int wave = (blockIdx.x * blockDim.x + threadIdx.x) >> 6;
  int lane = threadIdx.x & 63;
  if (wave >= NN) return;
  int n = wave;
  float v0 = hfin[(size_t)n * 64 + lane];
  int c1 = lane + 64;
  float v1 = (c1 < 96)
                 ? sArr[(size_t)n * 32 + (c1 - 64)] / fmaxf((float)deg[n], 1.0f) + nn_bias[c1 - 64]
                 : 0.f;
  out[(size_t)n * 128 + lane] = v0;
  out[(size_t)n * 128 + c1] = v1;
  float p = v0 * gate_w[lane] + ((c1 < 96) ? v1 * gate_w[c1] : 0.f);
#pragma unroll
  for (int off = 32; off; off >>= 1) p += __shfl_xor(p, off, 64);
  if (lane == 0) g[n] = p + gate_b[0];
}

// ---------------- max over g (block-reduced, 1 atomic per block) ----------------
__global__ void gate_max_kernel(const float* __restrict__ g, unsigned* __restrict__ gmax) {
  int tid = blockIdx.x * blockDim.x + threadIdx.x;
  int stride = gridDim.x * blockDim.x;
  float v = -3.0e38f;
  for (int n = tid; n < NN; n += stride) v = fmaxf(v, g[n]);
#pragma unroll
  for (int off = 32; off; off >>= 1) v = fmaxf(v, __shfl_xor(v, off, 64));
  __shared__ float sm[4];
  int lane = threadIdx.x & 63, wid = threadIdx.x >> 6;
  if (lane == 0) sm[wid] = v;
  __syncthreads();
  if (threadIdx.x == 0) {
    float m = fmaxf(fmaxf(sm[0], sm[1]), fmaxf(sm[2], sm[3]));
    atomicMax(gmax, ord_enc(m));
  }
}

// ---------------- pooling: exp + weighted accumulate into per-row-stream partials --------
__global__ __launch_bounds__(256, 4) void pool_exp_kernel(
    const float* __restrict__ nf, const float* __restrict__ g, const unsigned* __restrict__ gmax,
    float* __restrict__ pacc, float* __restrict__ wsb) {
  int o = threadIdx.x & 127;
  int half = threadIdx.x >> 7;
  int ri = blockIdx.x * 2 + half;   // 0 .. 2*PB-1
  float m = ord_dec(*gmax);
  float acc0 = 0.f, acc1 = 0.f, ws = 0.f;
  int n = ri;
  const int STR = PB * 2;
  for (; n + STR < NN; n += STR * 2) {
    float w0 = __expf(g[n] - m);
    float w1 = __expf(g[n + STR] - m);
    float v0 = nf[(size_t)n * 128 + o];
    float v1 = nf[(size_t)(n + STR) * 128 + o];
    ws += w0 + w1;
    acc0 = fmaf(w0, v0, acc0);
    acc1 = fmaf(w1, v1, acc1);
  }
  if (n < NN) {
    float w = __expf(g[n] - m);
    ws += w;
    acc0 = fmaf(w, nf[(size_t)n * 128 + o], acc0);
  }
  pacc[(size_t)ri * 128 + o] = acc0 + acc1;
  if (o == 0) wsb[ri] = ws;
}

__global__ void pool_reduce_kernel(const float* __restrict__ pacc, const float* __restrict__ wsb,
                                   float* __restrict__ gacc, float* __restrict__ gsum) {
  int b = blockIdx.x;
  int t = threadIdx.x;  // 256
  float v = 0.f;
  if (b < 128) {
    for (int ri = t; ri < PB * 2; ri += 256) v += pacc[(size_t)ri * 128 + b];
  } else {
    for (int ri = t; ri < PB * 2; ri += 256) v += wsb[ri];
  }
#pragma unroll
  for (int off = 32; off; off >>= 1) v += __shfl_xor(v, off, 64);
  __shared__ float sm[4];
  int lane = t & 63, wid = t >> 6;
  if (lane == 0) sm[wid] = v;
  __syncthreads();
  if (t == 0) {
    float s = (sm[0] + sm[1]) + (sm[2] + sm[3]);
    if (b < 128) gacc[b] = s;
    else gsum[0] = s;
  }
}

__global__ void finalize_kernel(const float* __restrict__ gacc, const float* __restrict__ gsum,
                                float* __restrict__ out) {
  int o = threadIdx.x;
  if (o < 128) out[(size_t)NN * 128 + o] = gacc[o] / gsum[0];
}

extern "C" void kernel_launch(void* const* d_in, const int* in_sizes, int n_in,
                              void* d_out, int out_size, void* d_ws, size_t ws_size,
                              hipStream_t stream) {
  const float* face    = (const float*)d_in[0];
  const float* ef      = (const float*)d_in[1];
  const float* fp_w    = (const float*)d_in[2];
  const float* fp_b    = (const float*)d_in[3];
  const float* ep_w    = (const float*)d_in[4];
  const float* ep_b    = (const float*)d_in[5];
  const float* nn_w    = (const float*)d_in[6];
  const float* nn_b    = (const float*)d_in[7];
  const float* nn_bias = (const float*)d_in[8];
  const float* gate_w  = (const float*)d_in[9];
  const float* gate_b  = (const float*)d_in[10];
  const int*   src     = (const int*)d_in[11];
  const int*   dst     = (const int*)d_in[12];
  const float* e1_attn = (const float*)d_in[17];
  const float* e2_ni   = (const float*)d_in[19];
  const float* e2_nj   = (const float*)d_in[20];
  const float* e2_fij  = (const float*)d_in[21];
  const float* e2_attn = (const float*)d_in[23];
  const float* e2_bias = (const float*)d_in[24];
  float* out = (float*)d_out;

  char* p = (char*)d_ws;
  auto alloc = [&](size_t nfloats) {
    float* r = (float*)p;
    p += ((nfloats * 4 + 255) / 256) * 256;
    return r;
  };
  float* h0 = alloc((size_t)NN * 64);         // layer-2 output (f32)
  ush* h1bf = (ush*)alloc((size_t)NN * 32);   // layer-1 output (bf16)
  // big region: G (NN*544 bf16 = 65.28 MB) aliases hs16|hd16|hn16|f116|logit (dead post-EGAT)
  char* bigreg = p;
  ush* hs16 = (ush*)alloc((size_t)NN * 32);   // NN*64 bf16
  ush* hd16 = (ush*)alloc((size_t)NN * 32);
  ush* hn16 = (ush*)alloc((size_t)NN * 32);
  ush* f116 = (ush*)alloc((size_t)NE * 32);   // NE*64 bf16 (dst-sorted order)
  float* logit = alloc(NE);                   // dst-sorted order
  {  // pad bigreg to >= NN*544*2 bytes for G
    size_t used = (size_t)(p - bigreg);
    size_t need = (size_t)NN * 544 * 2;
    if (used < need) p += ((need - used + 255) / 256) * 256;
  }
  ush* G = (ush*)bigreg;
  float* sArr  = alloc((size_t)NN * 32);
  float* g     = alloc(NN);
  float* gacc  = alloc(128);
  float* gsum  = alloc(1);
  unsigned* gmax = (unsigned*)alloc(1);
  float* fold  = alloc(7424);
  ush* Wfrag   = (ush*)alloc(17408 / 2);      // nn MFMA B-fragments
  ush* Wfrag2  = (ush*)alloc(4096 / 2);       // e2_fij MFMA B-fragments
  ush* WfragH  = (ush*)alloc(12288 / 2);      // e2_{ni,nj,node} MFMA B-fragments
  ush* Wf1frag = (ush*)alloc(2048 / 2);       // layer-1 folded fij MFMA B-fragments
  ush* WfragH1 = (ush*)alloc(6144 / 2);       // layer-1 folded {ni,nj,node} B-fragments
  ush* face16  = (ush*)alloc((size_t)NN * 16);  // NN*32 bf16
  ush* ef16    = (ush*)alloc((size_t)NE * 16);  // NE*32 bf16 (k>=16 zero, dst-sorted)
  float* pacc  = alloc((size_t)PB * 2 * 128); // pooling partials
  float* wsb   = alloc(PB * 2);
  // dst-CSR
  int* deg    = (int*)alloc(NN);
  int* rowptr = (int*)alloc(NN);
  int* cursor = (int*)alloc(NN);
  int* partial = (int*)alloc(256);
  int* src_s  = (int*)alloc(NE);
  int* dst_s  = (int*)alloc(NE);
  float* ef_s = alloc((size_t)NE * 16);       // permuted edge features (f32)

  const int B = 256;
  const int NB256 = cdiv(NN, 256);

  // ---- CSR build (dst-sorted) + fused edge permutation (f32 + bf16) ----
  hipMemsetAsync(deg, 0, NN * 4, stream);
  deg_kernel<<<cdiv(NE, B), B, 0, stream>>>(dst, deg);
  scan1_kernel<<<NB256, 256, 0, stream>>>(deg, rowptr, partial);
  scan2_kernel<<<1, 256, 0, stream>>>(partial, NB256);
  scan3_kernel<<<NB256, 256, 0, stream>>>(rowptr, partial, cursor);
  scatter_dst_kernel<<<cdiv(NE, B), B, 0, stream>>>(src, dst, ef, cursor, src_s, dst_s,
                                                    ef_s, ef16);

  // ---- weight prep: fold + fragment packs + face convert (tiny) ----
  fold_kernel<<<29, B, 0, stream>>>(fp_w, fp_b, ep_w, ep_b,
                                    (const float*)d_in[15], (const float*)d_in[18],
                                    (const float*)d_in[13], (const float*)d_in[14],
                                    (const float*)d_in[16], fold);
  fold1_frag_kernel<<<32, B, 0, stream>>>(fold, Wf1frag, WfragH1);
  nnwt_frag_kernel<<<68, B, 0, stream>>>(nn_w, nn_b, Wfrag);
  fij_frag_kernel<<<16, B, 0, stream>>>(e2_fij, Wfrag2);
  hproj_frag_kernel<<<48, B, 0, stream>>>(e2_ni, e2_nj, (const float*)d_in[22], WfragH);
  face16_kernel<<<cdiv(NN * 8, B), B, 0, stream>>>(face, face16);

  // ---- EGAT layer 1 (all matmuls on matrix cores) ----
  mfma_hproj1_kernel<<<cdiv(NN * 4, B), B, 0, stream>>>(face16, WfragH1, fold, hs16, hd16, hn16);
  mfma_fout1_kernel<<<cdiv(NE * 4, B), B, 0, stream>>>(ef16, Wf1frag, fold, hs16, hd16,
                                                       src_s, dst_s, e1_attn, f116, logit);
  agg_gather_kernel<true><<<cdiv(NN * 64, B), B, 0, stream>>>(hn16, logit, rowptr, deg,
                                                              src_s, h1bf);

  // ---- EGAT layer 2 (hproj + edge GEMM on matrix cores) ----
  mfma_hproj_kernel<<<cdiv(NN * 4, B), B, 0, stream>>>(h1bf, WfragH, hs16, hd16, hn16);
  mfma_fout_kernel<<<cdiv(NE * 4, B), B, 0, stream>>>(f116, Wfrag2, e2_bias, hs16, hd16,
                                                      src_s, dst_s, e2_attn, logit);
  agg_gather_kernel<false><<<cdiv(NN * 64, B), B, 0, stream>>>(hn16, logit, rowptr, deg,
                                                               src_s, h0);

  // ---- NNConv (outer-product form; G aliases dead EGAT buffers — runs after EGAT) ----
  nnconv_G_kernel<<<cdiv(NN * 64, B), B, 0, stream>>>(face, ef_s, rowptr, deg, src_s, G);
  gemm_G_mfma_kernel<<<cdiv(NN * 4, B), B, 0, stream>>>(G, Wfrag, sArr, NN);

  // ---- combine node features + gate logits ----
  hipMemsetAsync(gmax, 0, 4, stream);
  combine_gate_kernel<<<cdiv(NN * 64, B), B, 0, stream>>>(h0, sArr, deg, nn_bias, gate_w,
                                                          gate_b, out, g);
  gate_max_kernel<<<128, B, 0, stream>>>(g, gmax);
  pool_exp_kernel<<<PB, B, 0, stream>>>(out, g, gmax, pacc, wsb);
  pool_reduce_kernel<<<129, B, 0, stream>>>(pacc, wsb, gacc, gsum);
  finalize_kernel<<<1, 128, 0, stream>>>(gacc, gsum, out);
}

// Round 23
// 255.687 us; speedup vs baseline: 1.5720x; 1.0133x over previous
//
#include <hip/hip_runtime.h>

#define NN 60000
#define NE 300000
#define PB 768
typedef unsigned short ush;
typedef __attribute__((ext_vector_type(8))) short bf16x8;
typedef __attribute__((ext_vector_type(4))) float f32x4;

static inline int cdiv(int a, int b) { return (a + b - 1) / b; }

__device__ inline unsigned ord_enc(float x) {
  unsigned u = __float_as_uint(x);
  return (u & 0x80000000u) ? ~u : (u | 0x80000000u);
}
__device__ inline float ord_dec(unsigned u) {
  return __uint_as_float((u & 0x80000000u) ? (u & 0x7fffffffu) : ~u);
}
__device__ inline float bf2f(unsigned u16) { return __uint_as_float(u16 << 16); }
__device__ inline ush f2bf(float x) {
  unsigned u = __float_as_uint(x);
  return (ush)((u + 0x7FFFu + ((u >> 16) & 1u)) >> 16);
}
__device__ inline unsigned pack2(float lo, float hi) {
  return ((unsigned)f2bf(hi) << 16) | (unsigned)f2bf(lo);
}

// ================= CSR build (dst-sorted) =================
__global__ void deg_kernel(const int* __restrict__ key, int* __restrict__ deg) {
  int e = blockIdx.x * blockDim.x + threadIdx.x;
  if (e < NE) atomicAdd(deg + key[e], 1);
}

__global__ void scan1_kernel(const int* __restrict__ deg, int* __restrict__ rowptr,
                             int* __restrict__ partial) {
  __shared__ int s[256];
  int i = blockIdx.x * 256 + threadIdx.x;
  int v = (i < NN) ? deg[i] : 0;
  s[threadIdx.x] = v;
  __syncthreads();
  for (int off = 1; off < 256; off <<= 1) {
    int t = (threadIdx.x >= off) ? s[threadIdx.x - off] : 0;
    __syncthreads();
    s[threadIdx.x] += t;
    __syncthreads();
  }
  if (i < NN) rowptr[i] = s[threadIdx.x] - v;
  if (threadIdx.x == 255) partial[blockIdx.x] = s[255];
}

__global__ void scan2_kernel(int* __restrict__ partial, int nb) {
  __shared__ int s[256];
  int v = (threadIdx.x < nb) ? partial[threadIdx.x] : 0;
  s[threadIdx.x] = v;
  __syncthreads();
  for (int off = 1; off < 256; off <<= 1) {
    int t = (threadIdx.x >= off) ? s[threadIdx.x - off] : 0;
    __syncthreads();
    s[threadIdx.x] += t;
    __syncthreads();
  }
  if (threadIdx.x < nb) partial[threadIdx.x] = s[threadIdx.x] - v;
}

__global__ void scan3_kernel(int* __restrict__ rowptr, const int* __restrict__ partial,
                             int* __restrict__ cursor) {
  int i = blockIdx.x * 256 + threadIdx.x;
  if (i < NN) {
    int r = rowptr[i] + partial[blockIdx.x];
    rowptr[i] = r;
    cursor[i] = r;
  }
}

// scatter + ef permutation fused; emits ONLY ef16 (NEx32 bf16, k>=16 zero) + indices
__global__ void scatter_dst_kernel(const int* __restrict__ src, const int* __restrict__ dst,
                                   const float* __restrict__ ef, int* __restrict__ cursor,
                                   int* __restrict__ src_s, int* __restrict__ dst_s,
                                   ush* __restrict__ ef16) {
  int e = blockIdx.x * blockDim.x + threadIdx.x;
  if (e >= NE) return;
  int d = dst[e];
  int j = atomicAdd(cursor + d, 1);
  src_s[j] = src[e];
  dst_s[j] = d;
  const float4* ep = (const float4*)(ef + (size_t)e * 16);
  float4 a = ep[0], b = ep[1], c = ep[2], dd = ep[3];
  uint4* bp = (uint4*)(ef16 + (size_t)j * 32);
  uint4 p0, p1;
  p0.x = pack2(a.x, a.y); p0.y = pack2(a.z, a.w);
  p0.z = pack2(b.x, b.y); p0.w = pack2(b.z, b.w);
  p1.x = pack2(c.x, c.y); p1.y = pack2(c.z, c.w);
  p1.z = pack2(dd.x, dd.y); p1.w = pack2(dd.z, dd.w);
  bp[0] = p0; bp[1] = p1;
  bp[2] = make_uint4(0, 0, 0, 0);
  bp[3] = make_uint4(0, 0, 0, 0);
}

// ---------------- convert face f32 -> bf16 (NNx32) ----------------
__global__ void face16_kernel(const float* __restrict__ face, ush* __restrict__ face16) {
  int t = blockIdx.x * blockDim.x + threadIdx.x;
  if (t >= NN * 8) return;  // each handles 4 floats
  const float4 v = ((const float4*)face)[t];
  ((uint2*)face16)[t] = make_uint2(pack2(v.x, v.y), pack2(v.z, v.w));
}

// ---------------- fold: precompute folded weight products (7424 dots of length 64) -------
__global__ void fold_kernel(const float* __restrict__ fp_w, const float* __restrict__ fp_b,
                            const float* __restrict__ ep_w, const float* __restrict__ ep_b,
                            const float* __restrict__ fij, const float* __restrict__ ebias,
                            const float* __restrict__ ni, const float* __restrict__ nj,
                            const float* __restrict__ node, float* __restrict__ fold) {
  int t = blockIdx.x * blockDim.x + threadIdx.x;
  if (t >= 7424) return;
  int o = t & 63;
  const float* A;
  const float* B;
  float init = 0.f;
  if (t < 1024)      { A = ep_w + (size_t)(t >> 6) * 64; B = fij + o; }
  else if (t < 1088) { A = ep_b; B = fij + o; init = ebias[o]; }
  else if (t < 3136) { A = fp_w + (size_t)((t - 1088) >> 6) * 64; B = ni + o; }
  else if (t < 5184) { A = fp_w + (size_t)((t - 3136) >> 6) * 64; B = nj + o; }
  else if (t < 7232) { A = fp_w + (size_t)((t - 5184) >> 6) * 64; B = node + o; }
  else if (t < 7296) { A = fp_b; B = ni + o; }
  else if (t < 7360) { A = fp_b; B = nj + o; }
  else               { A = fp_b; B = node + o; }
  float a = init;
  for (int i = 0; i < 64; ++i) a = fmaf(A[i], B[(size_t)i * 64], a);
  fold[t] = a;
}

// ---------------- pack folded layer-1 weights into MFMA B-frag order ----------------
__global__ void fold1_frag_kernel(const float* __restrict__ fold, ush* __restrict__ Wf1frag,
                                  ush* __restrict__ WfragH1) {
  int t = blockIdx.x * blockDim.x + threadIdx.x;
  if (t >= 2048 + 6144) return;
  if (t < 2048) {
    int i = t & 7, lane = (t >> 3) & 63, ct = t >> 9;
    int k = (lane >> 4) * 8 + i;
    int o = ct * 16 + (lane & 15);
    Wf1frag[t] = (k < 16) ? f2bf(fold[(size_t)k * 64 + o]) : 0;
  } else {
    int idx = t - 2048;
    int i = idx & 7, lane = (idx >> 3) & 63, ct = (idx >> 9) & 3, m = idx >> 11;
    int k = (lane >> 4) * 8 + i;
    int o = ct * 16 + (lane & 15);
    WfragH1[idx] = f2bf(fold[1088 + (size_t)m * 2048 + (size_t)k * 64 + o]);
  }
}

// ---------------- pack nn_w/nn_b into MFMA B-fragment order (17 K-steps x 2 col tiles) ---
__global__ void nnwt_frag_kernel(const float* __restrict__ nn_w, const float* __restrict__ nn_b,
                                 ush* __restrict__ Wfrag) {
  int t = blockIdx.x * blockDim.x + threadIdx.x;
  if (t >= 17408) return;
  int i = t & 7, lane = (t >> 3) & 63, ct = (t >> 9) & 1, kk = t >> 10;
  int k = kk * 32 + (lane >> 4) * 8 + i;
  int o = ct * 16 + (lane & 15);
  float v = (k < 512) ? nn_w[(size_t)(k >> 5) * 1024 + (k & 31) * 32 + o]
                      : nn_b[(k - 512) * 32 + o];
  Wfrag[t] = f2bf(v);
}

// ---------------- pack e2_fij (64x64 f32) into MFMA B-frag order (2 kk x 4 col tiles) ----
__global__ void fij_frag_kernel(const float* __restrict__ fij, ush* __restrict__ Wfrag2) {
  int t = blockIdx.x * blockDim.x + threadIdx.x;
  if (t >= 4096) return;
  int i = t & 7, lane = (t >> 3) & 63, ct = (t >> 9) & 3, kk = t >> 11;
  int k = kk * 32 + (lane >> 4) * 8 + i;
  int o = ct * 16 + (lane & 15);
  Wfrag2[t] = f2bf(fij[(size_t)k * 64 + o]);
}

// ---------------- pack e2_{ni,nj,node} into MFMA B-frag order (3 mats x 2 kk x 4 ct) -----
__global__ void hproj_frag_kernel(const float* __restrict__ ni, const float* __restrict__ nj,
                                  const float* __restrict__ node, ush* __restrict__ WfragH) {
  int t = blockIdx.x * blockDim.x + threadIdx.x;
  if (t >= 12288) return;
  int i = t & 7, lane = (t >> 3) & 63, ct = (t >> 9) & 3, kk = (t >> 11) & 1, m = t >> 12;
  int k = kk * 32 + (lane >> 4) * 8 + i;
  int o = ct * 16 + (lane & 15);
  const float* W = (m == 0) ? ni : (m == 1) ? nj : node;
  WfragH[t] = f2bf(W[(size_t)k * 64 + o]);
}

// ---------------- layer-1 hproj via MFMA: face16(NNx32) @ folded {ni,nj,node}(32x64) -----
__global__ __launch_bounds__(256, 4) void mfma_hproj1_kernel(
    const ush* __restrict__ face16, const ush* __restrict__ WfragH1,
    const float* __restrict__ fold, ush* __restrict__ hs, ush* __restrict__ hd,
    ush* __restrict__ hn) {
  int wave = (blockIdx.x * blockDim.x + threadIdx.x) >> 6;
  int lane = threadIdx.x & 63;
  int m0 = wave * 16;
  if (m0 >= NN) return;
  int arow = lane & 15;
  int aoff = (lane >> 4) * 8;
  bf16x8 a = *(const bf16x8*)(face16 + (size_t)(m0 + arow) * 32 + aoff);
  int ccol = lane & 15;
  int crow = (lane >> 4) * 4;
#pragma unroll
  for (int m = 0; m < 3; ++m) {
    const ush* wm = WfragH1 + (size_t)m * 2048 + lane * 8;
    bf16x8 b0 = *(const bf16x8*)(wm + 0 * 512);
    bf16x8 b1 = *(const bf16x8*)(wm + 1 * 512);
    bf16x8 b2 = *(const bf16x8*)(wm + 2 * 512);
    bf16x8 b3 = *(const bf16x8*)(wm + 3 * 512);
    f32x4 acc0 = {0.f, 0.f, 0.f, 0.f};
    f32x4 acc1 = {0.f, 0.f, 0.f, 0.f};
    f32x4 acc2 = {0.f, 0.f, 0.f, 0.f};
    f32x4 acc3 = {0.f, 0.f, 0.f, 0.f};
    acc0 = __builtin_amdgcn_mfma_f32_16x16x32_bf16(a, b0, acc0, 0, 0, 0);
    acc1 = __builtin_amdgcn_mfma_f32_16x16x32_bf16(a, b1, acc1, 0, 0, 0);
    acc2 = __builtin_amdgcn_mfma_f32_16x16x32_bf16(a, b2, acc2, 0, 0, 0);
    acc3 = __builtin_amdgcn_mfma_f32_16x16x32_bf16(a, b3, acc3, 0, 0, 0);
    float bv0 = fold[7232 + m * 64 + ccol];
    float bv1 = fold[7232 + m * 64 + 16 + ccol];
    float bv2 = fold[7232 + m * 64 + 32 + ccol];
    float bv3 = fold[7232 + m * 64 + 48 + ccol];
    ush* outm = (m == 0) ? hs : (m == 1) ? hd : hn;
#pragma unroll
    for (int j = 0; j < 4; ++j) {
      ush* op = outm + (size_t)(m0 + crow + j) * 64;
      op[ccol] = f2bf(acc0[j] + bv0);
      op[16 + ccol] = f2bf(acc1[j] + bv1);
      op[32 + ccol] = f2bf(acc2[j] + bv2);
      op[48 + ccol] = f2bf(acc3[j] + bv3);
    }
  }
}

// ---------------- layer-1 edge GEMM via MFMA: ef16(NEx32) @ Wf1(32x64, folded) -----------
__global__ __launch_bounds__(256, 4) void mfma_fout1_kernel(
    const ush* __restrict__ ef16, const ush* __restrict__ Wf1frag, const float* __restrict__ fold,
    const ush* __restrict__ hs, const ush* __restrict__ hd, const int* __restrict__ src_s,
    const int* __restrict__ dst_s, const float* __restrict__ attn, ush* __restrict__ f116,
    float* __restrict__ logit) {
  int wave = (blockIdx.x * blockDim.x + threadIdx.x) >> 6;
  int lane = threadIdx.x & 63;
  int m0 = wave * 16;
  if (m0 >= NE) return;
  int arow = lane & 15;
  int aoff = (lane >> 4) * 8;
  bf16x8 a = *(const bf16x8*)(ef16 + (size_t)(m0 + arow) * 32 + aoff);
  const ush* wp = Wf1frag + lane * 8;
  bf16x8 b0 = *(const bf16x8*)(wp + 0 * 512);
  bf16x8 b1 = *(const bf16x8*)(wp + 1 * 512);
  bf16x8 b2 = *(const bf16x8*)(wp + 2 * 512);
  bf16x8 b3 = *(const bf16x8*)(wp + 3 * 512);
  f32x4 acc0 = {0.f, 0.f, 0.f, 0.f};
  f32x4 acc1 = {0.f, 0.f, 0.f, 0.f};
  f32x4 acc2 = {0.f, 0.f, 0.f, 0.f};
  f32x4 acc3 = {0.f, 0.f, 0.f, 0.f};
  acc0 = __builtin_amdgcn_mfma_f32_16x16x32_bf16(a, b0, acc0, 0, 0, 0);
  acc1 = __builtin_amdgcn_mfma_f32_16x16x32_bf16(a, b1, acc1, 0, 0, 0);
  acc2 = __builtin_amdgcn_mfma_f32_16x16x32_bf16(a, b2, acc2, 0, 0, 0);
  acc3 = __builtin_amdgcn_mfma_f32_16x16x32_bf16(a, b3, acc3, 0, 0, 0);
  int ccol = lane & 15;
  int crow = (lane >> 4) * 4;
  float av0 = attn[ccol], av1 = attn[16 + ccol], av2 = attn[32 + ccol], av3 = attn[48 + ccol];
  float bv0 = fold[1024 + ccol], bv1 = fold[1024 + 16 + ccol];
  float bv2 = fold[1024 + 32 + ccol], bv3 = fold[1024 + 48 + ccol];
#pragma unroll
  for (int j = 0; j < 4; ++j) {
    int r = m0 + crow + j;
    int s = src_s[r], d = dst_s[r];
    const ush* hsp = hs + (size_t)s * 64;
    const ush* hdp = hd + (size_t)d * 64;
    float f0 = acc0[j] + bf2f(hsp[ccol]) + bf2f(hdp[ccol]) + bv0;
    float f1 = acc1[j] + bf2f(hsp[16 + ccol]) + bf2f(hdp[16 + ccol]) + bv1;
    float f2 = acc2[j] + bf2f(hsp[32 + ccol]) + bf2f(hdp[32 + ccol]) + bv2;
    float f3 = acc3[j] + bf2f(hsp[48 + ccol]) + bf2f(hdp[48 + ccol]) + bv3;
    f0 = f0 >= 0.f ? f0 : 0.01f * f0;
    f1 = f1 >= 0.f ? f1 : 0.01f * f1;
    f2 = f2 >= 0.f ? f2 : 0.01f * f2;
    f3 = f3 >= 0.f ? f3 : 0.01f * f3;
    ush* fp = f116 + (size_t)r * 64;
    fp[ccol] = f2bf(f0);
    fp[16 + ccol] = f2bf(f1);
    fp[32 + ccol] = f2bf(f2);
    fp[48 + ccol] = f2bf(f3);
    float p = fmaf(f0, av0, fmaf(f1, av1, fmaf(f2, av2, f3 * av3)));
    p += __shfl_xor(p, 1, 64);
    p += __shfl_xor(p, 2, 64);
    p += __shfl_xor(p, 4, 64);
    p += __shfl_xor(p, 8, 64);
    if (ccol == 0) logit[r] = p;
  }
}

// ---------------- layer-2 hproj via MFMA: h1bf(NNx64) @ {ni,nj,node}(64x64) --------------
__global__ __launch_bounds__(256, 4) void mfma_hproj_kernel(
    const ush* __restrict__ h1bf, const ush* __restrict__ WfragH, ush* __restrict__ hs,
    ush* __restrict__ hd, ush* __restrict__ hn) {
  int wave = (blockIdx.x * blockDim.x + threadIdx.x) >> 6;
  int lane = threadIdx.x & 63;
  int m0 = wave * 16;
  if (m0 >= NN) return;
  int arow = lane & 15;
  int aoff = (lane >> 4) * 8;
  const ush* ap = h1bf + (size_t)(m0 + arow) * 64 + aoff;
  bf16x8 a0 = *(const bf16x8*)(ap);
  bf16x8 a1 = *(const bf16x8*)(ap + 32);
  const ush* wp = WfragH + lane * 8;
  int ccol = lane & 15;
  int crow = (lane >> 4) * 4;
#pragma unroll
  for (int m = 0; m < 3; ++m) {
    f32x4 acc0 = {0.f, 0.f, 0.f, 0.f};
    f32x4 acc1 = {0.f, 0.f, 0.f, 0.f};
    f32x4 acc2 = {0.f, 0.f, 0.f, 0.f};
    f32x4 acc3 = {0.f, 0.f, 0.f, 0.f};
    const ush* wm = wp + (size_t)m * 8 * 512;
    bf16x8 b0 = *(const bf16x8*)(wm + 0 * 512);
    bf16x8 b1 = *(const bf16x8*)(wm + 1 * 512);
    bf16x8 b2 = *(const bf16x8*)(wm + 2 * 512);
    bf16x8 b3 = *(const bf16x8*)(wm + 3 * 512);
    acc0 = __builtin_amdgcn_mfma_f32_16x16x32_bf16(a0, b0, acc0, 0, 0, 0);
    acc1 = __builtin_amdgcn_mfma_f32_16x16x32_bf16(a0, b1, acc1, 0, 0, 0);
    acc2 = __builtin_amdgcn_mfma_f32_16x16x32_bf16(a0, b2, acc2, 0, 0, 0);
    acc3 = __builtin_amdgcn_mfma_f32_16x16x32_bf16(a0, b3, acc3, 0, 0, 0);
    b0 = *(const bf16x8*)(wm + 4 * 512);
    b1 = *(const bf16x8*)(wm + 5 * 512);
    b2 = *(const bf16x8*)(wm + 6 * 512);
    b3 = *(const bf16x8*)(wm + 7 * 512);
    acc0 = __builtin_amdgcn_mfma_f32_16x16x32_bf16(a1, b0, acc0, 0, 0, 0);
    acc1 = __builtin_amdgcn_mfma_f32_16x16x32_bf16(a1, b1, acc1, 0, 0, 0);
    acc2 = __builtin_amdgcn_mfma_f32_16x16x32_bf16(a1, b2, acc2, 0, 0, 0);
    acc3 = __builtin_amdgcn_mfma_f32_16x16x32_bf16(a1, b3, acc3, 0, 0, 0);
    ush* outm = (m == 0) ? hs : (m == 1) ? hd : hn;
#pragma unroll
    for (int j = 0; j < 4; ++j) {
      ush* op = outm + (size_t)(m0 + crow + j) * 64;
      op[ccol] = f2bf(acc0[j]);
      op[16 + ccol] = f2bf(acc1[j]);
      op[32 + ccol] = f2bf(acc2[j]);
      op[48 + ccol] = f2bf(acc3[j]);
    }
  }
}

// ---------------- layer-2 edge GEMM via MFMA: f116(NEx64 bf16) @ fij(64x64) --------------
__global__ __launch_bounds__(256, 4) void mfma_fout_kernel(
    const ush* __restrict__ f116, const ush* __restrict__ Wfrag2, const float* __restrict__ bias,
    const ush* __restrict__ hs, const ush* __restrict__ hd, const int* __restrict__ src_s,
    const int* __restrict__ dst_s, const float* __restrict__ attn, float* __restrict__ logit) {
  int wave = (blockIdx.x * blockDim.x + threadIdx.x) >> 6;
  int lane = threadIdx.x & 63;
  int m0 = wave * 16;
  if (m0 >= NE) return;
  int arow = lane & 15;
  int aoff = (lane >> 4) * 8;
  const ush* ap = f116 + (size_t)(m0 + arow) * 64 + aoff;
  const ush* wp = Wfrag2 + lane * 8;
  f32x4 acc0 = {0.f, 0.f, 0.f, 0.f};
  f32x4 acc1 = {0.f, 0.f, 0.f, 0.f};
  f32x4 acc2 = {0.f, 0.f, 0.f, 0.f};
  f32x4 acc3 = {0.f, 0.f, 0.f, 0.f};
#pragma unroll
  for (int kk = 0; kk < 2; ++kk) {
    bf16x8 a = *(const bf16x8*)(ap + kk * 32);
    bf16x8 b0 = *(const bf16x8*)(wp + (size_t)(kk * 4 + 0) * 512);
    bf16x8 b1 = *(const bf16x8*)(wp + (size_t)(kk * 4 + 1) * 512);
    bf16x8 b2 = *(const bf16x8*)(wp + (size_t)(kk * 4 + 2) * 512);
    bf16x8 b3 = *(const bf16x8*)(wp + (size_t)(kk * 4 + 3) * 512);
    acc0 = __builtin_amdgcn_mfma_f32_16x16x32_bf16(a, b0, acc0, 0, 0, 0);
    acc1 = __builtin_amdgcn_mfma_f32_16x16x32_bf16(a, b1, acc1, 0, 0, 0);
    acc2 = __builtin_amdgcn_mfma_f32_16x16x32_bf16(a, b2, acc2, 0, 0, 0);
    acc3 = __builtin_amdgcn_mfma_f32_16x16x32_bf16(a, b3, acc3, 0, 0, 0);
  }
  int ccol = lane & 15;
  int crow = (lane >> 4) * 4;
  float av0 = attn[ccol], av1 = attn[16 + ccol], av2 = attn[32 + ccol], av3 = attn[48 + ccol];
  float bv0 = bias[ccol], bv1 = bias[16 + ccol], bv2 = bias[32 + ccol], bv3 = bias[48 + ccol];
#pragma unroll
  for (int j = 0; j < 4; ++j) {
    int r = m0 + crow + j;
    int s = src_s[r], d = dst_s[r];
    const ush* hsp = hs + (size_t)s * 64;
    const ush* hdp = hd + (size_t)d * 64;
    float f0 = acc0[j] + bf2f(hsp[ccol]) + bf2f(hdp[ccol]) + bv0;
    float f1 = acc1[j] + bf2f(hsp[16 + ccol]) + bf2f(hdp[16 + ccol]) + bv1;
    float f2 = acc2[j] + bf2f(hsp[32 + ccol]) + bf2f(hdp[32 + ccol]) + bv2;
    float f3 = acc3[j] + bf2f(hsp[48 + ccol]) + bf2f(hdp[48 + ccol]) + bv3;
    f0 = f0 >= 0.f ? f0 : 0.01f * f0;
    f1 = f1 >= 0.f ? f1 : 0.01f * f1;
    f2 = f2 >= 0.f ? f2 : 0.01f * f2;
    f3 = f3 >= 0.f ? f3 : 0.01f * f3;
    float p = fmaf(f0, av0, fmaf(f1, av1, fmaf(f2, av2, f3 * av3)));
    p += __shfl_xor(p, 1, 64);
    p += __shfl_xor(p, 2, 64);
    p += __shfl_xor(p, 4, 64);
    p += __shfl_xor(p, 8, 64);
    if (ccol == 0) logit[r] = p;
  }
}

// ---------------- EGAT: gather-aggregate (BF16OUT: h_out stored as bf16) -----------------
template <bool BF16OUT>
__global__ __launch_bounds__(256, 4) void agg_gather_kernel(
    const ush* __restrict__ hn, const float* __restrict__ logit, const int* __restrict__ rowptr,
    const int* __restrict__ deg, const int* __restrict__ src_s, void* __restrict__ hnew) {
  int wave = (blockIdx.x * blockDim.x + threadIdx.x) >> 6;
  int lane = threadIdx.x & 63;
  if (wave >= NN) return;
  int n = wave, d = deg[n], r0 = rowptr[n];
  if (d == 0) {
    if (BF16OUT) ((ush*)hnew)[(size_t)n * 64 + lane] = 0;
    else ((float*)hnew)[(size_t)n * 64 + lane] = 0.f;
    return;
  }
  float sum = 0.f, acc0 = 0.f, acc1 = 0.f, acc2 = 0.f, acc3 = 0.f;
  int j = 0;
  for (; j + 3 < d; j += 4) {
    int jj = r0 + j;
    int s0 = src_s[jj + 0], s1 = src_s[jj + 1], s2 = src_s[jj + 2], s3 = src_s[jj + 3];
    float l0 = logit[jj + 0], l1 = logit[jj + 1], l2 = logit[jj + 2], l3 = logit[jj + 3];
    ush h0 = hn[(size_t)s0 * 64 + lane];
    ush h1 = hn[(size_t)s1 * 64 + lane];
    ush h2 = hn[(size_t)s2 * 64 + lane];
    ush h3 = hn[(size_t)s3 * 64 + lane];
    float w0 = __expf(l0), w1 = __expf(l1);
    float w2 = __expf(l2), w3 = __expf(l3);
    sum += (w0 + w1) + (w2 + w3);
    acc0 = fmaf(w0, bf2f(h0), acc0);
    acc1 = fmaf(w1, bf2f(h1), acc1);
    acc2 = fmaf(w2, bf2f(h2), acc2);
    acc3 = fmaf(w3, bf2f(h3), acc3);
  }
  for (; j < d; ++j) {
    int jj = r0 + j;
    float w = __expf(logit[jj]);
    sum += w;
    acc0 = fmaf(w, bf2f(hn[(size_t)src_s[jj] * 64 + lane]), acc0);
  }
  float r = ((acc0 + acc1) + (acc2 + acc3)) / sum;
  if (BF16OUT) ((ush*)hnew)[(size_t)n * 64 + lane] = f2bf(r);
  else ((float*)hnew)[(size_t)n * 64 + lane] = r;
}

// ---------------- NNConv phase A: per-node outer-product G accumulate (registers only) ---
// ef read from ef16 (bf16, dst-sorted, sequential).
__global__ __launch_bounds__(256, 4) void nnconv_G_kernel(
    const float* __restrict__ face, const ush* __restrict__ ef16,
    const int* __restrict__ rowptr, const int* __restrict__ deg, const int* __restrict__ src_s,
    ush* __restrict__ G) {
  int wave = (blockIdx.x * blockDim.x + threadIdx.x) >> 6;
  int lane = threadIdx.x & 63;
  if (wave >= NN) return;
  int n = wave, d = deg[n], r0 = rowptr[n];
  int k4 = lane >> 2, ib = lane & 3;
  float g[8], fs[8];
#pragma unroll
  for (int u = 0; u < 8; ++u) { g[u] = 0.f; fs[u] = 0.f; }
  int j = 0;
  for (; j + 1 < d; j += 2) {
    int jj = r0 + j;
    int s0 = src_s[jj], s1 = src_s[jj + 1];
    float ev0 = bf2f(ef16[(size_t)jj * 32 + k4]);
    float ev1 = bf2f(ef16[(size_t)(jj + 1) * 32 + k4]);
    const float4* fp0 = (const float4*)(face + (size_t)s0 * 32 + ib * 8);
    const float4* fp1 = (const float4*)(face + (size_t)s1 * 32 + ib * 8);
    float4 fa0 = fp0[0], fb0 = fp0[1];
    float4 fa1 = fp1[0], fb1 = fp1[1];
    g[0] = fmaf(ev0, fa0.x, g[0]); g[1] = fmaf(ev0, fa0.y, g[1]);
    g[2] = fmaf(ev0, fa0.z, g[2]); g[3] = fmaf(ev0, fa0.w, g[3]);
    g[4] = fmaf(ev0, fb0.x, g[4]); g[5] = fmaf(ev0, fb0.y, g[5]);
    g[6] = fmaf(ev0, fb0.z, g[6]); g[7] = fmaf(ev0, fb0.w, g[7]);
    g[0] = fmaf(ev1, fa1.x, g[0]); g[1] = fmaf(ev1, fa1.y, g[1]);
    g[2] = fmaf(ev1, fa1.z, g[2]); g[3] = fmaf(ev1, fa1.w, g[3]);
    g[4] = fmaf(ev1, fb1.x, g[4]); g[5] = fmaf(ev1, fb1.y, g[5]);
    g[6] = fmaf(ev1, fb1.z, g[6]); g[7] = fmaf(ev1, fb1.w, g[7]);
    if (k4 == 0) {
      fs[0] += fa0.x + fa1.x; fs[1] += fa0.y + fa1.y;
      fs[2] += fa0.z + fa1.z; fs[3] += fa0.w + fa1.w;
      fs[4] += fb0.x + fb1.x; fs[5] += fb0.y + fb1.y;
      fs[6] += fb0.z + fb1.z; fs[7] += fb0.w + fb1.w;
    }
  }
  if (j < d) {
    int jj = r0 + j;
    int s0 = src_s[jj];
    float ev0 = bf2f(ef16[(size_t)jj * 32 + k4]);
    const float4* fp0 = (const float4*)(face + (size_t)s0 * 32 + ib * 8);
    float4 fa0 = fp0[0], fb0 = fp0[1];
    g[0] = fmaf(ev0, fa0.x, g[0]); g[1] = fmaf(ev0, fa0.y, g[1]);
    g[2] = fmaf(ev0, fa0.z, g[2]); g[3] = fmaf(ev0, fa0.w, g[3]);
    g[4] = fmaf(ev0, fb0.x, g[4]); g[5] = fmaf(ev0, fb0.y, g[5]);
    g[6] = fmaf(ev0, fb0.z, g[6]); g[7] = fmaf(ev0, fb0.w, g[7]);
    if (k4 == 0) {
      fs[0] += fa0.x; fs[1] += fa0.y; fs[2] += fa0.z; fs[3] += fa0.w;
      fs[4] += fb0.x; fs[5] += fb0.y; fs[6] += fb0.z; fs[7] += fb0.w;
    }
  }
  uint4 pv;
  pv.x = pack2(g[0], g[1]); pv.y = pack2(g[2], g[3]);
  pv.z = pack2(g[4], g[5]); pv.w = pack2(g[6], g[7]);
  *(uint4*)(G + (size_t)n * 544 + lane * 8) = pv;
  if (k4 == 0) {
    uint4 fv;
    fv.x = pack2(fs[0], fs[1]); fv.y = pack2(fs[2], fs[3]);
    fv.z = pack2(fs[4], fs[5]); fv.w = pack2(fs[6], fs[7]);
    *(uint4*)(G + (size_t)n * 544 + 512 + ib * 8) = fv;
  }
}

// ---------------- NNConv phase B: MFMA GEMM sArr = G(NNx544) @ W(544x32) ----------------
__global__ __launch_bounds__(256, 4) void gemm_G_mfma_kernel(const ush* __restrict__ G,
                                                             const ush* __restrict__ Wfrag,
                                                             float* __restrict__ sArr,
                                                             int rows) {
  int wave = (blockIdx.x * blockDim.x + threadIdx.x) >> 6;
  int lane = threadIdx.x & 63;
  int m0 = wave * 16;
  if (m0 >= rows) return;
  int arow = lane & 15;
  int aoff = (lane >> 4) * 8;
  const ush* gp = G + (size_t)(m0 + arow) * 544 + aoff;
  const ush* wp = Wfrag + lane * 8;
  f32x4 acc0 = {0.f, 0.f, 0.f, 0.f};
  f32x4 acc1 = {0.f, 0.f, 0.f, 0.f};
#pragma unroll 4
  for (int kk = 0; kk < 17; ++kk) {
    bf16x8 a = *(const bf16x8*)(gp + kk * 32);
    bf16x8 b0 = *(const bf16x8*)(wp + (size_t)(kk * 2 + 0) * 512);
    bf16x8 b1 = *(const bf16x8*)(wp + (size_t)(kk * 2 + 1) * 512);
    acc0 = __builtin_amdgcn_mfma_f32_16x16x32_bf16(a, b0, acc0, 0, 0, 0);
    acc1 = __builtin_amdgcn_mfma_f32_16x16x32_bf16(a, b1, acc1, 0, 0, 0);
  }
  int ccol = lane & 15;
  int crow = (lane >> 4) * 4;
#pragma unroll
  for (int j = 0; j < 4; ++j) {
    int r = m0 + crow + j;
    sArr[(size_t)r * 32 + ccol] = acc0[j];
    sArr[(size_t)r * 32 + 16 + ccol] = acc1[j];
  }
}

// ---------------- combine node_features + gate logit (fused; wave per node) --------------
__global__ void combine_gate_kernel(const float* __restrict__ hfin, const float* __restrict__ sArr,
                                    const int* __restrict__ deg, const float* __restrict__ nn_bias,
                                    const float* __restrict__ gate_w, const float* __restrict__ gate_b,
                                    float* __restrict__ out, float* __restrict__ g) {
  int wave = (blockIdx.x * blockDim.x + threadIdx.x) >> 6;
  int lane = threadIdx.x & 63;
  if (wave >= NN) return;
  int n = wave;
  float v0 = hfin[(size_t)n * 64 + lane];
  int c1 = lane + 64;
  float v1 = (c1 < 96)
                 ? sArr[(size_t)n * 32 + (c1 - 64)] / fmaxf((float)deg[n], 1.0f) + nn_bias[c1 - 64]
                 : 0.f;
  out[(size_t)n * 128 + lane] = v0;
  out[(size_t)n * 128 + c1] = v1;
  float p = v0 * gate_w[lane] + ((c1 < 96) ? v1 * gate_w[c1] : 0.f);
#pragma unroll
  for (int off = 32; off; off >>= 1) p += __shfl_xor(p, off, 64);
  if (lane == 0) g[n] = p + gate_b[0];
}

// ---------------- max over g (block-reduced, 1 atomic per block) ----------------
__global__ void gate_max_kernel(const float* __restrict__ g, unsigned* __restrict__ gmax) {
  int tid = blockIdx.x * blockDim.x + threadIdx.x;
  int stride = gridDim.x * blockDim.x;
  float v = -3.0e38f;
  for (int n = tid; n < NN; n += stride) v = fmaxf(v, g[n]);
#pragma unroll
  for (int off = 32; off; off >>= 1) v = fmaxf(v, __shfl_xor(v, off, 64));
  __shared__ float sm[4];
  int lane = threadIdx.x & 63, wid = threadIdx.x >> 6;
  if (lane == 0) sm[wid] = v;
  __syncthreads();
  if (threadIdx.x == 0) {
    float m = fmaxf(fmaxf(sm[0], sm[1]), fmaxf(sm[2], sm[3]));
    atomicMax(gmax, ord_enc(m));
  }
}

// ---------------- pooling: exp + weighted accumulate into per-row-stream partials --------
__global__ __launch_bounds__(256, 4) void pool_exp_kernel(
    const float* __restrict__ nf, const float* __restrict__ g, const unsigned* __restrict__ gmax,
    float* __restrict__ pacc, float* __restrict__ wsb) {
  int o = threadIdx.x & 127;
  int half = threadIdx.x >> 7;
  int ri = blockIdx.x * 2 + half;   // 0 .. 2*PB-1
  float m = ord_dec(*gmax);
  float acc0 = 0.f, acc1 = 0.f, ws = 0.f;
  int n = ri;
  const int STR = PB * 2;
  for (; n + STR < NN; n += STR * 2) {
    float w0 = __expf(g[n] - m);
    float w1 = __expf(g[n + STR] - m);
    float v0 = nf[(size_t)n * 128 + o];
    float v1 = nf[(size_t)(n + STR) * 128 + o];
    ws += w0 + w1;
    acc0 = fmaf(w0, v0, acc0);
    acc1 = fmaf(w1, v1, acc1);
  }
  if (n < NN) {
    float w = __expf(g[n] - m);
    ws += w;
    acc0 = fmaf(w, nf[(size_t)n * 128 + o], acc0);
  }
  pacc[(size_t)ri * 128 + o] = acc0 + acc1;
  if (o == 0) wsb[ri] = ws;
}

__global__ void pool_reduce_kernel(const float* __restrict__ pacc, const float* __restrict__ wsb,
                                   float* __restrict__ gacc, float* __restrict__ gsum) {
  int b = blockIdx.x;
  int t = threadIdx.x;  // 256
  float v = 0.f;
  if (b < 128) {
    for (int ri = t; ri < PB * 2; ri += 256) v += pacc[(size_t)ri * 128 + b];
  } else {
    for (int ri = t; ri < PB * 2; ri += 256) v += wsb[ri];
  }
#pragma unroll
  for (int off = 32; off; off >>= 1) v += __shfl_xor(v, off, 64);
  __shared__ float sm[4];
  int lane = t & 63, wid = t >> 6;
  if (lane == 0) sm[wid] = v;
  __syncthreads();
  if (t == 0) {
    float s = (sm[0] + sm[1]) + (sm[2] + sm[3]);
    if (b < 128) gacc[b] = s;
    else gsum[0] = s;
  }
}

__global__ void finalize_kernel(const float* __restrict__ gacc, const float* __restrict__ gsum,
                                float* __restrict__ out) {
  int o = threadIdx.x;
  if (o < 128) out[(size_t)NN * 128 + o] = gacc[o] / gsum[0];
}

extern "C" void kernel_launch(void* const* d_in, const int* in_sizes, int n_in,
                              void* d_out, int out_size, void* d_ws, size_t ws_size,
                              hipStream_t stream) {
  const float* face    = (const float*)d_in[0];
  const float* ef      = (const float*)d_in[1];
  const float* fp_w    = (const float*)d_in[2];
  const float* fp_b    = (const float*)d_in[3];
  const float* ep_w    = (const float*)d_in[4];
  const float* ep_b    = (const float*)d_in[5];
  const float* nn_w    = (const float*)d_in[6];
  const float* nn_b    = (const float*)d_in[7];
  const float* nn_bias = (const float*)d_in[8];
  const float* gate_w  = (const float*)d_in[9];
  const float* gate_b  = (const float*)d_in[10];
  const int*   src     = (const int*)d_in[11];
  const int*   dst     = (const int*)d_in[12];
  const float* e1_attn = (const float*)d_in[17];
  const float* e2_ni   = (const float*)d_in[19];
  const float* e2_nj   = (const float*)d_in[20];
  const float* e2_fij  = (const float*)d_in[21];
  const float* e2_attn = (const float*)d_in[23];
  const float* e2_bias = (const float*)d_in[24];
  float* out = (float*)d_out;

  char* p = (char*)d_ws;
  auto alloc = [&](size_t nfloats) {
    float* r = (float*)p;
    p += ((nfloats * 4 + 255) / 256) * 256;
    return r;
  };
  float* h0 = alloc((size_t)NN * 64);         // layer-2 output (f32)
  ush* h1bf = (ush*)alloc((size_t)NN * 32);   // layer-1 output (bf16)
  // big region: G (NN*544 bf16 = 65.28 MB) aliases hs16|hd16|hn16|f116|logit (dead post-EGAT)
  char* bigreg = p;
  ush* hs16 = (ush*)alloc((size_t)NN * 32);   // NN*64 bf16
  ush* hd16 = (ush*)alloc((size_t)NN * 32);
  ush* hn16 = (ush*)alloc((size_t)NN * 32);
  ush* f116 = (ush*)alloc((size_t)NE * 32);   // NE*64 bf16 (dst-sorted order)
  float* logit = alloc(NE);                   // dst-sorted order
  {  // pad bigreg to >= NN*544*2 bytes for G
    size_t used = (size_t)(p - bigreg);
    size_t need = (size_t)NN * 544 * 2;
    if (used < need) p += ((need - used + 255) / 256) * 256;
  }
  ush* G = (ush*)bigreg;
  float* sArr  = alloc((size_t)NN * 32);
  float* g     = alloc(NN);
  float* gacc  = alloc(128);
  float* gsum  = alloc(1);
  unsigned* gmax = (unsigned*)alloc(1);
  float* fold  = alloc(7424);
  ush* Wfrag   = (ush*)alloc(17408 / 2);      // nn MFMA B-fragments
  ush* Wfrag2  = (ush*)alloc(4096 / 2);       // e2_fij MFMA B-fragments
  ush* WfragH  = (ush*)alloc(12288 / 2);      // e2_{ni,nj,node} MFMA B-fragments
  ush* Wf1frag = (ush*)alloc(2048 / 2);       // layer-1 folded fij MFMA B-fragments
  ush* WfragH1 = (ush*)alloc(6144 / 2);       // layer-1 folded {ni,nj,node} B-fragments
  ush* face16  = (ush*)alloc((size_t)NN * 16);  // NN*32 bf16
  ush* ef16    = (ush*)alloc((size_t)NE * 16);  // NE*32 bf16 (k>=16 zero, dst-sorted)
  float* pacc  = alloc((size_t)PB * 2 * 128); // pooling partials
  float* wsb   = alloc(PB * 2);
  // dst-CSR
  int* deg    = (int*)alloc(NN);
  int* rowptr = (int*)alloc(NN);
  int* cursor = (int*)alloc(NN);
  int* partial = (int*)alloc(256);
  int* src_s  = (int*)alloc(NE);
  int* dst_s  = (int*)alloc(NE);

  const int B = 256;
  const int NB256 = cdiv(NN, 256);

  // ---- CSR build (dst-sorted) + fused edge permutation (bf16 only) ----
  hipMemsetAsync(deg, 0, NN * 4, stream);
  deg_kernel<<<cdiv(NE, B), B, 0, stream>>>(dst, deg);
  scan1_kernel<<<NB256, 256, 0, stream>>>(deg, rowptr, partial);
  scan2_kernel<<<1, 256, 0, stream>>>(partial, NB256);
  scan3_kernel<<<NB256, 256, 0, stream>>>(rowptr, partial, cursor);
  scatter_dst_kernel<<<cdiv(NE, B), B, 0, stream>>>(src, dst, ef, cursor, src_s, dst_s, ef16);

  // ---- weight prep: fold + fragment packs + face convert (tiny) ----
  fold_kernel<<<29, B, 0, stream>>>(fp_w, fp_b, ep_w, ep_b,
                                    (const float*)d_in[15], (const float*)d_in[18],
                                    (const float*)d_in[13], (const float*)d_in[14],
                                    (const float*)d_in[16], fold);
  fold1_frag_kernel<<<32, B, 0, stream>>>(fold, Wf1frag, WfragH1);
  nnwt_frag_kernel<<<68, B, 0, stream>>>(nn_w, nn_b, Wfrag);
  fij_frag_kernel<<<16, B, 0, stream>>>(e2_fij, Wfrag2);
  hproj_frag_kernel<<<48, B, 0, stream>>>(e2_ni, e2_nj, (const float*)d_in[22], WfragH);
  face16_kernel<<<cdiv(NN * 8, B), B, 0, stream>>>(face, face16);

  // ---- EGAT layer 1 (all matmuls on matrix cores) ----
  mfma_hproj1_kernel<<<cdiv(NN * 4, B), B, 0, stream>>>(face16, WfragH1, fold, hs16, hd16, hn16);
  mfma_fout1_kernel<<<cdiv(NE * 4, B), B, 0, stream>>>(ef16, Wf1frag, fold, hs16, hd16,
                                                       src_s, dst_s, e1_attn, f116, logit);
  agg_gather_kernel<true><<<cdiv(NN * 64, B), B, 0, stream>>>(hn16, logit, rowptr, deg,
                                                              src_s, h1bf);

  // ---- EGAT layer 2 (hproj + edge GEMM on matrix cores) ----
  mfma_hproj_kernel<<<cdiv(NN * 4, B), B, 0, stream>>>(h1bf, WfragH, hs16, hd16, hn16);
  mfma_fout_kernel<<<cdiv(NE * 4, B), B, 0, stream>>>(f116, Wfrag2, e2_bias, hs16, hd16,
                                                      src_s, dst_s, e2_attn, logit);
  agg_gather_kernel<false><<<cdiv(NN * 64, B), B, 0, stream>>>(hn16, logit, rowptr, deg,
                                                               src_s, h0);

  // ---- NNConv (outer-product form; G aliases dead EGAT buffers — runs after EGAT) ----
  nnconv_G_kernel<<<cdiv(NN * 64, B), B, 0, stream>>>(face, ef16, rowptr, deg, src_s, G);
  gemm_G_mfma_kernel<<<cdiv(NN * 4, B), B, 0, stream>>>(G, Wfrag, sArr, NN);

  // ---- combine node features + gate logits ----
  hipMemsetAsync(gmax, 0, 4, stream);
  combine_gate_kernel<<<cdiv(NN * 64, B), B, 0, stream>>>(h0, sArr, deg, nn_bias, gate_w,
                                                          gate_b, out, g);
  gate_max_kernel<<<128, B, 0, stream>>>(g, gmax);
  pool_exp_kernel<<<PB, B, 0, stream>>>(out, g, gmax, pacc, wsb);
  pool_reduce_kernel<<<129, B, 0, stream>>>(pacc, wsb, gacc, gsum);
  finalize_kernel<<<1, 128, 0, stream>>>(gacc, gsum, out);
}